// Round 2
// baseline (741.475 us; speedup 1.0000x reference)
//
#include <hip/hip_runtime.h>

#define NN 100000
#define NE 800000

#define FMA4(acc, s, w) do { \
    acc.x = fmaf(s, w.x, acc.x); \
    acc.y = fmaf(s, w.y, acc.y); \
    acc.z = fmaf(s, w.z, acc.z); \
    acc.w = fmaf(s, w.w, acc.w); } while (0)

__global__ void k_fill(float* __restrict__ p, int n, float v) {
  int i = blockIdx.x * blockDim.x + threadIdx.x;
  int st = gridDim.x * blockDim.x;
  for (; i < n; i += st) p[i] = v;
}

__global__ void k_deg(const int* __restrict__ ei, float* __restrict__ deg) {
  int e = blockIdx.x * blockDim.x + threadIdx.x;
  if (e < NE) atomicAdd(&deg[ei[NE + e]], 1.0f);
}

__global__ void k_rsqrt(float* __restrict__ p, int n) {
  int i = blockIdx.x * blockDim.x + threadIdx.x;
  if (i < n) p[i] = rsqrtf(p[i]);
}

// cvec[c] = blin[c] + sum_k b3[k] * Wlin[k][c]
__global__ void k_cvec(const float* __restrict__ b3, const float* __restrict__ Wlin,
                       const float* __restrict__ blin, float* __restrict__ cvec) {
  int c = threadIdx.x;
  if (c < 10) {
    float s = blin[c];
    for (int k = 0; k < 64; ++k) s = fmaf(b3[k], Wlin[k * 10 + c], s);
    cvec[c] = s;
  }
}

// Per block: 128 rows. Y = act(A) @ Wa ; Z = act(A) @ Wb + bias   (DUAL)
// or (SCALE): Y = Z = (act(A) @ Wa) * scale[row]
template<bool RELU_IN, bool DUAL, bool SCALE>
__global__ __launch_bounds__(256) void k_gemm64(
    const float* __restrict__ A,
    const float* __restrict__ Wa, const float* __restrict__ Wb,
    const float* __restrict__ bias, const float* __restrict__ scale,
    float* __restrict__ Y, float* __restrict__ Z)
{
  __shared__ float sWa[64 * 64];
  __shared__ float sWb[DUAL ? 64 * 64 : 4];
  __shared__ float sA[128 * 68];   // stride 68: float4-aligned, 2-way-max bank alias

  const int tid = threadIdx.x;

  // stage W (and Wb) into LDS: 1024 float4 each
  {
    const float4* wa4 = (const float4*)Wa;
    float4* swa4 = (float4*)sWa;
#pragma unroll
    for (int i = 0; i < 4; ++i) swa4[tid + 256 * i] = wa4[tid + 256 * i];
    if (DUAL) {
      const float4* wb4 = (const float4*)Wb;
      float4* swb4 = (float4*)sWb;
#pragma unroll
      for (int i = 0; i < 4; ++i) swb4[tid + 256 * i] = wb4[tid + 256 * i];
    }
  }

  const int row0 = blockIdx.x * 128;
  // stage A tile: 128 rows x 16 float4, optional relu on read
#pragma unroll
  for (int i = 0; i < 8; ++i) {
    int pos = tid + 256 * i;
    int r = pos >> 4, c4 = pos & 15;
    int row = row0 + r;
    float4 v = make_float4(0.f, 0.f, 0.f, 0.f);
    if (row < NN) v = *(const float4*)&A[row * 64 + c4 * 4];
    if (RELU_IN) {
      v.x = fmaxf(v.x, 0.f); v.y = fmaxf(v.y, 0.f);
      v.z = fmaxf(v.z, 0.f); v.w = fmaxf(v.w, 0.f);
    }
    *(float4*)&sA[r * 68 + c4 * 4] = v;
  }
  __syncthreads();

  const int node = tid >> 2;   // 0..63
  const int quad = tid & 3;    // 0..3 -> output cols quad*16 .. +15

  float4 y0[4], y1[4], z0[4], z1[4];
#pragma unroll
  for (int j = 0; j < 4; ++j) {
    y0[j] = make_float4(0.f, 0.f, 0.f, 0.f);
    y1[j] = make_float4(0.f, 0.f, 0.f, 0.f);
    if (DUAL) {
      float4 b = *(const float4*)&bias[quad * 16 + j * 4];
      z0[j] = b; z1[j] = b;
    } else {
      z0[j] = make_float4(0.f, 0.f, 0.f, 0.f);
      z1[j] = make_float4(0.f, 0.f, 0.f, 0.f);
    }
  }

  const float* pA0 = &sA[node * 68];
  const float* pA1 = &sA[(node + 64) * 68];

#pragma unroll 8
  for (int k = 0; k < 64; ++k) {
    float a0 = pA0[k];
    float a1 = pA1[k];
    const float4* wr = (const float4*)&sWa[k * 64 + quad * 16];
#pragma unroll
    for (int j = 0; j < 4; ++j) {
      float4 w = wr[j];
      FMA4(y0[j], a0, w);
      FMA4(y1[j], a1, w);
    }
    if (DUAL) {
      const float4* wrb = (const float4*)&sWb[k * 64 + quad * 16];
#pragma unroll
      for (int j = 0; j < 4; ++j) {
        float4 w = wrb[j];
        FMA4(z0[j], a0, w);
        FMA4(z1[j], a1, w);
      }
    }
  }

  const int r0 = row0 + node;
  const int r1 = row0 + node + 64;
  if (r0 < NN) {
    if (SCALE) {
      float s = scale[r0];
#pragma unroll
      for (int j = 0; j < 4; ++j) {
        float4 v = y0[j];
        v.x *= s; v.y *= s; v.z *= s; v.w *= s;
        *(float4*)&Y[r0 * 64 + quad * 16 + j * 4] = v;
        *(float4*)&Z[r0 * 64 + quad * 16 + j * 4] = v;
      }
    } else {
#pragma unroll
      for (int j = 0; j < 4; ++j) {
        *(float4*)&Y[r0 * 64 + quad * 16 + j * 4] = y0[j];
        if (DUAL) *(float4*)&Z[r0 * 64 + quad * 16 + j * 4] = z0[j];
      }
    }
  }
  if (r1 < NN) {
    if (SCALE) {
      float s = scale[r1];
#pragma unroll
      for (int j = 0; j < 4; ++j) {
        float4 v = y1[j];
        v.x *= s; v.y *= s; v.z *= s; v.w *= s;
        *(float4*)&Y[r1 * 64 + quad * 16 + j * 4] = v;
        *(float4*)&Z[r1 * 64 + quad * 16 + j * 4] = v;
      }
    } else {
#pragma unroll
      for (int j = 0; j < 4; ++j) {
        *(float4*)&Y[r1 * 64 + quad * 16 + j * 4] = y1[j];
        if (DUAL) *(float4*)&Z[r1 * 64 + quad * 16 + j * 4] = z1[j];
      }
    }
  }
}

// one wave per edge: Z[dst][lane] += Y[src][lane]
__global__ __launch_bounds__(256) void k_scatter(const int* __restrict__ ei,
    const float* __restrict__ Y, float* __restrict__ Z)
{
  int idx = blockIdx.x * 256 + threadIdx.x;
  int e = idx >> 6;
  int lane = idx & 63;
  if (e >= NE) return;
  int s = ei[e];
  int d = ei[NE + e];
  atomicAdd(&Z[d * 64 + lane], Y[s * 64 + lane]);
}

// out[n][c] = dinv[n] * dot(T[n], Wlin[:,c]) + cvec[c]
__global__ __launch_bounds__(256) void k_head(const float* __restrict__ T,
    const float* __restrict__ dinv, const float* __restrict__ Wlin,
    const float* __restrict__ cvec, float* __restrict__ out)
{
  __shared__ float sW[64 * 10];
  __shared__ float sc[10];
  int tid = threadIdx.x;
  if (tid < 10) sc[tid] = cvec[tid];
  for (int i = tid; i < 640; i += 256) sW[i] = Wlin[i];
  __syncthreads();
  int n = blockIdx.x * 256 + tid;
  if (n >= NN) return;
  float di = dinv[n];
  float dot[10];
#pragma unroll
  for (int c = 0; c < 10; ++c) dot[c] = 0.f;
  const float* row = &T[n * 64];
#pragma unroll
  for (int kc = 0; kc < 16; ++kc) {
    float4 v = *(const float4*)&row[kc * 4];
#pragma unroll
    for (int c = 0; c < 10; ++c) {
      dot[c] = fmaf(v.x, sW[(kc * 4 + 0) * 10 + c], dot[c]);
      dot[c] = fmaf(v.y, sW[(kc * 4 + 1) * 10 + c], dot[c]);
      dot[c] = fmaf(v.z, sW[(kc * 4 + 2) * 10 + c], dot[c]);
      dot[c] = fmaf(v.w, sW[(kc * 4 + 3) * 10 + c], dot[c]);
    }
  }
#pragma unroll
  for (int c = 0; c < 10; ++c) out[n * 10 + c] = fmaf(di, dot[c], sc[c]);
}

extern "C" void kernel_launch(void* const* d_in, const int* in_sizes, int n_in,
                              void* d_out, int out_size, void* d_ws, size_t ws_size,
                              hipStream_t stream) {
  const float* x       = (const float*)d_in[0];
  const int*   ei      = (const int*)d_in[1];   // int32 per harness contract
  const float* W1_rel  = (const float*)d_in[2];
  const float* b1      = (const float*)d_in[3];
  const float* W1_root = (const float*)d_in[4];
  const float* W2_rel  = (const float*)d_in[5];
  const float* b2      = (const float*)d_in[6];
  const float* W2_root = (const float*)d_in[7];
  const float* W3      = (const float*)d_in[8];
  const float* b3      = (const float*)d_in[9];
  const float* Wlin    = (const float*)d_in[10];
  const float* blin    = (const float*)d_in[11];
  float* out = (float*)d_out;

  char* ws = (char*)d_ws;
  float* Y    = (float*)(ws);                 // N*64*4 = 25,600,000 B
  float* Z    = (float*)(ws + 25600000);      // 25,600,000 B
  float* D    = (float*)(ws + 51200000);      // N*4 = 400,000 B (deg -> dinv)
  float* cvec = (float*)(ws + 51600000);      // 40 B

  dim3 b256(256);

  k_fill<<<392, b256, 0, stream>>>(D, NN, 1.0f);
  k_deg<<<(NE + 255) / 256, b256, 0, stream>>>(ei, D);
  k_rsqrt<<<(NN + 255) / 256, b256, 0, stream>>>(D, NN);
  k_cvec<<<1, 16, 0, stream>>>(b3, Wlin, blin, cvec);

  const int gg = (NN + 127) / 128;           // 782
  const int gs = (NE * 64) / 256;            // 200000

  // layer 1: Y = x@W1_rel ; Z = x@W1_root + b1 ; Z[dst] += Y[src]
  k_gemm64<false, true, false><<<gg, b256, 0, stream>>>(x, W1_rel, W1_root, b1, nullptr, Y, Z);
  k_scatter<<<gs, b256, 0, stream>>>(ei, Y, Z);

  // layer 2: A = relu(Z); Y = A@W2_rel ; Z = A@W2_root + b2 ; Z[dst] += Y[src]
  k_gemm64<true, true, false><<<gg, b256, 0, stream>>>(Z, W2_rel, W2_root, b2, nullptr, Y, Z);
  k_scatter<<<gs, b256, 0, stream>>>(ei, Y, Z);

  // layer 3 (GCN): A = relu(Z); xs = (A@W3)*dinv ; Y = Z = xs ; Z[dst] += Y[src]
  k_gemm64<true, false, true><<<gg, b256, 0, stream>>>(Z, W3, nullptr, nullptr, D, Y, Z);
  k_scatter<<<gs, b256, 0, stream>>>(ei, Y, Z);

  // head: out = dinv * (Z @ Wlin) + (b3@Wlin + blin)
  k_head<<<(NN + 255) / 256, b256, 0, stream>>>(Z, D, Wlin, cvec, out);
}

// Round 3
// 426.917 us; speedup vs baseline: 1.7368x; 1.7368x over previous
//
#include <hip/hip_runtime.h>

#define NN 100000
#define NE 800000
#define SCAN_B 1024
#define NB ((NN + SCAN_B - 1) / SCAN_B)   // 98

#define FMA4(acc, s, w) do { \
    acc.x = fmaf(s, w.x, acc.x); \
    acc.y = fmaf(s, w.y, acc.y); \
    acc.z = fmaf(s, w.z, acc.z); \
    acc.w = fmaf(s, w.w, acc.w); } while (0)

__global__ void k_izero(int* __restrict__ p, int n) {
  int i = blockIdx.x * blockDim.x + threadIdx.x;
  if (i < n) p[i] = 0;
}

__global__ void k_hist(const int* __restrict__ ei, int* __restrict__ cnt) {
  int e = blockIdx.x * blockDim.x + threadIdx.x;
  if (e < NE) atomicAdd(&cnt[ei[NE + e]], 1);
}

// per-block exclusive scan of cnt (1024 elems/block), block sums out
__global__ __launch_bounds__(256) void k_scan_block(const int* __restrict__ cnt,
    int* __restrict__ eoff, int* __restrict__ bsum) {
  __shared__ int sd[256];
  int tid = threadIdx.x;
  int base = blockIdx.x * SCAN_B + tid * 4;
  int v0 = 0, v1 = 0, v2 = 0, v3 = 0;
  if (base + 0 < NN) v0 = cnt[base + 0];
  if (base + 1 < NN) v1 = cnt[base + 1];
  if (base + 2 < NN) v2 = cnt[base + 2];
  if (base + 3 < NN) v3 = cnt[base + 3];
  int tsum = v0 + v1 + v2 + v3;
  sd[tid] = tsum;
  __syncthreads();
  int incl = tsum;
  for (int off = 1; off < 256; off <<= 1) {
    int add = (tid >= off) ? sd[tid - off] : 0;
    __syncthreads();
    incl += add;
    sd[tid] = incl;
    __syncthreads();
  }
  if (tid == 255) bsum[blockIdx.x] = incl;
  int r = incl - tsum;
  if (base + 0 < NN) eoff[base + 0] = r; r += v0;
  if (base + 1 < NN) eoff[base + 1] = r; r += v1;
  if (base + 2 < NN) eoff[base + 2] = r; r += v2;
  if (base + 3 < NN) eoff[base + 3] = r;
}

// exclusive scan of NB block sums (single block)
__global__ __launch_bounds__(128) void k_scan_tops(const int* __restrict__ bsum,
    int* __restrict__ boff) {
  __shared__ int sd[128];
  int tid = threadIdx.x;
  int v = (tid < NB) ? bsum[tid] : 0;
  sd[tid] = v;
  __syncthreads();
  int incl = v;
  for (int off = 1; off < 128; off <<= 1) {
    int add = (tid >= off) ? sd[tid - off] : 0;
    __syncthreads();
    incl += add;
    sd[tid] = incl;
    __syncthreads();
  }
  if (tid < NB) boff[tid] = incl - v;
}

// row_ptr = boff[blk] + eoff ; cursor = row_ptr ; dinv = rsqrt(cnt+1)
__global__ void k_scan_apply(const int* __restrict__ cnt, const int* __restrict__ eoff,
    const int* __restrict__ boff, int* __restrict__ row_ptr, int* __restrict__ cursor,
    float* __restrict__ dinv) {
  int i = blockIdx.x * blockDim.x + threadIdx.x;
  if (i < NN) {
    int rp = boff[i >> 10] + eoff[i];
    row_ptr[i] = rp;
    cursor[i] = rp;
    dinv[i] = rsqrtf((float)cnt[i] + 1.0f);
    if (i == 0) row_ptr[NN] = NE;
  }
}

__global__ void k_fill_csr(const int* __restrict__ ei, int* __restrict__ cursor,
    int* __restrict__ csr) {
  int e = blockIdx.x * blockDim.x + threadIdx.x;
  if (e < NE) {
    int d = ei[NE + e];
    int slot = atomicAdd(&cursor[d], 1);
    csr[slot] = ei[e];
  }
}

// cvec[c] = blin[c] + sum_k b3[k] * Wlin[k][c]
__global__ void k_cvec(const float* __restrict__ b3, const float* __restrict__ Wlin,
                       const float* __restrict__ blin, float* __restrict__ cvec) {
  int c = threadIdx.x;
  if (c < 10) {
    float s = blin[c];
    for (int k = 0; k < 64; ++k) s = fmaf(b3[k], Wlin[k * 10 + c], s);
    cvec[c] = s;
  }
}

// Per block: 128 rows. Y = act(A) @ Wa ; Z = act(A) @ Wb + bias   (DUAL)
// or (SCALE): Y = Z = (act(A) @ Wa) * scale[row]
template<bool RELU_IN, bool DUAL, bool SCALE>
__global__ __launch_bounds__(256) void k_gemm64(
    const float* __restrict__ A,
    const float* __restrict__ Wa, const float* __restrict__ Wb,
    const float* __restrict__ bias, const float* __restrict__ scale,
    float* __restrict__ Y, float* __restrict__ Z)
{
  __shared__ float sWa[64 * 64];
  __shared__ float sWb[DUAL ? 64 * 64 : 4];
  __shared__ float sA[128 * 68];

  const int tid = threadIdx.x;

  {
    const float4* wa4 = (const float4*)Wa;
    float4* swa4 = (float4*)sWa;
#pragma unroll
    for (int i = 0; i < 4; ++i) swa4[tid + 256 * i] = wa4[tid + 256 * i];
    if (DUAL) {
      const float4* wb4 = (const float4*)Wb;
      float4* swb4 = (float4*)sWb;
#pragma unroll
      for (int i = 0; i < 4; ++i) swb4[tid + 256 * i] = wb4[tid + 256 * i];
    }
  }

  const int row0 = blockIdx.x * 128;
#pragma unroll
  for (int i = 0; i < 8; ++i) {
    int pos = tid + 256 * i;
    int r = pos >> 4, c4 = pos & 15;
    int row = row0 + r;
    float4 v = make_float4(0.f, 0.f, 0.f, 0.f);
    if (row < NN) v = *(const float4*)&A[row * 64 + c4 * 4];
    if (RELU_IN) {
      v.x = fmaxf(v.x, 0.f); v.y = fmaxf(v.y, 0.f);
      v.z = fmaxf(v.z, 0.f); v.w = fmaxf(v.w, 0.f);
    }
    *(float4*)&sA[r * 68 + c4 * 4] = v;
  }
  __syncthreads();

  const int node = tid >> 2;
  const int quad = tid & 3;

  float4 y0[4], y1[4], z0[4], z1[4];
#pragma unroll
  for (int j = 0; j < 4; ++j) {
    y0[j] = make_float4(0.f, 0.f, 0.f, 0.f);
    y1[j] = make_float4(0.f, 0.f, 0.f, 0.f);
    if (DUAL) {
      float4 b = *(const float4*)&bias[quad * 16 + j * 4];
      z0[j] = b; z1[j] = b;
    } else {
      z0[j] = make_float4(0.f, 0.f, 0.f, 0.f);
      z1[j] = make_float4(0.f, 0.f, 0.f, 0.f);
    }
  }

  const float* pA0 = &sA[node * 68];
  const float* pA1 = &sA[(node + 64) * 68];

#pragma unroll 8
  for (int k = 0; k < 64; ++k) {
    float a0 = pA0[k];
    float a1 = pA1[k];
    const float4* wr = (const float4*)&sWa[k * 64 + quad * 16];
#pragma unroll
    for (int j = 0; j < 4; ++j) {
      float4 w = wr[j];
      FMA4(y0[j], a0, w);
      FMA4(y1[j], a1, w);
    }
    if (DUAL) {
      const float4* wrb = (const float4*)&sWb[k * 64 + quad * 16];
#pragma unroll
      for (int j = 0; j < 4; ++j) {
        float4 w = wrb[j];
        FMA4(z0[j], a0, w);
        FMA4(z1[j], a1, w);
      }
    }
  }

  const int r0 = row0 + node;
  const int r1 = row0 + node + 64;
  if (r0 < NN) {
    if (SCALE) {
      float s = scale[r0];
#pragma unroll
      for (int j = 0; j < 4; ++j) {
        float4 v = y0[j];
        v.x *= s; v.y *= s; v.z *= s; v.w *= s;
        *(float4*)&Y[r0 * 64 + quad * 16 + j * 4] = v;
        *(float4*)&Z[r0 * 64 + quad * 16 + j * 4] = v;
      }
    } else {
#pragma unroll
      for (int j = 0; j < 4; ++j) {
        *(float4*)&Y[r0 * 64 + quad * 16 + j * 4] = y0[j];
        if (DUAL) *(float4*)&Z[r0 * 64 + quad * 16 + j * 4] = z0[j];
      }
    }
  }
  if (r1 < NN) {
    if (SCALE) {
      float s = scale[r1];
#pragma unroll
      for (int j = 0; j < 4; ++j) {
        float4 v = y1[j];
        v.x *= s; v.y *= s; v.z *= s; v.w *= s;
        *(float4*)&Y[r1 * 64 + quad * 16 + j * 4] = v;
        *(float4*)&Z[r1 * 64 + quad * 16 + j * 4] = v;
      }
    } else {
#pragma unroll
      for (int j = 0; j < 4; ++j) {
        *(float4*)&Y[r1 * 64 + quad * 16 + j * 4] = y1[j];
        if (DUAL) *(float4*)&Z[r1 * 64 + quad * 16 + j * 4] = z1[j];
      }
    }
  }
}

// one wave per node: Z[node][lane] += sum_{e in CSR[node]} Y[src_e][lane]
__global__ __launch_bounds__(256) void k_gather(const int* __restrict__ row_ptr,
    const int* __restrict__ csr, const float* __restrict__ Y, float* __restrict__ Z)
{
  int w = blockIdx.x * 4 + (threadIdx.x >> 6);
  int lane = threadIdx.x & 63;
  if (w >= NN) return;
  int beg = row_ptr[w];
  int end = row_ptr[w + 1];
  float acc = 0.f;
  int i = beg;
  for (; i + 2 <= end; i += 2) {
    int s0 = csr[i];
    int s1 = csr[i + 1];
    float a = Y[s0 * 64 + lane];
    float b = Y[s1 * 64 + lane];
    acc += a + b;
  }
  if (i < end) acc += Y[csr[i] * 64 + lane];
  Z[w * 64 + lane] += acc;
}

// out[n][c] = dinv[n] * dot(T[n], Wlin[:,c]) + cvec[c]
__global__ __launch_bounds__(256) void k_head(const float* __restrict__ T,
    const float* __restrict__ dinv, const float* __restrict__ Wlin,
    const float* __restrict__ cvec, float* __restrict__ out)
{
  __shared__ float sW[64 * 10];
  __shared__ float sc[10];
  int tid = threadIdx.x;
  if (tid < 10) sc[tid] = cvec[tid];
  for (int i = tid; i < 640; i += 256) sW[i] = Wlin[i];
  __syncthreads();
  int n = blockIdx.x * 256 + tid;
  if (n >= NN) return;
  float di = dinv[n];
  float dot[10];
#pragma unroll
  for (int c = 0; c < 10; ++c) dot[c] = 0.f;
  const float* row = &T[n * 64];
#pragma unroll
  for (int kc = 0; kc < 16; ++kc) {
    float4 v = *(const float4*)&row[kc * 4];
#pragma unroll
    for (int c = 0; c < 10; ++c) {
      dot[c] = fmaf(v.x, sW[(kc * 4 + 0) * 10 + c], dot[c]);
      dot[c] = fmaf(v.y, sW[(kc * 4 + 1) * 10 + c], dot[c]);
      dot[c] = fmaf(v.z, sW[(kc * 4 + 2) * 10 + c], dot[c]);
      dot[c] = fmaf(v.w, sW[(kc * 4 + 3) * 10 + c], dot[c]);
    }
  }
#pragma unroll
  for (int c = 0; c < 10; ++c) out[n * 10 + c] = fmaf(di, dot[c], sc[c]);
}

extern "C" void kernel_launch(void* const* d_in, const int* in_sizes, int n_in,
                              void* d_out, int out_size, void* d_ws, size_t ws_size,
                              hipStream_t stream) {
  const float* x       = (const float*)d_in[0];
  const int*   ei      = (const int*)d_in[1];
  const float* W1_rel  = (const float*)d_in[2];
  const float* b1      = (const float*)d_in[3];
  const float* W1_root = (const float*)d_in[4];
  const float* W2_rel  = (const float*)d_in[5];
  const float* b2      = (const float*)d_in[6];
  const float* W2_root = (const float*)d_in[7];
  const float* W3      = (const float*)d_in[8];
  const float* b3      = (const float*)d_in[9];
  const float* Wlin    = (const float*)d_in[10];
  const float* blin    = (const float*)d_in[11];
  float* out = (float*)d_out;

  char* ws = (char*)d_ws;
  float* Y       = (float*)(ws);                  // 25,600,000 B
  float* Z       = (float*)(ws + 25600000);       // 25,600,000 B
  float* dinv    = (float*)(ws + 51200000);       // 400,000 B
  int*   row_ptr = (int*)  (ws + 51600000);       // 400,016 B (NN+1 ints)
  int*   csr     = (int*)  (ws + 52000016);       // 3,200,000 B
  float* cvec    = (float*)(ws + 55200016);       // 40 B
  // CSR-build temporaries overlaid on Y (dead before first GEMM writes Y):
  int* cnt    = (int*)(ws);            // 400,000 B
  int* eoff   = (int*)(ws + 400000);   // 400,000 B
  int* cursor = (int*)(ws + 800000);   // 400,000 B
  int* bsum   = (int*)(ws + 1200000);  // 512 B
  int* boff   = (int*)(ws + 1200512);  // 512 B

  dim3 b256(256);
  const int gE = (NE + 255) / 256;   // 3125
  const int gN = (NN + 255) / 256;   // 391

  // ---- CSR build (graph is shared by all 3 layers) ----
  k_izero<<<gN, b256, 0, stream>>>(cnt, NN);
  k_hist<<<gE, b256, 0, stream>>>(ei, cnt);
  k_scan_block<<<NB, b256, 0, stream>>>(cnt, eoff, bsum);
  k_scan_tops<<<1, 128, 0, stream>>>(bsum, boff);
  k_scan_apply<<<gN, b256, 0, stream>>>(cnt, eoff, boff, row_ptr, cursor, dinv);
  k_fill_csr<<<gE, b256, 0, stream>>>(ei, cursor, csr);
  k_cvec<<<1, 16, 0, stream>>>(b3, Wlin, blin, cvec);

  const int gg = (NN + 127) / 128;   // 782
  const int gw = NN / 4;             // 25000 blocks, 4 waves each, 1 node/wave

  // layer 1
  k_gemm64<false, true, false><<<gg, b256, 0, stream>>>(x, W1_rel, W1_root, b1, nullptr, Y, Z);
  k_gather<<<gw, b256, 0, stream>>>(row_ptr, csr, Y, Z);

  // layer 2
  k_gemm64<true, true, false><<<gg, b256, 0, stream>>>(Z, W2_rel, W2_root, b2, nullptr, Y, Z);
  k_gather<<<gw, b256, 0, stream>>>(row_ptr, csr, Y, Z);

  // layer 3 (GCN)
  k_gemm64<true, false, true><<<gg, b256, 0, stream>>>(Z, W3, nullptr, nullptr, dinv, Y, Z);
  k_gather<<<gw, b256, 0, stream>>>(row_ptr, csr, Y, Z);

  // head
  k_head<<<gN, b256, 0, stream>>>(Z, dinv, Wlin, cvec, out);
}

// Round 4
// 315.924 us; speedup vs baseline: 2.3470x; 1.3513x over previous
//
#include <hip/hip_runtime.h>

#define NN 100000
#define NE 800000
#define SCAN_B 1024
#define NB ((NN + SCAN_B - 1) / SCAN_B)   // 98

typedef _Float16 half8 __attribute__((ext_vector_type(8)));
typedef float f32x4 __attribute__((ext_vector_type(4)));

// ---------------- CSR build ----------------
__global__ void k_izero(int* __restrict__ p, int n) {
  int i = blockIdx.x * blockDim.x + threadIdx.x;
  if (i < n) p[i] = 0;
}

__global__ void k_hist(const int* __restrict__ ei, int* __restrict__ cnt) {
  int e = blockIdx.x * blockDim.x + threadIdx.x;
  if (e < NE) atomicAdd(&cnt[ei[NE + e]], 1);
}

__global__ __launch_bounds__(256) void k_scan_block(const int* __restrict__ cnt,
    int* __restrict__ eoff, int* __restrict__ bsum) {
  __shared__ int sd[256];
  int tid = threadIdx.x;
  int base = blockIdx.x * SCAN_B + tid * 4;
  int v0 = 0, v1 = 0, v2 = 0, v3 = 0;
  if (base + 0 < NN) v0 = cnt[base + 0];
  if (base + 1 < NN) v1 = cnt[base + 1];
  if (base + 2 < NN) v2 = cnt[base + 2];
  if (base + 3 < NN) v3 = cnt[base + 3];
  int tsum = v0 + v1 + v2 + v3;
  sd[tid] = tsum;
  __syncthreads();
  int incl = tsum;
  for (int off = 1; off < 256; off <<= 1) {
    int add = (tid >= off) ? sd[tid - off] : 0;
    __syncthreads();
    incl += add;
    sd[tid] = incl;
    __syncthreads();
  }
  if (tid == 255) bsum[blockIdx.x] = incl;
  int r = incl - tsum;
  if (base + 0 < NN) eoff[base + 0] = r; r += v0;
  if (base + 1 < NN) eoff[base + 1] = r; r += v1;
  if (base + 2 < NN) eoff[base + 2] = r; r += v2;
  if (base + 3 < NN) eoff[base + 3] = r;
}

__global__ __launch_bounds__(128) void k_scan_tops(const int* __restrict__ bsum,
    int* __restrict__ boff) {
  __shared__ int sd[128];
  int tid = threadIdx.x;
  int v = (tid < NB) ? bsum[tid] : 0;
  sd[tid] = v;
  __syncthreads();
  int incl = v;
  for (int off = 1; off < 128; off <<= 1) {
    int add = (tid >= off) ? sd[tid - off] : 0;
    __syncthreads();
    incl += add;
    sd[tid] = incl;
    __syncthreads();
  }
  if (tid < NB) boff[tid] = incl - v;
}

__global__ void k_scan_apply(const int* __restrict__ cnt, const int* __restrict__ eoff,
    const int* __restrict__ boff, int* __restrict__ row_ptr, int* __restrict__ cursor,
    float* __restrict__ dinv) {
  int i = blockIdx.x * blockDim.x + threadIdx.x;
  if (i < NN) {
    int rp = boff[i >> 10] + eoff[i];
    row_ptr[i] = rp;
    cursor[i] = rp;
    dinv[i] = rsqrtf((float)cnt[i] + 1.0f);
    if (i == 0) row_ptr[NN] = NE;
  }
}

__global__ void k_fill_csr(const int* __restrict__ ei, int* __restrict__ cursor,
    int* __restrict__ csr) {
  int e = blockIdx.x * blockDim.x + threadIdx.x;
  if (e < NE) {
    int d = ei[NE + e];
    int slot = atomicAdd(&cursor[d], 1);
    csr[slot] = ei[e];
  }
}

// ---------------- small prep ----------------
__global__ void k_cvec(const float* __restrict__ b3, const float* __restrict__ Wlin,
                       const float* __restrict__ blin, float* __restrict__ cvec) {
  int c = threadIdx.x;
  if (c < 10) {
    float s = blin[c];
    for (int k = 0; k < 64; ++k) s = fmaf(b3[k], Wlin[k * 10 + c], s);
    cvec[c] = s;
  }
}

// Transpose + f16-convert the 5 weight matrices: WT[m][n*64+k] = W_m[k*64+n]
__global__ void k_prep(const float* __restrict__ W1r, const float* __restrict__ W1o,
                       const float* __restrict__ W2r, const float* __restrict__ W2o,
                       const float* __restrict__ W3, _Float16* __restrict__ WT) {
  int m = blockIdx.x;
  const float* s = (m == 0) ? W1r : (m == 1) ? W1o : (m == 2) ? W2r : (m == 3) ? W2o : W3;
  _Float16* dst = WT + m * 4096;
  for (int idx = threadIdx.x; idx < 4096; idx += 256) {
    int k = idx >> 6, n = idx & 63;
    dst[n * 64 + k] = (_Float16)s[idx];
  }
}

// ---------------- MFMA dual-GEMM ----------------
// Block: 256 thr = 4 waves; 128 rows/block; wave w -> rows w*32..w*32+31.
// DUAL : Yh = act(A)@Wa (f16) ; Z = act(A)@Wb + bias (f32)
// SCALE: Yh = Z = (act(A)@Wa) * scale[row]
template<bool RELU_IN, bool DUAL, bool SCALE>
__global__ __launch_bounds__(256) void k_gemmfma(
    const float* __restrict__ A, const _Float16* __restrict__ WTa,
    const _Float16* __restrict__ WTb, const float* __restrict__ bias,
    const float* __restrict__ scale, _Float16* __restrict__ Yh,
    float* __restrict__ Z)
{
  __shared__ _Float16 sA[128 * 64];              // 16 KB, XOR-swizzled rows
  __shared__ _Float16 sWa[64 * 64];              // 8 KB, [n][k] swizzled
  __shared__ _Float16 sWb[DUAL ? 64 * 64 : 8];

  const int tid = threadIdx.x;
  const int row0 = blockIdx.x * 128;

  // stage W tiles (global WT is f16 [n][k])
  {
    const uint4* g = (const uint4*)WTa;
#pragma unroll
    for (int i = 0; i < 2; ++i) {
      int c = tid + 256 * i;                     // 512 chunks of 16B
      int n = c >> 3, kc = c & 7;
      uint4 v = g[c];
      *(uint4*)((char*)sWa + n * 128 + ((kc * 16) ^ ((n & 7) << 4))) = v;
    }
    if (DUAL) {
      const uint4* gb = (const uint4*)WTb;
#pragma unroll
      for (int i = 0; i < 2; ++i) {
        int c = tid + 256 * i;
        int n = c >> 3, kc = c & 7;
        uint4 v = gb[c];
        *(uint4*)((char*)sWb + n * 128 + ((kc * 16) ^ ((n & 7) << 4))) = v;
      }
    }
  }

  // stage A: f32 global -> relu -> f16 LDS (swizzled)
#pragma unroll
  for (int i = 0; i < 4; ++i) {
    int c = tid + 256 * i;                       // 1024 chunks (row, 8 cols)
    int row = c >> 3, kc = c & 7;
    int grow = row0 + row;
    float4 v0 = make_float4(0.f, 0.f, 0.f, 0.f), v1 = v0;
    if (grow < NN) {
      const float4* ap = (const float4*)(A + grow * 64);
      v0 = ap[kc * 2]; v1 = ap[kc * 2 + 1];
    }
    if (RELU_IN) {
      v0.x = fmaxf(v0.x, 0.f); v0.y = fmaxf(v0.y, 0.f);
      v0.z = fmaxf(v0.z, 0.f); v0.w = fmaxf(v0.w, 0.f);
      v1.x = fmaxf(v1.x, 0.f); v1.y = fmaxf(v1.y, 0.f);
      v1.z = fmaxf(v1.z, 0.f); v1.w = fmaxf(v1.w, 0.f);
    }
    half8 h;
    h[0] = (_Float16)v0.x; h[1] = (_Float16)v0.y;
    h[2] = (_Float16)v0.z; h[3] = (_Float16)v0.w;
    h[4] = (_Float16)v1.x; h[5] = (_Float16)v1.y;
    h[6] = (_Float16)v1.z; h[7] = (_Float16)v1.w;
    *(half8*)((char*)sA + row * 128 + ((kc * 16) ^ ((row & 7) << 4))) = h;
  }
  __syncthreads();

  const int l = tid & 63, w = tid >> 6;
  const int lm = l & 15, lh = l >> 4;

  // A fragments: lane holds A[rt*16+lm][kb*32 + lh*8 + i]
  half8 a[2][2];
#pragma unroll
  for (int rt = 0; rt < 2; ++rt)
#pragma unroll
    for (int kb = 0; kb < 2; ++kb) {
      int row = w * 32 + rt * 16 + lm;
      a[rt][kb] = *(half8*)((char*)sA + row * 128 + ((kb * 64 + lh * 16) ^ ((row & 7) << 4)));
    }

  f32x4 accA[2][4], accB[2][4];
#pragma unroll
  for (int rt = 0; rt < 2; ++rt)
#pragma unroll
    for (int nt = 0; nt < 4; ++nt) {
      accA[rt][nt] = (f32x4){0.f, 0.f, 0.f, 0.f};
      accB[rt][nt] = (f32x4){0.f, 0.f, 0.f, 0.f};
    }

#pragma unroll
  for (int nt = 0; nt < 4; ++nt) {
    int n = nt * 16 + lm;
#pragma unroll
    for (int kb = 0; kb < 2; ++kb) {
      int off = n * 128 + ((kb * 64 + lh * 16) ^ ((n & 7) << 4));
      half8 ba = *(half8*)((char*)sWa + off);
#pragma unroll
      for (int rt = 0; rt < 2; ++rt)
        accA[rt][nt] = __builtin_amdgcn_mfma_f32_16x16x32_f16(a[rt][kb], ba, accA[rt][nt], 0, 0, 0);
      if (DUAL) {
        half8 bb = *(half8*)((char*)sWb + off);
#pragma unroll
        for (int rt = 0; rt < 2; ++rt)
          accB[rt][nt] = __builtin_amdgcn_mfma_f32_16x16x32_f16(a[rt][kb], bb, accB[rt][nt], 0, 0, 0);
      }
    }
  }

  // epilogue: C/D map col=lane&15, row=(lane>>4)*4+reg
#pragma unroll
  for (int rt = 0; rt < 2; ++rt) {
#pragma unroll
    for (int nt = 0; nt < 4; ++nt) {
      int col = nt * 16 + lm;
      float bv = DUAL ? bias[col] : 0.f;
#pragma unroll
      for (int r = 0; r < 4; ++r) {
        int row = row0 + w * 32 + rt * 16 + lh * 4 + r;
        if (row < NN) {
          float va = accA[rt][nt][r];
          if (SCALE) {
            float s = scale[row];
            va *= s;
            Yh[row * 64 + col] = (_Float16)va;
            Z[row * 64 + col] = va;
          } else {
            Yh[row * 64 + col] = (_Float16)va;
            Z[row * 64 + col] = accB[rt][nt][r] + bv;
          }
        }
      }
    }
  }
}

// ---------------- gather (f16 Y rows, non-atomic) ----------------
// one node per wave; lanes split into 2 halves processing interleaved edges;
// each lane covers 2 columns (packed f16 pair).
__global__ __launch_bounds__(256) void k_gather(const int* __restrict__ row_ptr,
    const int* __restrict__ csr, const _Float16* __restrict__ Yh, float* __restrict__ Z)
{
  int node = blockIdx.x * 4 + (threadIdx.x >> 6);
  int l = threadIdx.x & 63;
  int half = l >> 5, cp = l & 31;
  int beg = row_ptr[node], end = row_ptr[node + 1];
  float a0 = 0.f, a1 = 0.f;
  for (int i = beg + half; i < end; i += 2) {
    int s = csr[i];
    unsigned v = *(const unsigned*)(Yh + s * 64 + cp * 2);
    union { unsigned u; _Float16 h[2]; } cv; cv.u = v;
    a0 += (float)cv.h[0];
    a1 += (float)cv.h[1];
  }
  a0 += __shfl_xor(a0, 32);
  a1 += __shfl_xor(a1, 32);
  if (half == 0) {
    float2 z = *(float2*)(Z + node * 64 + cp * 2);
    z.x += a0; z.y += a1;
    *(float2*)(Z + node * 64 + cp * 2) = z;
  }
}

// ---------------- head ----------------
__global__ __launch_bounds__(256) void k_head(const float* __restrict__ T,
    const float* __restrict__ dinv, const float* __restrict__ Wlin,
    const float* __restrict__ cvec, float* __restrict__ out)
{
  __shared__ float sW[64 * 10];
  __shared__ float sc[10];
  int tid = threadIdx.x;
  if (tid < 10) sc[tid] = cvec[tid];
  for (int i = tid; i < 640; i += 256) sW[i] = Wlin[i];
  __syncthreads();
  int n = blockIdx.x * 256 + tid;
  if (n >= NN) return;
  float di = dinv[n];
  float dot[10];
#pragma unroll
  for (int c = 0; c < 10; ++c) dot[c] = 0.f;
  const float* row = &T[n * 64];
#pragma unroll
  for (int kc = 0; kc < 16; ++kc) {
    float4 v = *(const float4*)&row[kc * 4];
#pragma unroll
    for (int c = 0; c < 10; ++c) {
      dot[c] = fmaf(v.x, sW[(kc * 4 + 0) * 10 + c], dot[c]);
      dot[c] = fmaf(v.y, sW[(kc * 4 + 1) * 10 + c], dot[c]);
      dot[c] = fmaf(v.z, sW[(kc * 4 + 2) * 10 + c], dot[c]);
      dot[c] = fmaf(v.w, sW[(kc * 4 + 3) * 10 + c], dot[c]);
    }
  }
#pragma unroll
  for (int c = 0; c < 10; ++c) out[n * 10 + c] = fmaf(di, dot[c], sc[c]);
}

extern "C" void kernel_launch(void* const* d_in, const int* in_sizes, int n_in,
                              void* d_out, int out_size, void* d_ws, size_t ws_size,
                              hipStream_t stream) {
  const float* x       = (const float*)d_in[0];
  const int*   ei      = (const int*)d_in[1];
  const float* W1_rel  = (const float*)d_in[2];
  const float* b1      = (const float*)d_in[3];
  const float* W1_root = (const float*)d_in[4];
  const float* W2_rel  = (const float*)d_in[5];
  const float* b2      = (const float*)d_in[6];
  const float* W2_root = (const float*)d_in[7];
  const float* W3      = (const float*)d_in[8];
  const float* b3      = (const float*)d_in[9];
  const float* Wlin    = (const float*)d_in[10];
  const float* blin    = (const float*)d_in[11];
  float* out = (float*)d_out;

  char* ws = (char*)d_ws;
  _Float16* Yh     = (_Float16*)(ws);             // 12,800,000 B
  float*    Z      = (float*)(ws + 12800000);     // 25,600,000 B
  float*    dinv   = (float*)(ws + 38400000);     //    400,000 B
  int*      row_ptr= (int*)  (ws + 38800000);     //    400,004 B
  int*      csr    = (int*)  (ws + 39200016);     //  3,200,000 B
  _Float16* WT     = (_Float16*)(ws + 42400016);  //     40,960 B (5 mats)
  float*    cvec   = (float*)(ws + 42441024);     //         40 B
  // CSR-build temporaries overlaid on Yh (dead before gemm1 writes Yh):
  int* cnt    = (int*)(ws);
  int* eoff   = (int*)(ws + 400000);
  int* cursor = (int*)(ws + 800000);
  int* bsum   = (int*)(ws + 1200000);
  int* boff   = (int*)(ws + 1200512);

  dim3 b256(256);
  const int gE = (NE + 255) / 256;   // 3125
  const int gN = (NN + 255) / 256;   // 391

  k_izero<<<gN, b256, 0, stream>>>(cnt, NN);
  k_hist<<<gE, b256, 0, stream>>>(ei, cnt);
  k_scan_block<<<NB, b256, 0, stream>>>(cnt, eoff, bsum);
  k_scan_tops<<<1, 128, 0, stream>>>(bsum, boff);
  k_scan_apply<<<gN, b256, 0, stream>>>(cnt, eoff, boff, row_ptr, cursor, dinv);
  k_fill_csr<<<gE, b256, 0, stream>>>(ei, cursor, csr);
  k_cvec<<<1, 16, 0, stream>>>(b3, Wlin, blin, cvec);
  k_prep<<<5, b256, 0, stream>>>(W1_rel, W1_root, W2_rel, W2_root, W3, WT);

  const int gg = (NN + 127) / 128;   // 782
  const int gw = NN / 4;             // 25000

  // layer 1
  k_gemmfma<false, true, false><<<gg, b256, 0, stream>>>(x, WT, WT + 4096, b1, nullptr, Yh, Z);
  k_gather<<<gw, b256, 0, stream>>>(row_ptr, csr, Yh, Z);

  // layer 2
  k_gemmfma<true, true, false><<<gg, b256, 0, stream>>>(Z, WT + 2 * 4096, WT + 3 * 4096, b2, nullptr, Yh, Z);
  k_gather<<<gw, b256, 0, stream>>>(row_ptr, csr, Yh, Z);

  // layer 3 (GCN)
  k_gemmfma<true, false, true><<<gg, b256, 0, stream>>>(Z, WT + 4 * 4096, nullptr, nullptr, dinv, Yh, Z);
  k_gather<<<gw, b256, 0, stream>>>(row_ptr, csr, Yh, Z);

  // head
  k_head<<<gN, b256, 0, stream>>>(Z, dinv, Wlin, cvec, out);
}

// Round 5
// 263.145 us; speedup vs baseline: 2.8177x; 1.2006x over previous
//
#include <hip/hip_runtime.h>

#define NN 100000
#define NE 800000
#define SCAN_B 1024
#define NB ((NN + SCAN_B - 1) / SCAN_B)   // 98

typedef _Float16 half8 __attribute__((ext_vector_type(8)));
typedef float f32x4 __attribute__((ext_vector_type(4)));

// ---------------- CSR build ----------------
__global__ void k_izero(int* __restrict__ p, int n) {
  int i = blockIdx.x * blockDim.x + threadIdx.x;
  if (i < n) p[i] = 0;
}

__global__ void k_hist(const int* __restrict__ ei, int* __restrict__ cnt) {
  int e = blockIdx.x * blockDim.x + threadIdx.x;
  if (e < NE) atomicAdd(&cnt[ei[NE + e]], 1);
}

__global__ __launch_bounds__(256) void k_scan_block(const int* __restrict__ cnt,
    int* __restrict__ eoff, int* __restrict__ bsum) {
  __shared__ int sd[256];
  int tid = threadIdx.x;
  int base = blockIdx.x * SCAN_B + tid * 4;
  int v0 = 0, v1 = 0, v2 = 0, v3 = 0;
  if (base + 0 < NN) v0 = cnt[base + 0];
  if (base + 1 < NN) v1 = cnt[base + 1];
  if (base + 2 < NN) v2 = cnt[base + 2];
  if (base + 3 < NN) v3 = cnt[base + 3];
  int tsum = v0 + v1 + v2 + v3;
  sd[tid] = tsum;
  __syncthreads();
  int incl = tsum;
  for (int off = 1; off < 256; off <<= 1) {
    int add = (tid >= off) ? sd[tid - off] : 0;
    __syncthreads();
    incl += add;
    sd[tid] = incl;
    __syncthreads();
  }
  if (tid == 255) bsum[blockIdx.x] = incl;
  int r = incl - tsum;
  if (base + 0 < NN) eoff[base + 0] = r; r += v0;
  if (base + 1 < NN) eoff[base + 1] = r; r += v1;
  if (base + 2 < NN) eoff[base + 2] = r; r += v2;
  if (base + 3 < NN) eoff[base + 3] = r;
}

__global__ __launch_bounds__(128) void k_scan_tops(const int* __restrict__ bsum,
    int* __restrict__ boff) {
  __shared__ int sd[128];
  int tid = threadIdx.x;
  int v = (tid < NB) ? bsum[tid] : 0;
  sd[tid] = v;
  __syncthreads();
  int incl = v;
  for (int off = 1; off < 128; off <<= 1) {
    int add = (tid >= off) ? sd[tid - off] : 0;
    __syncthreads();
    incl += add;
    sd[tid] = incl;
    __syncthreads();
  }
  if (tid < NB) boff[tid] = incl - v;
}

__global__ void k_scan_apply(const int* __restrict__ cnt, const int* __restrict__ eoff,
    const int* __restrict__ boff, int* __restrict__ row_ptr, int* __restrict__ cursor,
    float* __restrict__ dinv) {
  int i = blockIdx.x * blockDim.x + threadIdx.x;
  if (i < NN) {
    int rp = boff[i >> 10] + eoff[i];
    row_ptr[i] = rp;
    cursor[i] = rp;
    dinv[i] = rsqrtf((float)cnt[i] + 1.0f);
    if (i == 0) row_ptr[NN] = NE;
  }
}

__global__ void k_fill_csr(const int* __restrict__ ei, int* __restrict__ cursor,
    int* __restrict__ csr) {
  int e = blockIdx.x * blockDim.x + threadIdx.x;
  if (e < NE) {
    int d = ei[NE + e];
    int slot = atomicAdd(&cursor[d], 1);
    csr[slot] = ei[e];
  }
}

// ---------------- small prep ----------------
__global__ void k_cvec(const float* __restrict__ b3, const float* __restrict__ Wlin,
                       const float* __restrict__ blin, float* __restrict__ cvec) {
  int c = threadIdx.x;
  if (c < 10) {
    float s = blin[c];
    for (int k = 0; k < 64; ++k) s = fmaf(b3[k], Wlin[k * 10 + c], s);
    cvec[c] = s;
  }
}

// Transpose + f16-convert the 5 weight matrices: WT[m][n*64+k] = W_m[k*64+n]
__global__ void k_prep(const float* __restrict__ W1r, const float* __restrict__ W1o,
                       const float* __restrict__ W2r, const float* __restrict__ W2o,
                       const float* __restrict__ W3, _Float16* __restrict__ WT) {
  int m = blockIdx.x;
  const float* s = (m == 0) ? W1r : (m == 1) ? W1o : (m == 2) ? W2r : (m == 3) ? W2o : W3;
  _Float16* dst = WT + m * 4096;
  for (int idx = threadIdx.x; idx < 4096; idx += 256) {
    int k = idx >> 6, n = idx & 63;
    dst[n * 64 + k] = (_Float16)s[idx];
  }
}

// ---------------- MFMA dual-GEMM ----------------
template<bool RELU_IN, bool DUAL, bool SCALE>
__global__ __launch_bounds__(256) void k_gemmfma(
    const float* __restrict__ A, const _Float16* __restrict__ WTa,
    const _Float16* __restrict__ WTb, const float* __restrict__ bias,
    const float* __restrict__ scale, _Float16* __restrict__ Yh,
    float* __restrict__ Z)
{
  __shared__ _Float16 sA[128 * 64];              // 16 KB, XOR-swizzled rows
  __shared__ _Float16 sWa[64 * 64];              // 8 KB, [n][k] swizzled
  __shared__ _Float16 sWb[DUAL ? 64 * 64 : 8];

  const int tid = threadIdx.x;
  const int row0 = blockIdx.x * 128;

  {
    const uint4* g = (const uint4*)WTa;
#pragma unroll
    for (int i = 0; i < 2; ++i) {
      int c = tid + 256 * i;
      int n = c >> 3, kc = c & 7;
      uint4 v = g[c];
      *(uint4*)((char*)sWa + n * 128 + ((kc * 16) ^ ((n & 7) << 4))) = v;
    }
    if (DUAL) {
      const uint4* gb = (const uint4*)WTb;
#pragma unroll
      for (int i = 0; i < 2; ++i) {
        int c = tid + 256 * i;
        int n = c >> 3, kc = c & 7;
        uint4 v = gb[c];
        *(uint4*)((char*)sWb + n * 128 + ((kc * 16) ^ ((n & 7) << 4))) = v;
      }
    }
  }

#pragma unroll
  for (int i = 0; i < 4; ++i) {
    int c = tid + 256 * i;
    int row = c >> 3, kc = c & 7;
    int grow = row0 + row;
    float4 v0 = make_float4(0.f, 0.f, 0.f, 0.f), v1 = v0;
    if (grow < NN) {
      const float4* ap = (const float4*)(A + grow * 64);
      v0 = ap[kc * 2]; v1 = ap[kc * 2 + 1];
    }
    if (RELU_IN) {
      v0.x = fmaxf(v0.x, 0.f); v0.y = fmaxf(v0.y, 0.f);
      v0.z = fmaxf(v0.z, 0.f); v0.w = fmaxf(v0.w, 0.f);
      v1.x = fmaxf(v1.x, 0.f); v1.y = fmaxf(v1.y, 0.f);
      v1.z = fmaxf(v1.z, 0.f); v1.w = fmaxf(v1.w, 0.f);
    }
    half8 h;
    h[0] = (_Float16)v0.x; h[1] = (_Float16)v0.y;
    h[2] = (_Float16)v0.z; h[3] = (_Float16)v0.w;
    h[4] = (_Float16)v1.x; h[5] = (_Float16)v1.y;
    h[6] = (_Float16)v1.z; h[7] = (_Float16)v1.w;
    *(half8*)((char*)sA + row * 128 + ((kc * 16) ^ ((row & 7) << 4))) = h;
  }
  __syncthreads();

  const int l = tid & 63, w = tid >> 6;
  const int lm = l & 15, lh = l >> 4;

  half8 a[2][2];
#pragma unroll
  for (int rt = 0; rt < 2; ++rt)
#pragma unroll
    for (int kb = 0; kb < 2; ++kb) {
      int row = w * 32 + rt * 16 + lm;
      a[rt][kb] = *(half8*)((char*)sA + row * 128 + ((kb * 64 + lh * 16) ^ ((row & 7) << 4)));
    }

  f32x4 accA[2][4], accB[2][4];
#pragma unroll
  for (int rt = 0; rt < 2; ++rt)
#pragma unroll
    for (int nt = 0; nt < 4; ++nt) {
      accA[rt][nt] = (f32x4){0.f, 0.f, 0.f, 0.f};
      accB[rt][nt] = (f32x4){0.f, 0.f, 0.f, 0.f};
    }

#pragma unroll
  for (int nt = 0; nt < 4; ++nt) {
    int n = nt * 16 + lm;
#pragma unroll
    for (int kb = 0; kb < 2; ++kb) {
      int off = n * 128 + ((kb * 64 + lh * 16) ^ ((n & 7) << 4));
      half8 ba = *(half8*)((char*)sWa + off);
#pragma unroll
      for (int rt = 0; rt < 2; ++rt)
        accA[rt][nt] = __builtin_amdgcn_mfma_f32_16x16x32_f16(a[rt][kb], ba, accA[rt][nt], 0, 0, 0);
      if (DUAL) {
        half8 bb = *(half8*)((char*)sWb + off);
#pragma unroll
        for (int rt = 0; rt < 2; ++rt)
          accB[rt][nt] = __builtin_amdgcn_mfma_f32_16x16x32_f16(a[rt][kb], bb, accB[rt][nt], 0, 0, 0);
      }
    }
  }

#pragma unroll
  for (int rt = 0; rt < 2; ++rt) {
#pragma unroll
    for (int nt = 0; nt < 4; ++nt) {
      int col = nt * 16 + lm;
      float bv = DUAL ? bias[col] : 0.f;
#pragma unroll
      for (int r = 0; r < 4; ++r) {
        int row = row0 + w * 32 + rt * 16 + lh * 4 + r;
        if (row < NN) {
          float va = accA[rt][nt][r];
          if (SCALE) {
            float s = scale[row];
            va *= s;
            Yh[row * 64 + col] = (_Float16)va;
            Z[row * 64 + col] = va;
          } else {
            Yh[row * 64 + col] = (_Float16)va;
            Z[row * 64 + col] = accB[rt][nt][r] + bv;
          }
        }
      }
    }
  }
}

// ---------------- gather: 1 node/wave, 8 edge-groups of 8 lanes ----------------
// Each 8-lane group reads a full 128B Yh row (lane = 8 f16); 8 edges in flight.
// Cross-group reduce via 3x shfl_xor; group 0 does the Z += write (256B).
__global__ __launch_bounds__(256) void k_gather(const int* __restrict__ row_ptr,
    const int* __restrict__ csr, const _Float16* __restrict__ Yh, float* __restrict__ Z)
{
  int node = blockIdx.x * 4 + (threadIdx.x >> 6);
  int l = threadIdx.x & 63;
  int g = l >> 3;        // edge group 0..7
  int c8 = l & 7;        // column chunk: cols c8*8 .. c8*8+7
  int beg = row_ptr[node], end = row_ptr[node + 1];

  float acc[8];
#pragma unroll
  for (int j = 0; j < 8; ++j) acc[j] = 0.f;

  for (int i = beg + g; i < end; i += 8) {
    int s = csr[i];
    half8 v = *(const half8*)(Yh + s * 64 + c8 * 8);
#pragma unroll
    for (int j = 0; j < 8; ++j) acc[j] += (float)v[j];
  }

#pragma unroll
  for (int off = 8; off < 64; off <<= 1) {
#pragma unroll
    for (int j = 0; j < 8; ++j) acc[j] += __shfl_xor(acc[j], off);
  }

  if (g == 0) {
    float4 z0 = *(float4*)(Z + node * 64 + c8 * 8);
    float4 z1 = *(float4*)(Z + node * 64 + c8 * 8 + 4);
    z0.x += acc[0]; z0.y += acc[1]; z0.z += acc[2]; z0.w += acc[3];
    z1.x += acc[4]; z1.y += acc[5]; z1.z += acc[6]; z1.w += acc[7];
    *(float4*)(Z + node * 64 + c8 * 8) = z0;
    *(float4*)(Z + node * 64 + c8 * 8 + 4) = z1;
  }
}

// ---------------- head ----------------
__global__ __launch_bounds__(256) void k_head(const float* __restrict__ T,
    const float* __restrict__ dinv, const float* __restrict__ Wlin,
    const float* __restrict__ cvec, float* __restrict__ out)
{
  __shared__ float sW[64 * 10];
  __shared__ float sc[10];
  int tid = threadIdx.x;
  if (tid < 10) sc[tid] = cvec[tid];
  for (int i = tid; i < 640; i += 256) sW[i] = Wlin[i];
  __syncthreads();
  int n = blockIdx.x * 256 + tid;
  if (n >= NN) return;
  float di = dinv[n];
  float dot[10];
#pragma unroll
  for (int c = 0; c < 10; ++c) dot[c] = 0.f;
  const float* row = &T[n * 64];
#pragma unroll
  for (int kc = 0; kc < 16; ++kc) {
    float4 v = *(const float4*)&row[kc * 4];
#pragma unroll
    for (int c = 0; c < 10; ++c) {
      dot[c] = fmaf(v.x, sW[(kc * 4 + 0) * 10 + c], dot[c]);
      dot[c] = fmaf(v.y, sW[(kc * 4 + 1) * 10 + c], dot[c]);
      dot[c] = fmaf(v.z, sW[(kc * 4 + 2) * 10 + c], dot[c]);
      dot[c] = fmaf(v.w, sW[(kc * 4 + 3) * 10 + c], dot[c]);
    }
  }
#pragma unroll
  for (int c = 0; c < 10; ++c) out[n * 10 + c] = fmaf(di, dot[c], sc[c]);
}

extern "C" void kernel_launch(void* const* d_in, const int* in_sizes, int n_in,
                              void* d_out, int out_size, void* d_ws, size_t ws_size,
                              hipStream_t stream) {
  const float* x       = (const float*)d_in[0];
  const int*   ei      = (const int*)d_in[1];
  const float* W1_rel  = (const float*)d_in[2];
  const float* b1      = (const float*)d_in[3];
  const float* W1_root = (const float*)d_in[4];
  const float* W2_rel  = (const float*)d_in[5];
  const float* b2      = (const float*)d_in[6];
  const float* W2_root = (const float*)d_in[7];
  const float* W3      = (const float*)d_in[8];
  const float* b3      = (const float*)d_in[9];
  const float* Wlin    = (const float*)d_in[10];
  const float* blin    = (const float*)d_in[11];
  float* out = (float*)d_out;

  char* ws = (char*)d_ws;
  _Float16* Yh     = (_Float16*)(ws);             // 12,800,000 B
  float*    Z      = (float*)(ws + 12800000);     // 25,600,000 B
  float*    dinv   = (float*)(ws + 38400000);     //    400,000 B
  int*      row_ptr= (int*)  (ws + 38800000);     //    400,004 B
  int*      csr    = (int*)  (ws + 39200016);     //  3,200,000 B
  _Float16* WT     = (_Float16*)(ws + 42400016);  //     40,960 B (5 mats)
  float*    cvec   = (float*)(ws + 42441024);     //         40 B
  // CSR-build temporaries overlaid on Yh (dead before gemm1 writes Yh):
  int* cnt    = (int*)(ws);
  int* eoff   = (int*)(ws + 400000);
  int* cursor = (int*)(ws + 800000);
  int* bsum   = (int*)(ws + 1200000);
  int* boff   = (int*)(ws + 1200512);

  dim3 b256(256);
  const int gE = (NE + 255) / 256;   // 3125
  const int gN = (NN + 255) / 256;   // 391

  k_izero<<<gN, b256, 0, stream>>>(cnt, NN);
  k_hist<<<gE, b256, 0, stream>>>(ei, cnt);
  k_scan_block<<<NB, b256, 0, stream>>>(cnt, eoff, bsum);
  k_scan_tops<<<1, 128, 0, stream>>>(bsum, boff);
  k_scan_apply<<<gN, b256, 0, stream>>>(cnt, eoff, boff, row_ptr, cursor, dinv);
  k_fill_csr<<<gE, b256, 0, stream>>>(ei, cursor, csr);
  k_cvec<<<1, 16, 0, stream>>>(b3, Wlin, blin, cvec);
  k_prep<<<5, b256, 0, stream>>>(W1_rel, W1_root, W2_rel, W2_root, W3, WT);

  const int gg = (NN + 127) / 128;   // 782
  const int gw = NN / 4;             // 25000

  // layer 1
  k_gemmfma<false, true, false><<<gg, b256, 0, stream>>>(x, WT, WT + 4096, b1, nullptr, Yh, Z);
  k_gather<<<gw, b256, 0, stream>>>(row_ptr, csr, Yh, Z);

  // layer 2
  k_gemmfma<true, true, false><<<gg, b256, 0, stream>>>(Z, WT + 2 * 4096, WT + 3 * 4096, b2, nullptr, Yh, Z);
  k_gather<<<gw, b256, 0, stream>>>(row_ptr, csr, Yh, Z);

  // layer 3 (GCN)
  k_gemmfma<true, false, true><<<gg, b256, 0, stream>>>(Z, WT + 4 * 4096, nullptr, nullptr, dinv, Yh, Z);
  k_gather<<<gw, b256, 0, stream>>>(row_ptr, csr, Yh, Z);

  // head
  k_head<<<gN, b256, 0, stream>>>(Z, dinv, Wlin, cvec, out);
}

// Round 6
// 204.142 us; speedup vs baseline: 3.6322x; 1.2890x over previous
//
#include <hip/hip_runtime.h>

#define NN 100000
#define NE 800000
#define BSH 9                 // 512 nodes per bucket
#define BSZ (1 << BSH)
#define NBUK ((NN + BSZ - 1) / BSZ)    // 196
#define CAP 5120              // bucket capacity (mean 4096, 8+ sigma margin)
#define ECHUNK 4096
#define GRID_C ((NE + ECHUNK - 1) / ECHUNK)  // 196

typedef _Float16 half8 __attribute__((ext_vector_type(8)));
typedef float f32x4 __attribute__((ext_vector_type(4)));

// ---------------- bucketed CSR build ----------------
// Phase C: bin edges into dst-buckets; packed entry = src | dst_local<<17
__global__ __launch_bounds__(256) void k_bucket(const int* __restrict__ ei,
    int* __restrict__ bucket_cnt, int* __restrict__ ebuf) {
  __shared__ int h[256];
  __shared__ int cur[256];
  const int tid = threadIdx.x;
  h[tid] = 0;
  __syncthreads();

  const int e0 = blockIdx.x * ECHUNK;
  int pk[16], bk[16];
#pragma unroll
  for (int i = 0; i < 16; ++i) {
    int e = e0 + i * 256 + tid;
    if (e < NE) {
      int src = ei[e];
      int dst = ei[NE + e];
      int b = dst >> BSH;
      pk[i] = src | ((dst & (BSZ - 1)) << 17);
      bk[i] = b;
      atomicAdd(&h[b], 1);
    } else bk[i] = -1;
  }
  __syncthreads();
  cur[tid] = (tid < NBUK && h[tid] > 0) ? atomicAdd(&bucket_cnt[tid], h[tid]) : 0;
  __syncthreads();
#pragma unroll
  for (int i = 0; i < 16; ++i) {
    if (bk[i] >= 0) {
      int slot = atomicAdd(&cur[bk[i]], 1);
      ebuf[bk[i] * CAP + slot] = pk[i];
    }
  }
}

// Phase D: per bucket -> per-node row spans (int2), dinv, csr srcs
__global__ __launch_bounds__(256) void k_csr_build(const int* __restrict__ bucket_cnt,
    const int* __restrict__ ebuf, int2* __restrict__ rp2, int* __restrict__ csr,
    float* __restrict__ dinv) {
  __shared__ int h[BSZ];
  __shared__ int loff[BSZ];
  __shared__ int cur[BSZ];
  __shared__ int sd[256];
  const int tid = threadIdx.x;
  const int b = blockIdx.x;
  h[tid] = 0; h[tid + 256] = 0;
  __syncthreads();

  const int n = bucket_cnt[b];
  const int ebase = b * CAP;
  for (int i = tid; i < n; i += 256)
    atomicAdd(&h[ebuf[ebase + i] >> 17], 1);
  __syncthreads();

  // exclusive scan over 512 entries: thread owns pair (2t, 2t+1)
  int a0 = h[2 * tid], a1 = h[2 * tid + 1];
  int ps = a0 + a1;
  sd[tid] = ps;
  __syncthreads();
  int incl = ps;
  for (int o = 1; o < 256; o <<= 1) {
    int add = (tid >= o) ? sd[tid - o] : 0;
    __syncthreads();
    incl += add;
    sd[tid] = incl;
    __syncthreads();
  }
  int ex = incl - ps;
  loff[2 * tid] = ex;
  loff[2 * tid + 1] = ex + a0;
  cur[2 * tid] = ex;
  cur[2 * tid + 1] = ex + a0;
  __syncthreads();

  const int node0 = b * BSZ;
#pragma unroll
  for (int t = 0; t < 2; ++t) {
    int j = tid + t * 256;
    int node = node0 + j;
    if (node < NN) {
      int beg = ebase + loff[j];
      rp2[node] = make_int2(beg, beg + h[j]);
      dinv[node] = rsqrtf((float)h[j] + 1.0f);
    }
  }

  for (int i = tid; i < n; i += 256) {
    int v = ebuf[ebase + i];
    int dl = v >> 17;
    int slot = atomicAdd(&cur[dl], 1);
    csr[ebase + slot] = v & 0x1FFFF;
  }
}

// ---------------- small prep ----------------
__global__ void k_cvec(const float* __restrict__ b3, const float* __restrict__ Wlin,
                       const float* __restrict__ blin, float* __restrict__ cvec) {
  int c = threadIdx.x;
  if (c < 10) {
    float s = blin[c];
    for (int k = 0; k < 64; ++k) s = fmaf(b3[k], Wlin[k * 10 + c], s);
    cvec[c] = s;
  }
}

// Transpose + f16-convert the 5 weight matrices: WT[m][n*64+k] = W_m[k*64+n]
__global__ void k_prep(const float* __restrict__ W1r, const float* __restrict__ W1o,
                       const float* __restrict__ W2r, const float* __restrict__ W2o,
                       const float* __restrict__ W3, _Float16* __restrict__ WT) {
  int m = blockIdx.x;
  const float* s = (m == 0) ? W1r : (m == 1) ? W1o : (m == 2) ? W2r : (m == 3) ? W2o : W3;
  _Float16* dst = WT + m * 4096;
  for (int idx = threadIdx.x; idx < 4096; idx += 256) {
    int k = idx >> 6, n = idx & 63;
    dst[n * 64 + k] = (_Float16)s[idx];
  }
}

// ---------------- MFMA dual-GEMM ----------------
template<bool RELU_IN, bool DUAL, bool SCALE>
__global__ __launch_bounds__(256) void k_gemmfma(
    const float* __restrict__ A, const _Float16* __restrict__ WTa,
    const _Float16* __restrict__ WTb, const float* __restrict__ bias,
    const float* __restrict__ scale, _Float16* __restrict__ Yh,
    float* __restrict__ Z)
{
  __shared__ _Float16 sA[128 * 64];
  __shared__ _Float16 sWa[64 * 64];
  __shared__ _Float16 sWb[DUAL ? 64 * 64 : 8];

  const int tid = threadIdx.x;
  const int row0 = blockIdx.x * 128;

  {
    const uint4* g = (const uint4*)WTa;
#pragma unroll
    for (int i = 0; i < 2; ++i) {
      int c = tid + 256 * i;
      int n = c >> 3, kc = c & 7;
      uint4 v = g[c];
      *(uint4*)((char*)sWa + n * 128 + ((kc * 16) ^ ((n & 7) << 4))) = v;
    }
    if (DUAL) {
      const uint4* gb = (const uint4*)WTb;
#pragma unroll
      for (int i = 0; i < 2; ++i) {
        int c = tid + 256 * i;
        int n = c >> 3, kc = c & 7;
        uint4 v = gb[c];
        *(uint4*)((char*)sWb + n * 128 + ((kc * 16) ^ ((n & 7) << 4))) = v;
      }
    }
  }

#pragma unroll
  for (int i = 0; i < 4; ++i) {
    int c = tid + 256 * i;
    int row = c >> 3, kc = c & 7;
    int grow = row0 + row;
    float4 v0 = make_float4(0.f, 0.f, 0.f, 0.f), v1 = v0;
    if (grow < NN) {
      const float4* ap = (const float4*)(A + grow * 64);
      v0 = ap[kc * 2]; v1 = ap[kc * 2 + 1];
    }
    if (RELU_IN) {
      v0.x = fmaxf(v0.x, 0.f); v0.y = fmaxf(v0.y, 0.f);
      v0.z = fmaxf(v0.z, 0.f); v0.w = fmaxf(v0.w, 0.f);
      v1.x = fmaxf(v1.x, 0.f); v1.y = fmaxf(v1.y, 0.f);
      v1.z = fmaxf(v1.z, 0.f); v1.w = fmaxf(v1.w, 0.f);
    }
    half8 h;
    h[0] = (_Float16)v0.x; h[1] = (_Float16)v0.y;
    h[2] = (_Float16)v0.z; h[3] = (_Float16)v0.w;
    h[4] = (_Float16)v1.x; h[5] = (_Float16)v1.y;
    h[6] = (_Float16)v1.z; h[7] = (_Float16)v1.w;
    *(half8*)((char*)sA + row * 128 + ((kc * 16) ^ ((row & 7) << 4))) = h;
  }
  __syncthreads();

  const int l = tid & 63, w = tid >> 6;
  const int lm = l & 15, lh = l >> 4;

  half8 a[2][2];
#pragma unroll
  for (int rt = 0; rt < 2; ++rt)
#pragma unroll
    for (int kb = 0; kb < 2; ++kb) {
      int row = w * 32 + rt * 16 + lm;
      a[rt][kb] = *(half8*)((char*)sA + row * 128 + ((kb * 64 + lh * 16) ^ ((row & 7) << 4)));
    }

  f32x4 accA[2][4], accB[2][4];
#pragma unroll
  for (int rt = 0; rt < 2; ++rt)
#pragma unroll
    for (int nt = 0; nt < 4; ++nt) {
      accA[rt][nt] = (f32x4){0.f, 0.f, 0.f, 0.f};
      accB[rt][nt] = (f32x4){0.f, 0.f, 0.f, 0.f};
    }

#pragma unroll
  for (int nt = 0; nt < 4; ++nt) {
    int n = nt * 16 + lm;
#pragma unroll
    for (int kb = 0; kb < 2; ++kb) {
      int off = n * 128 + ((kb * 64 + lh * 16) ^ ((n & 7) << 4));
      half8 ba = *(half8*)((char*)sWa + off);
#pragma unroll
      for (int rt = 0; rt < 2; ++rt)
        accA[rt][nt] = __builtin_amdgcn_mfma_f32_16x16x32_f16(a[rt][kb], ba, accA[rt][nt], 0, 0, 0);
      if (DUAL) {
        half8 bb = *(half8*)((char*)sWb + off);
#pragma unroll
        for (int rt = 0; rt < 2; ++rt)
          accB[rt][nt] = __builtin_amdgcn_mfma_f32_16x16x32_f16(a[rt][kb], bb, accB[rt][nt], 0, 0, 0);
      }
    }
  }

#pragma unroll
  for (int rt = 0; rt < 2; ++rt) {
#pragma unroll
    for (int nt = 0; nt < 4; ++nt) {
      int col = nt * 16 + lm;
      float bv = DUAL ? bias[col] : 0.f;
#pragma unroll
      for (int r = 0; r < 4; ++r) {
        int row = row0 + w * 32 + rt * 16 + lh * 4 + r;
        if (row < NN) {
          float va = accA[rt][nt][r];
          if (SCALE) {
            float s = scale[row];
            va *= s;
            Yh[row * 64 + col] = (_Float16)va;
            Z[row * 64 + col] = va;
          } else {
            Yh[row * 64 + col] = (_Float16)va;
            Z[row * 64 + col] = accB[rt][nt][r] + bv;
          }
        }
      }
    }
  }
}

// ---------------- gather: 1 node/wave, 8 edge-groups of 8 lanes ----------------
__global__ __launch_bounds__(256) void k_gather(const int2* __restrict__ rp2,
    const int* __restrict__ csr, const _Float16* __restrict__ Yh, float* __restrict__ Z)
{
  int node = blockIdx.x * 4 + (threadIdx.x >> 6);
  int l = threadIdx.x & 63;
  int g = l >> 3;
  int c8 = l & 7;
  int2 se = rp2[node];
  int beg = se.x, end = se.y;

  float acc[8];
#pragma unroll
  for (int j = 0; j < 8; ++j) acc[j] = 0.f;

  for (int i = beg + g; i < end; i += 8) {
    int s = csr[i];
    half8 v = *(const half8*)(Yh + s * 64 + c8 * 8);
#pragma unroll
    for (int j = 0; j < 8; ++j) acc[j] += (float)v[j];
  }

#pragma unroll
  for (int off = 8; off < 64; off <<= 1) {
#pragma unroll
    for (int j = 0; j < 8; ++j) acc[j] += __shfl_xor(acc[j], off);
  }

  if (g == 0) {
    float4 z0 = *(float4*)(Z + node * 64 + c8 * 8);
    float4 z1 = *(float4*)(Z + node * 64 + c8 * 8 + 4);
    z0.x += acc[0]; z0.y += acc[1]; z0.z += acc[2]; z0.w += acc[3];
    z1.x += acc[4]; z1.y += acc[5]; z1.z += acc[6]; z1.w += acc[7];
    *(float4*)(Z + node * 64 + c8 * 8) = z0;
    *(float4*)(Z + node * 64 + c8 * 8 + 4) = z1;
  }
}

// ---------------- head ----------------
__global__ __launch_bounds__(256) void k_head(const float* __restrict__ T,
    const float* __restrict__ dinv, const float* __restrict__ Wlin,
    const float* __restrict__ cvec, float* __restrict__ out)
{
  __shared__ float sW[64 * 10];
  __shared__ float sc[10];
  int tid = threadIdx.x;
  if (tid < 10) sc[tid] = cvec[tid];
  for (int i = tid; i < 640; i += 256) sW[i] = Wlin[i];
  __syncthreads();
  int n = blockIdx.x * 256 + tid;
  if (n >= NN) return;
  float di = dinv[n];
  float dot[10];
#pragma unroll
  for (int c = 0; c < 10; ++c) dot[c] = 0.f;
  const float* row = &T[n * 64];
#pragma unroll
  for (int kc = 0; kc < 16; ++kc) {
    float4 v = *(const float4*)&row[kc * 4];
#pragma unroll
    for (int c = 0; c < 10; ++c) {
      dot[c] = fmaf(v.x, sW[(kc * 4 + 0) * 10 + c], dot[c]);
      dot[c] = fmaf(v.y, sW[(kc * 4 + 1) * 10 + c], dot[c]);
      dot[c] = fmaf(v.z, sW[(kc * 4 + 2) * 10 + c], dot[c]);
      dot[c] = fmaf(v.w, sW[(kc * 4 + 3) * 10 + c], dot[c]);
    }
  }
#pragma unroll
  for (int c = 0; c < 10; ++c) out[n * 10 + c] = fmaf(di, dot[c], sc[c]);
}

extern "C" void kernel_launch(void* const* d_in, const int* in_sizes, int n_in,
                              void* d_out, int out_size, void* d_ws, size_t ws_size,
                              hipStream_t stream) {
  const float* x       = (const float*)d_in[0];
  const int*   ei      = (const int*)d_in[1];
  const float* W1_rel  = (const float*)d_in[2];
  const float* b1      = (const float*)d_in[3];
  const float* W1_root = (const float*)d_in[4];
  const float* W2_rel  = (const float*)d_in[5];
  const float* b2      = (const float*)d_in[6];
  const float* W2_root = (const float*)d_in[7];
  const float* W3      = (const float*)d_in[8];
  const float* b3      = (const float*)d_in[9];
  const float* Wlin    = (const float*)d_in[10];
  const float* blin    = (const float*)d_in[11];
  float* out = (float*)d_out;

  char* ws = (char*)d_ws;
  _Float16* Yh     = (_Float16*)(ws);             // 12,800,000 B
  float*    Z      = (float*)(ws + 12800000);     // 25,600,000 B
  float*    dinv   = (float*)(ws + 38400000);     //    400,000 B
  int2*     rp2    = (int2*) (ws + 38800000);     //    800,000 B
  int*      csr    = (int*)  (ws + 39600000);     //  4,014,080 B (196*5120*4)
  _Float16* WT     = (_Float16*)(ws + 43614080);  //     40,960 B
  float*    cvec   = (float*)(ws + 43655040);     //         40 B
  // build temporaries overlaid on Yh (dead before gemm1 writes Yh):
  int* ebuf       = (int*)(ws);                   //  4,014,080 B
  int* bucket_cnt = (int*)(ws + 4014080);         //      1,024 B

  dim3 b256(256);

  hipMemsetAsync(bucket_cnt, 0, 256 * sizeof(int), stream);
  k_bucket<<<GRID_C, b256, 0, stream>>>(ei, bucket_cnt, ebuf);
  k_csr_build<<<NBUK, b256, 0, stream>>>(bucket_cnt, ebuf, rp2, csr, dinv);
  k_cvec<<<1, 16, 0, stream>>>(b3, Wlin, blin, cvec);
  k_prep<<<5, b256, 0, stream>>>(W1_rel, W1_root, W2_rel, W2_root, W3, WT);

  const int gg = (NN + 127) / 128;   // 782
  const int gw = NN / 4;             // 25000
  const int gN = (NN + 255) / 256;   // 391

  // layer 1
  k_gemmfma<false, true, false><<<gg, b256, 0, stream>>>(x, WT, WT + 4096, b1, nullptr, Yh, Z);
  k_gather<<<gw, b256, 0, stream>>>(rp2, csr, Yh, Z);

  // layer 2
  k_gemmfma<true, true, false><<<gg, b256, 0, stream>>>(Z, WT + 2 * 4096, WT + 3 * 4096, b2, nullptr, Yh, Z);
  k_gather<<<gw, b256, 0, stream>>>(rp2, csr, Yh, Z);

  // layer 3 (GCN)
  k_gemmfma<true, false, true><<<gg, b256, 0, stream>>>(Z, WT + 4 * 4096, nullptr, nullptr, dinv, Yh, Z);
  k_gather<<<gw, b256, 0, stream>>>(rp2, csr, Yh, Z);

  // head
  k_head<<<gN, b256, 0, stream>>>(Z, dinv, Wlin, cvec, out);
}

// Round 7
// 202.073 us; speedup vs baseline: 3.6693x; 1.0102x over previous
//
#include <hip/hip_runtime.h>

#define NN 100000
#define NE 800000
#define BSH 9                 // 512 nodes per bucket
#define BSZ (1 << BSH)
#define NBUK ((NN + BSZ - 1) / BSZ)    // 196
#define CAP 5120              // bucket capacity (mean 4096, 16 sigma margin)
#define ECHUNK 4096
#define GRID_C ((NE + ECHUNK - 1) / ECHUNK)  // 196

typedef _Float16 half8 __attribute__((ext_vector_type(8)));
typedef float f32x4 __attribute__((ext_vector_type(4)));

// ---------------- bucketed CSR build ----------------
__global__ __launch_bounds__(256) void k_bucket(const int* __restrict__ ei,
    int* __restrict__ bucket_cnt, int* __restrict__ ebuf) {
  __shared__ int h[256];
  __shared__ int cur[256];
  const int tid = threadIdx.x;
  h[tid] = 0;
  __syncthreads();

  const int e0 = blockIdx.x * ECHUNK;
  int pk[16], bk[16];
#pragma unroll
  for (int i = 0; i < 16; ++i) {
    int e = e0 + i * 256 + tid;
    if (e < NE) {
      int src = ei[e];
      int dst = ei[NE + e];
      int b = dst >> BSH;
      pk[i] = src | ((dst & (BSZ - 1)) << 17);
      bk[i] = b;
      atomicAdd(&h[b], 1);
    } else bk[i] = -1;
  }
  __syncthreads();
  cur[tid] = (tid < NBUK && h[tid] > 0) ? atomicAdd(&bucket_cnt[tid], h[tid]) : 0;
  __syncthreads();
#pragma unroll
  for (int i = 0; i < 16; ++i) {
    if (bk[i] >= 0) {
      int slot = atomicAdd(&cur[bk[i]], 1);
      ebuf[bk[i] * CAP + slot] = pk[i];
    }
  }
}

__global__ __launch_bounds__(256) void k_csr_build(const int* __restrict__ bucket_cnt,
    const int* __restrict__ ebuf, int2* __restrict__ rp2, int* __restrict__ csr,
    float* __restrict__ dinv) {
  __shared__ int h[BSZ];
  __shared__ int loff[BSZ];
  __shared__ int cur[BSZ];
  __shared__ int sd[256];
  const int tid = threadIdx.x;
  const int b = blockIdx.x;
  h[tid] = 0; h[tid + 256] = 0;
  __syncthreads();

  const int n = bucket_cnt[b];
  const int ebase = b * CAP;
  for (int i = tid; i < n; i += 256)
    atomicAdd(&h[ebuf[ebase + i] >> 17], 1);
  __syncthreads();

  int a0 = h[2 * tid], a1 = h[2 * tid + 1];
  int ps = a0 + a1;
  sd[tid] = ps;
  __syncthreads();
  int incl = ps;
  for (int o = 1; o < 256; o <<= 1) {
    int add = (tid >= o) ? sd[tid - o] : 0;
    __syncthreads();
    incl += add;
    sd[tid] = incl;
    __syncthreads();
  }
  int ex = incl - ps;
  loff[2 * tid] = ex;
  loff[2 * tid + 1] = ex + a0;
  cur[2 * tid] = ex;
  cur[2 * tid + 1] = ex + a0;
  __syncthreads();

  const int node0 = b * BSZ;
#pragma unroll
  for (int t = 0; t < 2; ++t) {
    int j = tid + t * 256;
    int node = node0 + j;
    if (node < NN) {
      int beg = ebase + loff[j];
      rp2[node] = make_int2(beg, beg + h[j]);
      dinv[node] = rsqrtf((float)h[j] + 1.0f);
    }
  }

  for (int i = tid; i < n; i += 256) {
    int v = ebuf[ebase + i];
    int dl = v >> 17;
    int slot = atomicAdd(&cur[dl], 1);
    csr[ebase + slot] = v & 0x1FFFF;
  }
}

// ---------------- small prep ----------------
__global__ void k_cvec(const float* __restrict__ b3, const float* __restrict__ Wlin,
                       const float* __restrict__ blin, float* __restrict__ cvec) {
  int c = threadIdx.x;
  if (c < 10) {
    float s = blin[c];
    for (int k = 0; k < 64; ++k) s = fmaf(b3[k], Wlin[k * 10 + c], s);
    cvec[c] = s;
  }
}

__global__ void k_prep(const float* __restrict__ W1r, const float* __restrict__ W1o,
                       const float* __restrict__ W2r, const float* __restrict__ W2o,
                       const float* __restrict__ W3, _Float16* __restrict__ WT) {
  int m = blockIdx.x;
  const float* s = (m == 0) ? W1r : (m == 1) ? W1o : (m == 2) ? W2r : (m == 3) ? W2o : W3;
  _Float16* dst = WT + m * 4096;
  for (int idx = threadIdx.x; idx < 4096; idx += 256) {
    int k = idx >> 6, n = idx & 63;
    dst[n * 64 + k] = (_Float16)s[idx];
  }
}

// ---------------- MFMA dual-GEMM (f16 in/out) ----------------
// IN_F16: A is f16 [N][64] (pre-relu'd by gather); else A is f32.
// DUAL : Yh = A@Wa ; Zh = A@Wb + bias  (both f16)
// SCALE: Yh = (A@Wa) * scale[row]      (single f16 output)
template<bool IN_F16, bool DUAL, bool SCALE>
__global__ __launch_bounds__(256) void k_gemmfma(
    const void* __restrict__ Ain, const _Float16* __restrict__ WTa,
    const _Float16* __restrict__ WTb, const float* __restrict__ bias,
    const float* __restrict__ scale, _Float16* __restrict__ Yh,
    _Float16* __restrict__ Zh)
{
  __shared__ _Float16 sA[128 * 64];
  __shared__ _Float16 sWa[64 * 64];
  __shared__ _Float16 sWb[DUAL ? 64 * 64 : 8];

  const int tid = threadIdx.x;
  const int row0 = blockIdx.x * 128;

  {
    const uint4* g = (const uint4*)WTa;
#pragma unroll
    for (int i = 0; i < 2; ++i) {
      int c = tid + 256 * i;
      int n = c >> 3, kc = c & 7;
      uint4 v = g[c];
      *(uint4*)((char*)sWa + n * 128 + ((kc * 16) ^ ((n & 7) << 4))) = v;
    }
    if (DUAL) {
      const uint4* gb = (const uint4*)WTb;
#pragma unroll
      for (int i = 0; i < 2; ++i) {
        int c = tid + 256 * i;
        int n = c >> 3, kc = c & 7;
        uint4 v = gb[c];
        *(uint4*)((char*)sWb + n * 128 + ((kc * 16) ^ ((n & 7) << 4))) = v;
      }
    }
  }

  if (IN_F16) {
    const _Float16* Af = (const _Float16*)Ain;
#pragma unroll
    for (int i = 0; i < 4; ++i) {
      int c = tid + 256 * i;
      int row = c >> 3, kc = c & 7;
      int grow = row0 + row;
      half8 h = {};
      if (grow < NN) h = *(const half8*)(Af + grow * 64 + kc * 8);
      *(half8*)((char*)sA + row * 128 + ((kc * 16) ^ ((row & 7) << 4))) = h;
    }
  } else {
    const float* Af = (const float*)Ain;
#pragma unroll
    for (int i = 0; i < 4; ++i) {
      int c = tid + 256 * i;
      int row = c >> 3, kc = c & 7;
      int grow = row0 + row;
      float4 v0 = make_float4(0.f, 0.f, 0.f, 0.f), v1 = v0;
      if (grow < NN) {
        const float4* ap = (const float4*)(Af + grow * 64);
        v0 = ap[kc * 2]; v1 = ap[kc * 2 + 1];
      }
      half8 h;
      h[0] = (_Float16)v0.x; h[1] = (_Float16)v0.y;
      h[2] = (_Float16)v0.z; h[3] = (_Float16)v0.w;
      h[4] = (_Float16)v1.x; h[5] = (_Float16)v1.y;
      h[6] = (_Float16)v1.z; h[7] = (_Float16)v1.w;
      *(half8*)((char*)sA + row * 128 + ((kc * 16) ^ ((row & 7) << 4))) = h;
    }
  }
  __syncthreads();

  const int l = tid & 63, w = tid >> 6;
  const int lm = l & 15, lh = l >> 4;

  half8 a[2][2];
#pragma unroll
  for (int rt = 0; rt < 2; ++rt)
#pragma unroll
    for (int kb = 0; kb < 2; ++kb) {
      int row = w * 32 + rt * 16 + lm;
      a[rt][kb] = *(half8*)((char*)sA + row * 128 + ((kb * 64 + lh * 16) ^ ((row & 7) << 4)));
    }

  f32x4 accA[2][4], accB[2][4];
#pragma unroll
  for (int rt = 0; rt < 2; ++rt)
#pragma unroll
    for (int nt = 0; nt < 4; ++nt) {
      accA[rt][nt] = (f32x4){0.f, 0.f, 0.f, 0.f};
      accB[rt][nt] = (f32x4){0.f, 0.f, 0.f, 0.f};
    }

#pragma unroll
  for (int nt = 0; nt < 4; ++nt) {
    int n = nt * 16 + lm;
#pragma unroll
    for (int kb = 0; kb < 2; ++kb) {
      int off = n * 128 + ((kb * 64 + lh * 16) ^ ((n & 7) << 4));
      half8 ba = *(half8*)((char*)sWa + off);
#pragma unroll
      for (int rt = 0; rt < 2; ++rt)
        accA[rt][nt] = __builtin_amdgcn_mfma_f32_16x16x32_f16(a[rt][kb], ba, accA[rt][nt], 0, 0, 0);
      if (DUAL) {
        half8 bb = *(half8*)((char*)sWb + off);
#pragma unroll
        for (int rt = 0; rt < 2; ++rt)
          accB[rt][nt] = __builtin_amdgcn_mfma_f32_16x16x32_f16(a[rt][kb], bb, accB[rt][nt], 0, 0, 0);
      }
    }
  }

#pragma unroll
  for (int rt = 0; rt < 2; ++rt) {
#pragma unroll
    for (int nt = 0; nt < 4; ++nt) {
      int col = nt * 16 + lm;
      float bv = DUAL ? bias[col] : 0.f;
#pragma unroll
      for (int r = 0; r < 4; ++r) {
        int row = row0 + w * 32 + rt * 16 + lh * 4 + r;
        if (row < NN) {
          float va = accA[rt][nt][r];
          if (SCALE) {
            Yh[row * 64 + col] = (_Float16)(va * scale[row]);
          } else {
            Yh[row * 64 + col] = (_Float16)va;
            Zh[row * 64 + col] = (_Float16)(accB[rt][nt][r] + bv);
          }
        }
      }
    }
  }
}

// ---------------- gather: 1 node/wave, 8 edge-groups of 8 lanes ----------------
// acc = sum_{e} Yh[src_e]; out row = (RELU? relu : id)(Zrow[node] + acc)  -> f16
__global__ __launch_bounds__(256) void k_gather(const int2* __restrict__ rp2,
    const int* __restrict__ csr, const _Float16* __restrict__ Yh,
    const _Float16* __restrict__ Zrow, _Float16* __restrict__ Aout, int relu)
{
  int node = blockIdx.x * 4 + (threadIdx.x >> 6);
  int l = threadIdx.x & 63;
  int g = l >> 3;
  int c8 = l & 7;
  int2 se = rp2[node];
  int beg = se.x, end = se.y;

  float acc[8];
#pragma unroll
  for (int j = 0; j < 8; ++j) acc[j] = 0.f;

  for (int i = beg + g; i < end; i += 8) {
    int s = csr[i];
    half8 v = *(const half8*)(Yh + s * 64 + c8 * 8);
#pragma unroll
    for (int j = 0; j < 8; ++j) acc[j] += (float)v[j];
  }

#pragma unroll
  for (int off = 8; off < 64; off <<= 1) {
#pragma unroll
    for (int j = 0; j < 8; ++j) acc[j] += __shfl_xor(acc[j], off);
  }

  if (g == 0) {
    half8 zr = *(const half8*)(Zrow + node * 64 + c8 * 8);
    half8 o;
#pragma unroll
    for (int j = 0; j < 8; ++j) {
      float t = acc[j] + (float)zr[j];
      if (relu) t = fmaxf(t, 0.f);
      o[j] = (_Float16)t;
    }
    *(half8*)(Aout + node * 64 + c8 * 8) = o;
  }
}

// ---------------- head (f16 T rows) ----------------
__global__ __launch_bounds__(256) void k_head(const _Float16* __restrict__ T,
    const float* __restrict__ dinv, const float* __restrict__ Wlin,
    const float* __restrict__ cvec, float* __restrict__ out)
{
  __shared__ float sW[64 * 10];
  __shared__ float sc[10];
  int tid = threadIdx.x;
  if (tid < 10) sc[tid] = cvec[tid];
  for (int i = tid; i < 640; i += 256) sW[i] = Wlin[i];
  __syncthreads();
  int n = blockIdx.x * 256 + tid;
  if (n >= NN) return;
  float di = dinv[n];
  float dot[10];
#pragma unroll
  for (int c = 0; c < 10; ++c) dot[c] = 0.f;
  const half8* row = (const half8*)(T + n * 64);
#pragma unroll
  for (int kc = 0; kc < 8; ++kc) {
    half8 v = row[kc];
#pragma unroll
    for (int j = 0; j < 8; ++j) {
      float f = (float)v[j];
#pragma unroll
      for (int c = 0; c < 10; ++c)
        dot[c] = fmaf(f, sW[(kc * 8 + j) * 10 + c], dot[c]);
    }
  }
#pragma unroll
  for (int c = 0; c < 10; ++c) out[n * 10 + c] = fmaf(di, dot[c], sc[c]);
}

extern "C" void kernel_launch(void* const* d_in, const int* in_sizes, int n_in,
                              void* d_out, int out_size, void* d_ws, size_t ws_size,
                              hipStream_t stream) {
  const float* x       = (const float*)d_in[0];
  const int*   ei      = (const int*)d_in[1];
  const float* W1_rel  = (const float*)d_in[2];
  const float* b1      = (const float*)d_in[3];
  const float* W1_root = (const float*)d_in[4];
  const float* W2_rel  = (const float*)d_in[5];
  const float* b2      = (const float*)d_in[6];
  const float* W2_root = (const float*)d_in[7];
  const float* W3      = (const float*)d_in[8];
  const float* b3      = (const float*)d_in[9];
  const float* Wlin    = (const float*)d_in[10];
  const float* blin    = (const float*)d_in[11];
  float* out = (float*)d_out;

  char* ws = (char*)d_ws;
  _Float16* Yh     = (_Float16*)(ws);             // 12,800,000 B
  _Float16* Zh     = (_Float16*)(ws + 12800000);  // 12,800,000 B
  _Float16* Ah     = (_Float16*)(ws + 25600000);  // 12,800,000 B
  float*    dinv   = (float*)(ws + 38400000);     //    400,000 B
  int2*     rp2    = (int2*) (ws + 38800000);     //    800,000 B
  int*      csr    = (int*)  (ws + 39600000);     //  4,014,080 B
  _Float16* WT     = (_Float16*)(ws + 43614080);  //     40,960 B
  float*    cvec   = (float*)(ws + 43655040);     //         40 B
  // build temporaries overlaid on Yh (dead before gemm1 writes Yh):
  int* ebuf       = (int*)(ws);                   //  4,014,080 B
  int* bucket_cnt = (int*)(ws + 4014080);         //      1,024 B

  dim3 b256(256);

  hipMemsetAsync(bucket_cnt, 0, 256 * sizeof(int), stream);
  k_bucket<<<GRID_C, b256, 0, stream>>>(ei, bucket_cnt, ebuf);
  k_csr_build<<<NBUK, b256, 0, stream>>>(bucket_cnt, ebuf, rp2, csr, dinv);
  k_cvec<<<1, 16, 0, stream>>>(b3, Wlin, blin, cvec);
  k_prep<<<5, b256, 0, stream>>>(W1_rel, W1_root, W2_rel, W2_root, W3, WT);

  const int gg = (NN + 127) / 128;   // 782
  const int gw = NN / 4;             // 25000
  const int gN = (NN + 255) / 256;   // 391

  // layer 1: Yh = x@W1_rel ; Zh = x@W1_root + b1 ; Ah = relu(Zh + agg(Yh))
  k_gemmfma<false, true, false><<<gg, b256, 0, stream>>>(x, WT, WT + 4096, b1, nullptr, Yh, Zh);
  k_gather<<<gw, b256, 0, stream>>>(rp2, csr, Yh, Zh, Ah, 1);

  // layer 2: Yh = Ah@W2_rel ; Zh = Ah@W2_root + b2 ; Ah = relu(Zh + agg(Yh))
  k_gemmfma<true, true, false><<<gg, b256, 0, stream>>>(Ah, WT + 2 * 4096, WT + 3 * 4096, b2, nullptr, Yh, Zh);
  k_gather<<<gw, b256, 0, stream>>>(rp2, csr, Yh, Zh, Ah, 1);

  // layer 3 (GCN): Yh = (Ah@W3)*dinv ; Ah(T) = Yh[node] + agg(Yh)
  k_gemmfma<true, false, true><<<gg, b256, 0, stream>>>(Ah, WT + 4 * 4096, nullptr, nullptr, dinv, Yh, nullptr);
  k_gather<<<gw, b256, 0, stream>>>(rp2, csr, Yh, Yh, Ah, 0);

  // head: out = dinv * (T @ Wlin) + (b3@Wlin + blin)
  k_head<<<gN, b256, 0, stream>>>(Ah, dinv, Wlin, cvec, out);
}

// Round 8
// 178.515 us; speedup vs baseline: 4.1536x; 1.1320x over previous
//
#include <hip/hip_runtime.h>

#define NN 100000
#define NE 800000
#define BSH 9                 // 512 nodes per bucket
#define BSZ (1 << BSH)
#define NBUK ((NN + BSZ - 1) / BSZ)    // 196
#define CAP 5120              // bucket capacity (mean 4096, 16 sigma margin)
#define ECHUNK 4096
#define GRID_C ((NE + ECHUNK - 1) / ECHUNK)  // 196

typedef _Float16 half8 __attribute__((ext_vector_type(8)));
typedef float f32x4 __attribute__((ext_vector_type(4)));

// ---------------- bucketed CSR build ----------------
__global__ __launch_bounds__(256) void k_bucket(const int* __restrict__ ei,
    int* __restrict__ bucket_cnt, int* __restrict__ ebuf) {
  __shared__ int h[256];
  __shared__ int cur[256];
  const int tid = threadIdx.x;
  h[tid] = 0;
  __syncthreads();

  const int e0 = blockIdx.x * ECHUNK;
  int pk[16], bk[16];
#pragma unroll
  for (int i = 0; i < 16; ++i) {
    int e = e0 + i * 256 + tid;
    if (e < NE) {
      int src = ei[e];
      int dst = ei[NE + e];
      int b = dst >> BSH;
      pk[i] = src | ((dst & (BSZ - 1)) << 17);
      bk[i] = b;
      atomicAdd(&h[b], 1);
    } else bk[i] = -1;
  }
  __syncthreads();
  cur[tid] = (tid < NBUK && h[tid] > 0) ? atomicAdd(&bucket_cnt[tid], h[tid]) : 0;
  __syncthreads();
#pragma unroll
  for (int i = 0; i < 16; ++i) {
    if (bk[i] >= 0) {
      int slot = atomicAdd(&cur[bk[i]], 1);
      ebuf[bk[i] * CAP + slot] = pk[i];
    }
  }
}

__global__ __launch_bounds__(256) void k_csr_build(const int* __restrict__ bucket_cnt,
    const int* __restrict__ ebuf, int2* __restrict__ rp2, int* __restrict__ csr,
    float* __restrict__ dinv) {
  __shared__ int h[BSZ];
  __shared__ int loff[BSZ];
  __shared__ int cur[BSZ];
  __shared__ int sd[256];
  const int tid = threadIdx.x;
  const int b = blockIdx.x;
  h[tid] = 0; h[tid + 256] = 0;
  __syncthreads();

  const int n = bucket_cnt[b];
  const int ebase = b * CAP;
  for (int i = tid; i < n; i += 256)
    atomicAdd(&h[ebuf[ebase + i] >> 17], 1);
  __syncthreads();

  int a0 = h[2 * tid], a1 = h[2 * tid + 1];
  int ps = a0 + a1;
  sd[tid] = ps;
  __syncthreads();
  int incl = ps;
  for (int o = 1; o < 256; o <<= 1) {
    int add = (tid >= o) ? sd[tid - o] : 0;
    __syncthreads();
    incl += add;
    sd[tid] = incl;
    __syncthreads();
  }
  int ex = incl - ps;
  loff[2 * tid] = ex;
  loff[2 * tid + 1] = ex + a0;
  cur[2 * tid] = ex;
  cur[2 * tid + 1] = ex + a0;
  __syncthreads();

  const int node0 = b * BSZ;
#pragma unroll
  for (int t = 0; t < 2; ++t) {
    int j = tid + t * 256;
    int node = node0 + j;
    if (node < NN) {
      int beg = ebase + loff[j];
      rp2[node] = make_int2(beg, beg + h[j]);
      dinv[node] = rsqrtf((float)h[j] + 1.0f);
    }
  }

  for (int i = tid; i < n; i += 256) {
    int v = ebuf[ebase + i];
    int dl = v >> 17;
    int slot = atomicAdd(&cur[dl], 1);
    csr[ebase + slot] = v & 0x1FFFF;
  }
}

// ---------------- small prep (also zeroes bucket_cnt — replaces hipMemsetAsync) ----------------
__global__ __launch_bounds__(256) void k_cvec(const float* __restrict__ b3,
    const float* __restrict__ Wlin, const float* __restrict__ blin,
    float* __restrict__ cvec, int* __restrict__ bucket_cnt) {
  int c = threadIdx.x;
  bucket_cnt[c] = 0;
  if (c < 10) {
    float s = blin[c];
    for (int k = 0; k < 64; ++k) s = fmaf(b3[k], Wlin[k * 10 + c], s);
    cvec[c] = s;
  }
}

__global__ void k_prep(const float* __restrict__ W1r, const float* __restrict__ W1o,
                       const float* __restrict__ W2r, const float* __restrict__ W2o,
                       const float* __restrict__ W3, _Float16* __restrict__ WT) {
  int m = blockIdx.x;
  const float* s = (m == 0) ? W1r : (m == 1) ? W1o : (m == 2) ? W2r : (m == 3) ? W2o : W3;
  _Float16* dst = WT + m * 4096;
  for (int idx = threadIdx.x; idx < 4096; idx += 256) {
    int k = idx >> 6, n = idx & 63;
    dst[n * 64 + k] = (_Float16)s[idx];
  }
}

// ---------------- MFMA dual-GEMM (f16 in/out) ----------------
template<bool IN_F16, bool DUAL, bool SCALE>
__global__ __launch_bounds__(256) void k_gemmfma(
    const void* __restrict__ Ain, const _Float16* __restrict__ WTa,
    const _Float16* __restrict__ WTb, const float* __restrict__ bias,
    const float* __restrict__ scale, _Float16* __restrict__ Yh,
    _Float16* __restrict__ Zh)
{
  __shared__ _Float16 sA[128 * 64];
  __shared__ _Float16 sWa[64 * 64];
  __shared__ _Float16 sWb[DUAL ? 64 * 64 : 8];

  const int tid = threadIdx.x;
  const int row0 = blockIdx.x * 128;

  {
    const uint4* g = (const uint4*)WTa;
#pragma unroll
    for (int i = 0; i < 2; ++i) {
      int c = tid + 256 * i;
      int n = c >> 3, kc = c & 7;
      uint4 v = g[c];
      *(uint4*)((char*)sWa + n * 128 + ((kc * 16) ^ ((n & 7) << 4))) = v;
    }
    if (DUAL) {
      const uint4* gb = (const uint4*)WTb;
#pragma unroll
      for (int i = 0; i < 2; ++i) {
        int c = tid + 256 * i;
        int n = c >> 3, kc = c & 7;
        uint4 v = gb[c];
        *(uint4*)((char*)sWb + n * 128 + ((kc * 16) ^ ((n & 7) << 4))) = v;
      }
    }
  }

  if (IN_F16) {
    const _Float16* Af = (const _Float16*)Ain;
#pragma unroll
    for (int i = 0; i < 4; ++i) {
      int c = tid + 256 * i;
      int row = c >> 3, kc = c & 7;
      int grow = row0 + row;
      half8 h = {};
      if (grow < NN) h = *(const half8*)(Af + grow * 64 + kc * 8);
      *(half8*)((char*)sA + row * 128 + ((kc * 16) ^ ((row & 7) << 4))) = h;
    }
  } else {
    const float* Af = (const float*)Ain;
#pragma unroll
    for (int i = 0; i < 4; ++i) {
      int c = tid + 256 * i;
      int row = c >> 3, kc = c & 7;
      int grow = row0 + row;
      float4 v0 = make_float4(0.f, 0.f, 0.f, 0.f), v1 = v0;
      if (grow < NN) {
        const float4* ap = (const float4*)(Af + grow * 64);
        v0 = ap[kc * 2]; v1 = ap[kc * 2 + 1];
      }
      half8 h;
      h[0] = (_Float16)v0.x; h[1] = (_Float16)v0.y;
      h[2] = (_Float16)v0.z; h[3] = (_Float16)v0.w;
      h[4] = (_Float16)v1.x; h[5] = (_Float16)v1.y;
      h[6] = (_Float16)v1.z; h[7] = (_Float16)v1.w;
      *(half8*)((char*)sA + row * 128 + ((kc * 16) ^ ((row & 7) << 4))) = h;
    }
  }
  __syncthreads();

  const int l = tid & 63, w = tid >> 6;
  const int lm = l & 15, lh = l >> 4;

  half8 a[2][2];
#pragma unroll
  for (int rt = 0; rt < 2; ++rt)
#pragma unroll
    for (int kb = 0; kb < 2; ++kb) {
      int row = w * 32 + rt * 16 + lm;
      a[rt][kb] = *(half8*)((char*)sA + row * 128 + ((kb * 64 + lh * 16) ^ ((row & 7) << 4)));
    }

  f32x4 accA[2][4], accB[2][4];
#pragma unroll
  for (int rt = 0; rt < 2; ++rt)
#pragma unroll
    for (int nt = 0; nt < 4; ++nt) {
      accA[rt][nt] = (f32x4){0.f, 0.f, 0.f, 0.f};
      accB[rt][nt] = (f32x4){0.f, 0.f, 0.f, 0.f};
    }

#pragma unroll
  for (int nt = 0; nt < 4; ++nt) {
    int n = nt * 16 + lm;
#pragma unroll
    for (int kb = 0; kb < 2; ++kb) {
      int off = n * 128 + ((kb * 64 + lh * 16) ^ ((n & 7) << 4));
      half8 ba = *(half8*)((char*)sWa + off);
#pragma unroll
      for (int rt = 0; rt < 2; ++rt)
        accA[rt][nt] = __builtin_amdgcn_mfma_f32_16x16x32_f16(a[rt][kb], ba, accA[rt][nt], 0, 0, 0);
      if (DUAL) {
        half8 bb = *(half8*)((char*)sWb + off);
#pragma unroll
        for (int rt = 0; rt < 2; ++rt)
          accB[rt][nt] = __builtin_amdgcn_mfma_f32_16x16x32_f16(a[rt][kb], bb, accB[rt][nt], 0, 0, 0);
      }
    }
  }

#pragma unroll
  for (int rt = 0; rt < 2; ++rt) {
#pragma unroll
    for (int nt = 0; nt < 4; ++nt) {
      int col = nt * 16 + lm;
      float bv = DUAL ? bias[col] : 0.f;
#pragma unroll
      for (int r = 0; r < 4; ++r) {
        int row = row0 + w * 32 + rt * 16 + lh * 4 + r;
        if (row < NN) {
          float va = accA[rt][nt][r];
          if (SCALE) {
            Yh[row * 64 + col] = (_Float16)(va * scale[row]);
          } else {
            Yh[row * 64 + col] = (_Float16)va;
            Zh[row * 64 + col] = (_Float16)(accB[rt][nt][r] + bv);
          }
        }
      }
    }
  }
}

// ---------------- gather: 2 nodes/wave, 8 edge-groups, branchless dual stream ----------------
// acc_n = sum_{e in CSR[n]} Yh[src_e]; Aout[n] = act(Zrow[n] + acc_n) as f16.
__global__ __launch_bounds__(256) void k_gather(const int2* __restrict__ rp2,
    const int* __restrict__ csr, const _Float16* __restrict__ Yh,
    const _Float16* __restrict__ Zrow, _Float16* __restrict__ Aout, int relu)
{
  int wid = blockIdx.x * 4 + (threadIdx.x >> 6);
  int n0 = wid * 2, n1 = n0 + 1;
  int l = threadIdx.x & 63;
  int g = l >> 3;        // edge group 0..7
  int c8 = l & 7;        // column chunk
  int2 se0 = rp2[n0];
  int2 se1 = rp2[n1];

  float acc0[8], acc1[8];
#pragma unroll
  for (int j = 0; j < 8; ++j) { acc0[j] = 0.f; acc1[j] = 0.f; }

  int i0 = se0.x + g, i1 = se1.x + g;
  const int e0 = se0.y, e1 = se1.y;

  while (i0 < e0 || i1 < e1) {
    bool a0 = i0 < e0, a1 = i1 < e1;
    int ci0 = a0 ? i0 : 0;
    int ci1 = a1 ? i1 : 0;
    int s0 = csr[ci0];               // both index loads issue together
    int s1 = csr[ci1];
    s0 = min(s0 & 0x1FFFF, NN - 1);  // clamp: safe even for masked-off lanes
    s1 = min(s1 & 0x1FFFF, NN - 1);
    half8 v0 = *(const half8*)(Yh + s0 * 64 + c8 * 8);  // both rows in flight
    half8 v1 = *(const half8*)(Yh + s1 * 64 + c8 * 8);
    float m0 = a0 ? 1.f : 0.f;
    float m1 = a1 ? 1.f : 0.f;
#pragma unroll
    for (int j = 0; j < 8; ++j) {
      acc0[j] = fmaf(m0, (float)v0[j], acc0[j]);
      acc1[j] = fmaf(m1, (float)v1[j], acc1[j]);
    }
    i0 += 8; i1 += 8;
  }

#pragma unroll
  for (int off = 8; off < 64; off <<= 1) {
#pragma unroll
    for (int j = 0; j < 8; ++j) {
      acc0[j] += __shfl_xor(acc0[j], off);
      acc1[j] += __shfl_xor(acc1[j], off);
    }
  }

  if (g < 2) {
    int node = (g == 0) ? n0 : n1;
    half8 zr = *(const half8*)(Zrow + node * 64 + c8 * 8);
    half8 o;
#pragma unroll
    for (int j = 0; j < 8; ++j) {
      float t = ((g == 0) ? acc0[j] : acc1[j]) + (float)zr[j];
      if (relu) t = fmaxf(t, 0.f);
      o[j] = (_Float16)t;
    }
    *(half8*)(Aout + node * 64 + c8 * 8) = o;
  }
}

// ---------------- head (f16 T rows) ----------------
__global__ __launch_bounds__(256) void k_head(const _Float16* __restrict__ T,
    const float* __restrict__ dinv, const float* __restrict__ Wlin,
    const float* __restrict__ cvec, float* __restrict__ out)
{
  __shared__ float sW[64 * 10];
  __shared__ float sc[10];
  int tid = threadIdx.x;
  if (tid < 10) sc[tid] = cvec[tid];
  for (int i = tid; i < 640; i += 256) sW[i] = Wlin[i];
  __syncthreads();
  int n = blockIdx.x * 256 + tid;
  if (n >= NN) return;
  float di = dinv[n];
  float dot[10];
#pragma unroll
  for (int c = 0; c < 10; ++c) dot[c] = 0.f;
  const half8* row = (const half8*)(T + n * 64);
#pragma unroll
  for (int kc = 0; kc < 8; ++kc) {
    half8 v = row[kc];
#pragma unroll
    for (int j = 0; j < 8; ++j) {
      float f = (float)v[j];
#pragma unroll
      for (int c = 0; c < 10; ++c)
        dot[c] = fmaf(f, sW[(kc * 8 + j) * 10 + c], dot[c]);
    }
  }
#pragma unroll
  for (int c = 0; c < 10; ++c) out[n * 10 + c] = fmaf(di, dot[c], sc[c]);
}

extern "C" void kernel_launch(void* const* d_in, const int* in_sizes, int n_in,
                              void* d_out, int out_size, void* d_ws, size_t ws_size,
                              hipStream_t stream) {
  const float* x       = (const float*)d_in[0];
  const int*   ei      = (const int*)d_in[1];
  const float* W1_rel  = (const float*)d_in[2];
  const float* b1      = (const float*)d_in[3];
  const float* W1_root = (const float*)d_in[4];
  const float* W2_rel  = (const float*)d_in[5];
  const float* b2      = (const float*)d_in[6];
  const float* W2_root = (const float*)d_in[7];
  const float* W3      = (const float*)d_in[8];
  const float* b3      = (const float*)d_in[9];
  const float* Wlin    = (const float*)d_in[10];
  const float* blin    = (const float*)d_in[11];
  float* out = (float*)d_out;

  char* ws = (char*)d_ws;
  _Float16* Yh     = (_Float16*)(ws);             // 12,800,000 B
  _Float16* Zh     = (_Float16*)(ws + 12800000);  // 12,800,000 B
  _Float16* Ah     = (_Float16*)(ws + 25600000);  // 12,800,000 B
  float*    dinv   = (float*)(ws + 38400000);     //    400,000 B
  int2*     rp2    = (int2*) (ws + 38800000);     //    800,000 B
  int*      csr    = (int*)  (ws + 39600000);     //  4,014,080 B
  _Float16* WT     = (_Float16*)(ws + 43614080);  //     40,960 B
  float*    cvec   = (float*)(ws + 43655040);     //         40 B
  // build temporaries overlaid on Yh (dead before gemm1 writes Yh):
  int* ebuf       = (int*)(ws);                   //  4,014,080 B
  int* bucket_cnt = (int*)(ws + 4014080);         //      1,024 B

  dim3 b256(256);

  k_cvec<<<1, b256, 0, stream>>>(b3, Wlin, blin, cvec, bucket_cnt);
  k_prep<<<5, b256, 0, stream>>>(W1_rel, W1_root, W2_rel, W2_root, W3, WT);
  k_bucket<<<GRID_C, b256, 0, stream>>>(ei, bucket_cnt, ebuf);
  k_csr_build<<<NBUK, b256, 0, stream>>>(bucket_cnt, ebuf, rp2, csr, dinv);

  const int gg = (NN + 127) / 128;   // 782
  const int gw = NN / 8;             // 12500 blocks: 4 waves x 2 nodes
  const int gN = (NN + 255) / 256;   // 391

  // layer 1: Yh = x@W1_rel ; Zh = x@W1_root + b1 ; Ah = relu(Zh + agg(Yh))
  k_gemmfma<false, true, false><<<gg, b256, 0, stream>>>(x, WT, WT + 4096, b1, nullptr, Yh, Zh);
  k_gather<<<gw, b256, 0, stream>>>(rp2, csr, Yh, Zh, Ah, 1);

  // layer 2
  k_gemmfma<true, true, false><<<gg, b256, 0, stream>>>(Ah, WT + 2 * 4096, WT + 3 * 4096, b2, nullptr, Yh, Zh);
  k_gather<<<gw, b256, 0, stream>>>(rp2, csr, Yh, Zh, Ah, 1);

  // layer 3 (GCN): Yh = (Ah@W3)*dinv ; T = Yh[node] + agg(Yh)
  k_gemmfma<true, false, true><<<gg, b256, 0, stream>>>(Ah, WT + 4 * 4096, nullptr, nullptr, dinv, Yh, nullptr);
  k_gather<<<gw, b256, 0, stream>>>(rp2, csr, Yh, Yh, Ah, 0);

  // head
  k_head<<<gN, b256, 0, stream>>>(Ah, dinv, Wlin, cvec, out);
}

// Round 9
// 145.665 us; speedup vs baseline: 5.0903x; 1.2255x over previous
//
#include <hip/hip_runtime.h>

#define NN 100000
#define NE 800000
#define BSH 9                 // 512 nodes per bucket
#define BSZ (1 << BSH)
#define NBUK ((NN + BSZ - 1) / BSZ)    // 196
#define CAP 6144              // bucket capacity incl. padding (real <=~4500 + pad <=1536)
#define ECHUNK 4096
#define GRID_C ((NE + ECHUNK - 1) / ECHUNK)  // 196

typedef _Float16 half8 __attribute__((ext_vector_type(8)));
typedef float f32x4 __attribute__((ext_vector_type(4)));

// ---------------- bucketed CSR build ----------------
__global__ __launch_bounds__(256) void k_bucket(const int* __restrict__ ei,
    int* __restrict__ bucket_cnt, int* __restrict__ ebuf) {
  __shared__ int h[256];
  __shared__ int cur[256];
  const int tid = threadIdx.x;
  h[tid] = 0;
  __syncthreads();

  const int e0 = blockIdx.x * ECHUNK;
  int pk[16], bk[16];
#pragma unroll
  for (int i = 0; i < 16; ++i) {
    int e = e0 + i * 256 + tid;
    if (e < NE) {
      int src = ei[e];
      int dst = ei[NE + e];
      int b = dst >> BSH;
      pk[i] = src | ((dst & (BSZ - 1)) << 17);
      bk[i] = b;
      atomicAdd(&h[b], 1);
    } else bk[i] = -1;
  }
  __syncthreads();
  cur[tid] = (tid < NBUK && h[tid] > 0) ? atomicAdd(&bucket_cnt[tid], h[tid]) : 0;
  __syncthreads();
#pragma unroll
  for (int i = 0; i < 16; ++i) {
    if (bk[i] >= 0) {
      int slot = atomicAdd(&cur[bk[i]], 1);
      ebuf[bk[i] * CAP + slot] = pk[i];
    }
  }
}

// per bucket: per-node spans padded to x4 (pads -> dummy row NN), dinv, csr srcs
__global__ __launch_bounds__(256) void k_csr_build(const int* __restrict__ bucket_cnt,
    const int* __restrict__ ebuf, int2* __restrict__ rp2, int* __restrict__ csr,
    float* __restrict__ dinv) {
  __shared__ int h[BSZ];
  __shared__ int loff[BSZ];
  __shared__ int cur[BSZ];
  __shared__ int sd[256];
  const int tid = threadIdx.x;
  const int b = blockIdx.x;
  h[tid] = 0; h[tid + 256] = 0;
  __syncthreads();

  const int n = bucket_cnt[b];
  const int ebase = b * CAP;
  for (int i = tid; i < n; i += 256)
    atomicAdd(&h[ebuf[ebase + i] >> 17], 1);
  __syncthreads();

  // scan padded counts hp = (h+3)&~3 over 512 entries (thread owns 2t,2t+1)
  int r0 = h[2 * tid], r1 = h[2 * tid + 1];
  int p0 = (r0 + 3) & ~3, p1 = (r1 + 3) & ~3;
  int ps = p0 + p1;
  sd[tid] = ps;
  __syncthreads();
  int incl = ps;
  for (int o = 1; o < 256; o <<= 1) {
    int add = (tid >= o) ? sd[tid - o] : 0;
    __syncthreads();
    incl += add;
    sd[tid] = incl;
    __syncthreads();
  }
  int ex = incl - ps;
  loff[2 * tid] = ex;
  loff[2 * tid + 1] = ex + p0;
  cur[2 * tid] = ex;
  cur[2 * tid + 1] = ex + p0;
  __syncthreads();

  const int node0 = b * BSZ;
#pragma unroll
  for (int t = 0; t < 2; ++t) {
    int j = tid + t * 256;
    int node = node0 + j;
    if (node < NN) {
      int hr = h[j];
      int hp = (hr + 3) & ~3;
      int beg = ebase + loff[j];
      rp2[node] = make_int2(beg, beg + hp);    // loop bound = padded end
      dinv[node] = rsqrtf((float)hr + 1.0f);
      for (int p = hr; p < hp; ++p) csr[beg + p] = NN;  // pads -> zero row
    }
  }

  for (int i = tid; i < n; i += 256) {
    int v = ebuf[ebase + i];
    int dl = v >> 17;
    int slot = atomicAdd(&cur[dl], 1);
    csr[ebase + slot] = v & 0x1FFFF;
  }
}

// ---------------- prep: weights transpose->f16, cvec, bucket_cnt zero, zero row ----------------
__global__ __launch_bounds__(256) void k_prep(const float* __restrict__ W1r,
    const float* __restrict__ W1o, const float* __restrict__ W2r,
    const float* __restrict__ W2o, const float* __restrict__ W3,
    const float* __restrict__ b3, const float* __restrict__ Wlin,
    const float* __restrict__ blin, _Float16* __restrict__ WT,
    float* __restrict__ cvec, int* __restrict__ bucket_cnt,
    _Float16* __restrict__ Yh) {
  int m = blockIdx.x;
  int tid = threadIdx.x;
  if (m == 5) {
    bucket_cnt[tid] = 0;
    if (tid >= 64 && tid < 128) Yh[NN * 64 + (tid - 64)] = (_Float16)0.f;  // dummy row
    if (tid < 10) {
      float s = blin[tid];
      for (int k = 0; k < 64; ++k) s = fmaf(b3[k], Wlin[k * 10 + tid], s);
      cvec[tid] = s;
    }
    return;
  }
  const float* s = (m == 0) ? W1r : (m == 1) ? W1o : (m == 2) ? W2r : (m == 3) ? W2o : W3;
  _Float16* dst = WT + m * 4096;
  for (int idx = tid; idx < 4096; idx += 256) {
    int k = idx >> 6, n = idx & 63;
    dst[n * 64 + k] = (_Float16)s[idx];
  }
}

// ---------------- MFMA dual-GEMM (f16 in/out) ----------------
template<bool IN_F16, bool DUAL, bool SCALE>
__global__ __launch_bounds__(256) void k_gemmfma(
    const void* __restrict__ Ain, const _Float16* __restrict__ WTa,
    const _Float16* __restrict__ WTb, const float* __restrict__ bias,
    const float* __restrict__ scale, _Float16* __restrict__ Yh,
    _Float16* __restrict__ Zh)
{
  __shared__ _Float16 sA[128 * 64];
  __shared__ _Float16 sWa[64 * 64];
  __shared__ _Float16 sWb[DUAL ? 64 * 64 : 8];

  const int tid = threadIdx.x;
  const int row0 = blockIdx.x * 128;

  {
    const uint4* g = (const uint4*)WTa;
#pragma unroll
    for (int i = 0; i < 2; ++i) {
      int c = tid + 256 * i;
      int n = c >> 3, kc = c & 7;
      uint4 v = g[c];
      *(uint4*)((char*)sWa + n * 128 + ((kc * 16) ^ ((n & 7) << 4))) = v;
    }
    if (DUAL) {
      const uint4* gb = (const uint4*)WTb;
#pragma unroll
      for (int i = 0; i < 2; ++i) {
        int c = tid + 256 * i;
        int n = c >> 3, kc = c & 7;
        uint4 v = gb[c];
        *(uint4*)((char*)sWb + n * 128 + ((kc * 16) ^ ((n & 7) << 4))) = v;
      }
    }
  }

  if (IN_F16) {
    const _Float16* Af = (const _Float16*)Ain;
#pragma unroll
    for (int i = 0; i < 4; ++i) {
      int c = tid + 256 * i;
      int row = c >> 3, kc = c & 7;
      int grow = row0 + row;
      half8 h = {};
      if (grow < NN) h = *(const half8*)(Af + grow * 64 + kc * 8);
      *(half8*)((char*)sA + row * 128 + ((kc * 16) ^ ((row & 7) << 4))) = h;
    }
  } else {
    const float* Af = (const float*)Ain;
#pragma unroll
    for (int i = 0; i < 4; ++i) {
      int c = tid + 256 * i;
      int row = c >> 3, kc = c & 7;
      int grow = row0 + row;
      float4 v0 = make_float4(0.f, 0.f, 0.f, 0.f), v1 = v0;
      if (grow < NN) {
        const float4* ap = (const float4*)(Af + grow * 64);
        v0 = ap[kc * 2]; v1 = ap[kc * 2 + 1];
      }
      half8 h;
      h[0] = (_Float16)v0.x; h[1] = (_Float16)v0.y;
      h[2] = (_Float16)v0.z; h[3] = (_Float16)v0.w;
      h[4] = (_Float16)v1.x; h[5] = (_Float16)v1.y;
      h[6] = (_Float16)v1.z; h[7] = (_Float16)v1.w;
      *(half8*)((char*)sA + row * 128 + ((kc * 16) ^ ((row & 7) << 4))) = h;
    }
  }
  __syncthreads();

  const int l = tid & 63, w = tid >> 6;
  const int lm = l & 15, lh = l >> 4;

  half8 a[2][2];
#pragma unroll
  for (int rt = 0; rt < 2; ++rt)
#pragma unroll
    for (int kb = 0; kb < 2; ++kb) {
      int row = w * 32 + rt * 16 + lm;
      a[rt][kb] = *(half8*)((char*)sA + row * 128 + ((kb * 64 + lh * 16) ^ ((row & 7) << 4)));
    }

  f32x4 accA[2][4], accB[2][4];
#pragma unroll
  for (int rt = 0; rt < 2; ++rt)
#pragma unroll
    for (int nt = 0; nt < 4; ++nt) {
      accA[rt][nt] = (f32x4){0.f, 0.f, 0.f, 0.f};
      accB[rt][nt] = (f32x4){0.f, 0.f, 0.f, 0.f};
    }

#pragma unroll
  for (int nt = 0; nt < 4; ++nt) {
    int n = nt * 16 + lm;
#pragma unroll
    for (int kb = 0; kb < 2; ++kb) {
      int off = n * 128 + ((kb * 64 + lh * 16) ^ ((n & 7) << 4));
      half8 ba = *(half8*)((char*)sWa + off);
#pragma unroll
      for (int rt = 0; rt < 2; ++rt)
        accA[rt][nt] = __builtin_amdgcn_mfma_f32_16x16x32_f16(a[rt][kb], ba, accA[rt][nt], 0, 0, 0);
      if (DUAL) {
        half8 bb = *(half8*)((char*)sWb + off);
#pragma unroll
        for (int rt = 0; rt < 2; ++rt)
          accB[rt][nt] = __builtin_amdgcn_mfma_f32_16x16x32_f16(a[rt][kb], bb, accB[rt][nt], 0, 0, 0);
      }
    }
  }

#pragma unroll
  for (int rt = 0; rt < 2; ++rt) {
#pragma unroll
    for (int nt = 0; nt < 4; ++nt) {
      int col = nt * 16 + lm;
      float bv = DUAL ? bias[col] : 0.f;
#pragma unroll
      for (int r = 0; r < 4; ++r) {
        int row = row0 + w * 32 + rt * 16 + lh * 4 + r;
        if (row < NN) {
          float va = accA[rt][nt][r];
          if (SCALE) {
            Yh[row * 64 + col] = (_Float16)(va * scale[row]);
          } else {
            Yh[row * 64 + col] = (_Float16)va;
            Zh[row * 64 + col] = (_Float16)(accB[rt][nt][r] + bv);
          }
        }
      }
    }
  }
}

// ---------------- gather: lane = (node, 16B chunk); 8 nodes/wave; unroll-4 edges ----------------
// Edge spans are padded to x4 with dummy row NN (all zeros) -> branchless exact loop,
// 4 independent row loads in flight per lane-group (32 rows per wave).
__global__ __launch_bounds__(256) void k_gather(const int2* __restrict__ rp2,
    const int* __restrict__ csr, const _Float16* __restrict__ Yh,
    const _Float16* __restrict__ Zrow, _Float16* __restrict__ Aout, int relu)
{
  const int l = threadIdx.x & 63;
  const int wv = blockIdx.x * 4 + (threadIdx.x >> 6);
  const int node = wv * 8 + (l >> 3);          // grid sized exactly: node < NN
  const int base = (l & 7) * 8;
  const int2 se = rp2[node];

  float acc[8];
#pragma unroll
  for (int j = 0; j < 8; ++j) acc[j] = 0.f;

  for (int i = se.x; i < se.y; i += 4) {
    int4 ss = *(const int4*)(csr + i);
    half8 v0 = *(const half8*)(Yh + ss.x * 64 + base);
    half8 v1 = *(const half8*)(Yh + ss.y * 64 + base);
    half8 v2 = *(const half8*)(Yh + ss.z * 64 + base);
    half8 v3 = *(const half8*)(Yh + ss.w * 64 + base);
#pragma unroll
    for (int j = 0; j < 8; ++j)
      acc[j] += ((float)v0[j] + (float)v1[j]) + ((float)v2[j] + (float)v3[j]);
  }

  half8 zr = *(const half8*)(Zrow + node * 64 + base);
  half8 o;
#pragma unroll
  for (int j = 0; j < 8; ++j) {
    float t = acc[j] + (float)zr[j];
    if (relu) t = fmaxf(t, 0.f);
    o[j] = (_Float16)t;
  }
  *(half8*)(Aout + node * 64 + base) = o;
}

// ---------------- head (f16 T rows) ----------------
__global__ __launch_bounds__(256) void k_head(const _Float16* __restrict__ T,
    const float* __restrict__ dinv, const float* __restrict__ Wlin,
    const float* __restrict__ cvec, float* __restrict__ out)
{
  __shared__ float sW[64 * 10];
  __shared__ float sc[10];
  int tid = threadIdx.x;
  if (tid < 10) sc[tid] = cvec[tid];
  for (int i = tid; i < 640; i += 256) sW[i] = Wlin[i];
  __syncthreads();
  int n = blockIdx.x * 256 + tid;
  if (n >= NN) return;
  float di = dinv[n];
  float dot[10];
#pragma unroll
  for (int c = 0; c < 10; ++c) dot[c] = 0.f;
  const half8* row = (const half8*)(T + n * 64);
#pragma unroll
  for (int kc = 0; kc < 8; ++kc) {
    half8 v = row[kc];
#pragma unroll
    for (int j = 0; j < 8; ++j) {
      float f = (float)v[j];
#pragma unroll
      for (int c = 0; c < 10; ++c)
        dot[c] = fmaf(f, sW[(kc * 8 + j) * 10 + c], dot[c]);
    }
  }
#pragma unroll
  for (int c = 0; c < 10; ++c) out[n * 10 + c] = fmaf(di, dot[c], sc[c]);
}

extern "C" void kernel_launch(void* const* d_in, const int* in_sizes, int n_in,
                              void* d_out, int out_size, void* d_ws, size_t ws_size,
                              hipStream_t stream) {
  const float* x       = (const float*)d_in[0];
  const int*   ei      = (const int*)d_in[1];
  const float* W1_rel  = (const float*)d_in[2];
  const float* b1      = (const float*)d_in[3];
  const float* W1_root = (const float*)d_in[4];
  const float* W2_rel  = (const float*)d_in[5];
  const float* b2      = (const float*)d_in[6];
  const float* W2_root = (const float*)d_in[7];
  const float* W3      = (const float*)d_in[8];
  const float* b3      = (const float*)d_in[9];
  const float* Wlin    = (const float*)d_in[10];
  const float* blin    = (const float*)d_in[11];
  float* out = (float*)d_out;

  char* ws = (char*)d_ws;
  _Float16* Yh     = (_Float16*)(ws);             // (NN+1) rows: 12,800,128 B
  _Float16* Zh     = (_Float16*)(ws + 12800128);  // 12,800,000 B
  _Float16* Ah     = (_Float16*)(ws + 25600128);  // 12,800,000 B
  float*    dinv   = (float*)(ws + 38400128);     //    400,000 B
  int2*     rp2    = (int2*) (ws + 38800128);     //    800,000 B
  int*      csr    = (int*)  (ws + 39600128);     //  4,816,896 B (196*6144*4)
  _Float16* WT     = (_Float16*)(ws + 44417024);  //     40,960 B
  float*    cvec   = (float*)(ws + 44457984);     //         40 B
  // build temporaries overlaid on low Yh region (dead before gemm1 writes Yh):
  int* ebuf       = (int*)(ws);                   //  4,816,896 B
  int* bucket_cnt = (int*)(ws + 4900000);         //      1,024 B

  dim3 b256(256);

  k_prep<<<6, b256, 0, stream>>>(W1_rel, W1_root, W2_rel, W2_root, W3,
                                 b3, Wlin, blin, WT, cvec, bucket_cnt, Yh);
  k_bucket<<<GRID_C, b256, 0, stream>>>(ei, bucket_cnt, ebuf);
  k_csr_build<<<NBUK, b256, 0, stream>>>(bucket_cnt, ebuf, rp2, csr, dinv);

  const int gg = (NN + 127) / 128;   // 782
  const int gw = NN / 32;            // 3125 blocks: 4 waves x 8 nodes (exact)
  const int gN = (NN + 255) / 256;   // 391

  // layer 1: Yh = x@W1_rel ; Zh = x@W1_root + b1 ; Ah = relu(Zh + agg(Yh))
  k_gemmfma<false, true, false><<<gg, b256, 0, stream>>>(x, WT, WT + 4096, b1, nullptr, Yh, Zh);
  k_gather<<<gw, b256, 0, stream>>>(rp2, csr, Yh, Zh, Ah, 1);

  // layer 2
  k_gemmfma<true, true, false><<<gg, b256, 0, stream>>>(Ah, WT + 2 * 4096, WT + 3 * 4096, b2, nullptr, Yh, Zh);
  k_gather<<<gw, b256, 0, stream>>>(rp2, csr, Yh, Zh, Ah, 1);

  // layer 3 (GCN): Yh = (Ah@W3)*dinv ; T = Yh[node] + agg(Yh)
  k_gemmfma<true, false, true><<<gg, b256, 0, stream>>>(Ah, WT + 4 * 4096, nullptr, nullptr, dinv, Yh, nullptr);
  k_gather<<<gw, b256, 0, stream>>>(rp2, csr, Yh, Yh, Ah, 0);

  // head
  k_head<<<gN, b256, 0, stream>>>(Ah, dinv, Wlin, cvec, out);
}

// Round 10
// 122.748 us; speedup vs baseline: 6.0406x; 1.1867x over previous
//
#include <hip/hip_runtime.h>

#define NN 100000
#define NE 800000
#define BSH 9                 // 512 nodes per bucket
#define BSZ (1 << BSH)
#define NBUK ((NN + BSZ - 1) / BSZ)    // 196
#define CAP_E 5120            // ebuf bucket capacity (real edges, mean 4096)
#define CAP_C 7168            // csr bucket capacity (x8-padded spans, mean ~5786)
#define ECHUNK 4096
#define GRID_C ((NE + ECHUNK - 1) / ECHUNK)  // 196

typedef _Float16 half8 __attribute__((ext_vector_type(8)));
typedef float f32x4 __attribute__((ext_vector_type(4)));

// ---------------- bucketed CSR build ----------------
__global__ __launch_bounds__(256) void k_bucket(const int* __restrict__ ei,
    int* __restrict__ bucket_cnt, int* __restrict__ ebuf) {
  __shared__ int h[256];
  __shared__ int cur[256];
  const int tid = threadIdx.x;
  h[tid] = 0;
  __syncthreads();

  const int e0 = blockIdx.x * ECHUNK;
  int pk[16], bk[16];
#pragma unroll
  for (int i = 0; i < 16; ++i) {
    int e = e0 + i * 256 + tid;
    if (e < NE) {
      int src = ei[e];
      int dst = ei[NE + e];
      int b = dst >> BSH;
      pk[i] = src | ((dst & (BSZ - 1)) << 17);
      bk[i] = b;
      atomicAdd(&h[b], 1);
    } else bk[i] = -1;
  }
  __syncthreads();
  cur[tid] = (tid < NBUK && h[tid] > 0) ? atomicAdd(&bucket_cnt[tid], h[tid]) : 0;
  __syncthreads();
#pragma unroll
  for (int i = 0; i < 16; ++i) {
    if (bk[i] >= 0) {
      int slot = atomicAdd(&cur[bk[i]], 1);
      ebuf[bk[i] * CAP_E + slot] = pk[i];
    }
  }
}

// per bucket: spans padded to x8 (pads -> zero row NN), dinv, csr srcs
__global__ __launch_bounds__(256) void k_csr_build(const int* __restrict__ bucket_cnt,
    const int* __restrict__ ebuf, int2* __restrict__ rp2, int* __restrict__ csr,
    float* __restrict__ dinv) {
  __shared__ int h[BSZ];
  __shared__ int loff[BSZ];
  __shared__ int cur[BSZ];
  __shared__ int sd[256];
  const int tid = threadIdx.x;
  const int b = blockIdx.x;
  h[tid] = 0; h[tid + 256] = 0;
  __syncthreads();

  const int n = bucket_cnt[b];
  const int ebase = b * CAP_E;
  for (int i = tid; i < n; i += 256)
    atomicAdd(&h[ebuf[ebase + i] >> 17], 1);
  __syncthreads();

  // scan padded counts hp = (h+7)&~7 over 512 entries (thread owns 2t,2t+1)
  int r0 = h[2 * tid], r1 = h[2 * tid + 1];
  int p0 = (r0 + 7) & ~7, p1 = (r1 + 7) & ~7;
  int ps = p0 + p1;
  sd[tid] = ps;
  __syncthreads();
  int incl = ps;
  for (int o = 1; o < 256; o <<= 1) {
    int add = (tid >= o) ? sd[tid - o] : 0;
    __syncthreads();
    incl += add;
    sd[tid] = incl;
    __syncthreads();
  }
  int ex = incl - ps;
  loff[2 * tid] = ex;
  loff[2 * tid + 1] = ex + p0;
  cur[2 * tid] = ex;
  cur[2 * tid + 1] = ex + p0;
  __syncthreads();

  const int node0 = b * BSZ;
  const int cbase = b * CAP_C;
#pragma unroll
  for (int t = 0; t < 2; ++t) {
    int j = tid + t * 256;
    int node = node0 + j;
    if (node < NN) {
      int hr = h[j];
      int hp = (hr + 7) & ~7;
      int beg = cbase + loff[j];
      rp2[node] = make_int2(beg, beg + hp);
      dinv[node] = rsqrtf((float)hr + 1.0f);
      for (int p = hr; p < hp; ++p) csr[beg + p] = NN;  // pads -> zero row
    }
  }

  for (int i = tid; i < n; i += 256) {
    int v = ebuf[ebase + i];
    int dl = v >> 17;
    int slot = atomicAdd(&cur[dl], 1);
    csr[cbase + slot] = v & 0x1FFFF;
  }
}

// ---------------- prep: W12 stacks, W34T = W3@Wlin (transposed), cvec, zero rows ----------------
__global__ __launch_bounds__(256) void k_prep(
    const float* __restrict__ W1r, const float* __restrict__ W1o,
    const float* __restrict__ W2r, const float* __restrict__ W2o,
    const float* __restrict__ W3, const float* __restrict__ b3,
    const float* __restrict__ Wlin, const float* __restrict__ blin,
    _Float16* __restrict__ W12, float* __restrict__ W34T,
    float* __restrict__ cvec, int* __restrict__ bucket_cnt,
    _Float16* __restrict__ xh, _Float16* __restrict__ Ah, _Float16* __restrict__ A3)
{
  int m = blockIdx.x, tid = threadIdx.x;
  if (m < 2) {
    // W12[m][n*128+k] = k<64 ? Wrel[k][n] : Wroot[k-64][n]   (f16, [n][k] layout)
    const float* Wr = m ? W2r : W1r;
    const float* Wo = m ? W2o : W1o;
    _Float16* dst = W12 + m * 8192;
    for (int idx = tid; idx < 8192; idx += 256) {
      int n = idx >> 7, k = idx & 127;
      float v = (k < 64) ? Wr[k * 64 + n] : Wo[(k - 64) * 64 + n];
      dst[idx] = (_Float16)v;
    }
  } else if (m == 2) {
    // W34T[c*64+k] = sum_j W3[k][j] * Wlin[j][c]
    for (int idx = tid; idx < 640; idx += 256) {
      int c = idx >> 6, k = idx & 63;
      float s = 0.f;
      for (int j = 0; j < 64; ++j) s = fmaf(W3[k * 64 + j], Wlin[j * 10 + c], s);
      W34T[c * 64 + k] = s;
    }
    if (tid < 10) {
      float s = blin[tid];
      for (int j = 0; j < 64; ++j) s = fmaf(b3[j], Wlin[j * 10 + tid], s);
      cvec[tid] = s;
    }
  } else {
    bucket_cnt[tid] = 0;
    if (tid < 64) {
      xh[NN * 64 + tid] = (_Float16)0.f;
      Ah[NN * 64 + tid] = (_Float16)0.f;
      A3[NN * 64 + tid] = (_Float16)0.f;
    }
  }
}

// ---------------- x -> f16 ----------------
__global__ __launch_bounds__(256) void k_x16(const float* __restrict__ x,
    _Float16* __restrict__ xh) {
  int idx = blockIdx.x * 256 + threadIdx.x;     // 0..799999 exact
  const float4* p = (const float4*)(x + idx * 8);
  float4 a = p[0], b = p[1];
  half8 h;
  h[0] = (_Float16)a.x; h[1] = (_Float16)a.y; h[2] = (_Float16)a.z; h[3] = (_Float16)a.w;
  h[4] = (_Float16)b.x; h[5] = (_Float16)b.y; h[6] = (_Float16)b.z; h[7] = (_Float16)b.w;
  *(half8*)(xh + idx * 8) = h;
}

// ---------------- fused layer: gather -> LDS -> K=128 MFMA -> relu(+scale) ----------------
// out_row = relu( concat(agg_row, self_row) @ [Wrel; Wroot] + b ) [* dinv if SCALE_OUT]
template<bool SCALE_OUT>
__global__ __launch_bounds__(512) void k_layer(
    const _Float16* __restrict__ Ain, const int2* __restrict__ rp2,
    const int* __restrict__ csr, const _Float16* __restrict__ W12,
    const float* __restrict__ bias, const float* __restrict__ dinv,
    _Float16* __restrict__ Aout)
{
  __shared__ _Float16 sW[64 * 128];    // 16 KB [n][k] swizzled
  __shared__ _Float16 sA[128 * 128];   // 32 KB [node][k] swizzled (k<64 agg, k>=64 self)

  const int tid = threadIdx.x;
  const int node0 = blockIdx.x * 128;
  const int l = tid & 63, w = tid >> 6;          // 8 waves

  // stage W12: 1024 uint4 chunks
  {
    const uint4* g4 = (const uint4*)W12;
#pragma unroll
    for (int i = 0; i < 2; ++i) {
      int c = tid + 512 * i;
      int n = c >> 4, kc = c & 15;
      *(uint4*)((char*)sW + n * 256 + ((kc * 16) ^ ((n & 7) << 4))) = g4[c];
    }
  }

  // gather phase: 2 rounds x (8 waves x 8 groups) = 128 nodes
  const int grp = l >> 3, c8 = l & 7;
#pragma unroll
  for (int r = 0; r < 2; ++r) {
    int nl = r * 64 + w * 8 + grp;
    int node = node0 + nl;
    float acc[8];
#pragma unroll
    for (int j = 0; j < 8; ++j) acc[j] = 0.f;
    half8 selfv = {};
    if (node < NN) {
      int2 se = rp2[node];
      for (int i = se.x; i < se.y; i += 8) {
        int4 sa = *(const int4*)(csr + i);
        int4 sb = *(const int4*)(csr + i + 4);
        half8 v0 = *(const half8*)(Ain + sa.x * 64 + c8 * 8);
        half8 v1 = *(const half8*)(Ain + sa.y * 64 + c8 * 8);
        half8 v2 = *(const half8*)(Ain + sa.z * 64 + c8 * 8);
        half8 v3 = *(const half8*)(Ain + sa.w * 64 + c8 * 8);
        half8 v4 = *(const half8*)(Ain + sb.x * 64 + c8 * 8);
        half8 v5 = *(const half8*)(Ain + sb.y * 64 + c8 * 8);
        half8 v6 = *(const half8*)(Ain + sb.z * 64 + c8 * 8);
        half8 v7 = *(const half8*)(Ain + sb.w * 64 + c8 * 8);
#pragma unroll
        for (int j = 0; j < 8; ++j)
          acc[j] += (((float)v0[j] + (float)v1[j]) + ((float)v2[j] + (float)v3[j]))
                  + (((float)v4[j] + (float)v5[j]) + ((float)v6[j] + (float)v7[j]));
      }
      selfv = *(const half8*)(Ain + node * 64 + c8 * 8);
    }
    half8 ha;
#pragma unroll
    for (int j = 0; j < 8; ++j) ha[j] = (_Float16)acc[j];
    char* rowp = (char*)sA + nl * 256;
    int swz = (nl & 7) << 4;
    *(half8*)(rowp + ((c8 * 16) ^ swz)) = ha;
    *(half8*)(rowp + ((128 + c8 * 16) ^ swz)) = selfv;
  }
  __syncthreads();

  // MFMA phase: wave w -> rows w*16..w*16+15, all 64 cols, K=128
  const int lm = l & 15, lh = l >> 4;
  f32x4 acc[4];
#pragma unroll
  for (int nt = 0; nt < 4; ++nt) acc[nt] = (f32x4){0.f, 0.f, 0.f, 0.f};

  const int arow = w * 16 + lm;
  const int aswz = (arow & 7) << 4;
#pragma unroll
  for (int kb = 0; kb < 4; ++kb) {
    half8 af = *(half8*)((char*)sA + arow * 256 + ((kb * 64 + lh * 16) ^ aswz));
#pragma unroll
    for (int nt = 0; nt < 4; ++nt) {
      int n = nt * 16 + lm;
      half8 bf = *(half8*)((char*)sW + n * 256 + ((kb * 64 + lh * 16) ^ ((n & 7) << 4)));
      acc[nt] = __builtin_amdgcn_mfma_f32_16x16x32_f16(af, bf, acc[nt], 0, 0, 0);
    }
  }

  // epilogue: C/D map col=lane&15, row=(lane>>4)*4+reg
#pragma unroll
  for (int nt = 0; nt < 4; ++nt) {
    int col = nt * 16 + lm;
    float bv = bias[col];
#pragma unroll
    for (int r2 = 0; r2 < 4; ++r2) {
      int row = node0 + w * 16 + lh * 4 + r2;
      if (row < NN) {
        float v = fmaxf(acc[nt][r2] + bv, 0.f);
        if (SCALE_OUT) v *= dinv[row];
        Aout[row * 64 + col] = (_Float16)v;
      }
    }
  }
}

// ---------------- fused GCN layer + head ----------------
// S = agg(A3) + A3[self]; out[n][c] = dinv[n]*(S . W34T[c]) + cvec[c]
__global__ __launch_bounds__(256) void k_l3head(
    const _Float16* __restrict__ A3, const int2* __restrict__ rp2,
    const int* __restrict__ csr, const float* __restrict__ dinv,
    const float* __restrict__ W34T, const float* __restrict__ cvecg,
    float* __restrict__ out)
{
  __shared__ float sWT[640];
  __shared__ float sc[10];
  const int tid = threadIdx.x;
  if (tid < 10) sc[tid] = cvecg[tid];
  for (int i = tid; i < 640; i += 256) sWT[i] = W34T[i];
  __syncthreads();

  const int l = tid & 63, w = tid >> 6;
  const int grp = l >> 3, c8 = l & 7;
  const int node = blockIdx.x * 32 + w * 8 + grp;   // grid exact: 3125*32 = NN
  int2 se = rp2[node];

  float acc[8];
#pragma unroll
  for (int j = 0; j < 8; ++j) acc[j] = 0.f;

  for (int i = se.x; i < se.y; i += 8) {
    int4 sa = *(const int4*)(csr + i);
    int4 sb = *(const int4*)(csr + i + 4);
    half8 v0 = *(const half8*)(A3 + sa.x * 64 + c8 * 8);
    half8 v1 = *(const half8*)(A3 + sa.y * 64 + c8 * 8);
    half8 v2 = *(const half8*)(A3 + sa.z * 64 + c8 * 8);
    half8 v3 = *(const half8*)(A3 + sa.w * 64 + c8 * 8);
    half8 v4 = *(const half8*)(A3 + sb.x * 64 + c8 * 8);
    half8 v5 = *(const half8*)(A3 + sb.y * 64 + c8 * 8);
    half8 v6 = *(const half8*)(A3 + sb.z * 64 + c8 * 8);
    half8 v7 = *(const half8*)(A3 + sb.w * 64 + c8 * 8);
#pragma unroll
    for (int j = 0; j < 8; ++j)
      acc[j] += (((float)v0[j] + (float)v1[j]) + ((float)v2[j] + (float)v3[j]))
              + (((float)v4[j] + (float)v5[j]) + ((float)v6[j] + (float)v7[j]));
  }
  half8 selfv = *(const half8*)(A3 + node * 64 + c8 * 8);
#pragma unroll
  for (int j = 0; j < 8; ++j) acc[j] += (float)selfv[j];

  // partial dots over this lane's 8 k's, then reduce across the 8-lane group
  float p[10];
#pragma unroll
  for (int c = 0; c < 10; ++c) {
    float s = 0.f;
    const float* wb = sWT + c * 64 + c8 * 8;
#pragma unroll
    for (int j = 0; j < 8; ++j) s = fmaf(acc[j], wb[j], s);
    p[c] = s;
  }
#pragma unroll
  for (int off = 1; off < 8; off <<= 1)
#pragma unroll
    for (int c = 0; c < 10; ++c) p[c] += __shfl_xor(p[c], off);

  // static-index select (avoid scratch): lane c8 writes c8; lanes 0,1 also 8,9
  float v1p = 0.f, v2p = 0.f;
#pragma unroll
  for (int c = 0; c < 10; ++c) {
    if (c == c8) v1p = p[c];
    if (c == c8 + 8) v2p = p[c];
  }
  float dv = dinv[node];
  out[node * 10 + c8] = fmaf(dv, v1p, sc[c8]);
  if (c8 < 2) out[node * 10 + 8 + c8] = fmaf(dv, v2p, sc[8 + c8]);
}

extern "C" void kernel_launch(void* const* d_in, const int* in_sizes, int n_in,
                              void* d_out, int out_size, void* d_ws, size_t ws_size,
                              hipStream_t stream) {
  const float* x       = (const float*)d_in[0];
  const int*   ei      = (const int*)d_in[1];
  const float* W1_rel  = (const float*)d_in[2];
  const float* b1      = (const float*)d_in[3];
  const float* W1_root = (const float*)d_in[4];
  const float* W2_rel  = (const float*)d_in[5];
  const float* b2      = (const float*)d_in[6];
  const float* W2_root = (const float*)d_in[7];
  const float* W3      = (const float*)d_in[8];
  const float* b3      = (const float*)d_in[9];
  const float* Wlin    = (const float*)d_in[10];
  const float* blin    = (const float*)d_in[11];
  float* out = (float*)d_out;

  char* ws = (char*)d_ws;
  _Float16* xh   = (_Float16*)(ws);               // (NN+1)*64 f16 = 12,800,128 B
  _Float16* Ah   = (_Float16*)(ws + 12800128);    // 12,800,128 B
  _Float16* A3   = (_Float16*)(ws + 25600256);    // 12,800,128 B (dinv-scaled h2)
  float*    dinv = (float*)(ws + 38400384);       //    400,000 B
  int2*     rp2  = (int2*) (ws + 38800384);       //    800,000 B
  int*      csr  = (int*)  (ws + 39600384);       //  5,619,712 B (196*7168*4)
  _Float16* W12  = (_Float16*)(ws + 45220096);    //     32,768 B (2 stacked mats)
  float*    W34T = (float*)(ws + 45252864);       //      2,560 B
  float*    cvec = (float*)(ws + 45255424);       //         64 B
  int* bucket_cnt= (int*)  (ws + 45255488);       //      1,024 B
  // ebuf overlays A3 (dead until k_layer<true> writes it, after csr_build):
  int* ebuf      = (int*)  (ws + 25600256);       //  4,014,080 B

  dim3 b256(256), b512(512);

  k_prep<<<4, b256, 0, stream>>>(W1_rel, W1_root, W2_rel, W2_root, W3, b3, Wlin, blin,
                                 W12, W34T, cvec, bucket_cnt, xh, Ah, A3);
  k_x16<<<3125, b256, 0, stream>>>(x, xh);
  k_bucket<<<GRID_C, b256, 0, stream>>>(ei, bucket_cnt, ebuf);
  k_csr_build<<<NBUK, b256, 0, stream>>>(bucket_cnt, ebuf, rp2, csr, dinv);

  const int gl = (NN + 127) / 128;   // 782

  // layer 1: Ah = relu(concat(agg(xh), xh) @ [W1rel;W1root] + b1)
  k_layer<false><<<gl, b512, 0, stream>>>(xh, rp2, csr, W12, b1, nullptr, Ah);
  // layer 2: A3 = dinv * relu(concat(agg(Ah), Ah) @ [W2rel;W2root] + b2)
  k_layer<true><<<gl, b512, 0, stream>>>(Ah, rp2, csr, W12 + 8192, b2, dinv, A3);
  // layer 3 + head: out = dinv*( (agg(A3)+A3) @ (W3@Wlin) ) + (b3@Wlin + blin)
  k_l3head<<<3125, b256, 0, stream>>>(A3, rp2, csr, dinv, W34T, cvec, out);
}

// Round 11
// 121.364 us; speedup vs baseline: 6.1095x; 1.0114x over previous
//
#include <hip/hip_runtime.h>

#define NN 100000
#define NE 800000
#define BSH 9                 // 512 nodes per bucket
#define BSZ (1 << BSH)
#define NBUK ((NN + BSZ - 1) / BSZ)    // 196
#define CAP_E 5120            // ebuf bucket capacity (real edges, mean 4096)
#define CAP_C 7168            // csr bucket capacity (x8-padded spans, mean ~5786)
#define ECHUNK 4096
#define GRID_C ((NE + ECHUNK - 1) / ECHUNK)  // 196

typedef _Float16 half8 __attribute__((ext_vector_type(8)));
typedef float f32x4 __attribute__((ext_vector_type(4)));

// ---------------- bucketed CSR build ----------------
__global__ __launch_bounds__(256) void k_bucket(const int* __restrict__ ei,
    int* __restrict__ bucket_cnt, int* __restrict__ ebuf) {
  __shared__ int h[256];
  __shared__ int cur[256];
  const int tid = threadIdx.x;
  h[tid] = 0;
  __syncthreads();

  const int e0 = blockIdx.x * ECHUNK;
  int pk[16], bk[16];
#pragma unroll
  for (int i = 0; i < 16; ++i) {
    int e = e0 + i * 256 + tid;
    if (e < NE) {
      int src = ei[e];
      int dst = ei[NE + e];
      int b = dst >> BSH;
      pk[i] = src | ((dst & (BSZ - 1)) << 17);
      bk[i] = b;
      atomicAdd(&h[b], 1);
    } else bk[i] = -1;
  }
  __syncthreads();
  cur[tid] = (tid < NBUK && h[tid] > 0) ? atomicAdd(&bucket_cnt[tid], h[tid]) : 0;
  __syncthreads();
#pragma unroll
  for (int i = 0; i < 16; ++i) {
    if (bk[i] >= 0) {
      int slot = atomicAdd(&cur[bk[i]], 1);
      ebuf[bk[i] * CAP_E + slot] = pk[i];
    }
  }
}

// per bucket: spans padded to x8 (pads -> zero row NN), dinv, csr srcs
__global__ __launch_bounds__(256) void k_csr_build(const int* __restrict__ bucket_cnt,
    const int* __restrict__ ebuf, int2* __restrict__ rp2, int* __restrict__ csr,
    float* __restrict__ dinv) {
  __shared__ int h[BSZ];
  __shared__ int loff[BSZ];
  __shared__ int cur[BSZ];
  __shared__ int sd[256];
  const int tid = threadIdx.x;
  const int b = blockIdx.x;
  h[tid] = 0; h[tid + 256] = 0;
  __syncthreads();

  const int n = bucket_cnt[b];
  const int ebase = b * CAP_E;
  for (int i = tid; i < n; i += 256)
    atomicAdd(&h[ebuf[ebase + i] >> 17], 1);
  __syncthreads();

  int r0 = h[2 * tid], r1 = h[2 * tid + 1];
  int p0 = (r0 + 7) & ~7, p1 = (r1 + 7) & ~7;
  int ps = p0 + p1;
  sd[tid] = ps;
  __syncthreads();
  int incl = ps;
  for (int o = 1; o < 256; o <<= 1) {
    int add = (tid >= o) ? sd[tid - o] : 0;
    __syncthreads();
    incl += add;
    sd[tid] = incl;
    __syncthreads();
  }
  int ex = incl - ps;
  loff[2 * tid] = ex;
  loff[2 * tid + 1] = ex + p0;
  cur[2 * tid] = ex;
  cur[2 * tid + 1] = ex + p0;
  __syncthreads();

  const int node0 = b * BSZ;
  const int cbase = b * CAP_C;
#pragma unroll
  for (int t = 0; t < 2; ++t) {
    int j = tid + t * 256;
    int node = node0 + j;
    if (node < NN) {
      int hr = h[j];
      int hp = (hr + 7) & ~7;
      int beg = cbase + loff[j];
      rp2[node] = make_int2(beg, beg + hp);
      dinv[node] = rsqrtf((float)hr + 1.0f);
      for (int p = hr; p < hp; ++p) csr[beg + p] = NN;  // pads -> zero row
    }
  }

  for (int i = tid; i < n; i += 256) {
    int v = ebuf[ebase + i];
    int dl = v >> 17;
    int slot = atomicAdd(&cur[dl], 1);
    csr[cbase + slot] = v & 0x1FFFF;
  }
}

// ---------------- prep (weights, cvec, zero rows, bucket_cnt) + x->f16 ----------------
__global__ __launch_bounds__(256) void k_prep(
    const float* __restrict__ W1r, const float* __restrict__ W1o,
    const float* __restrict__ W2r, const float* __restrict__ W2o,
    const float* __restrict__ W3, const float* __restrict__ b3,
    const float* __restrict__ Wlin, const float* __restrict__ blin,
    const float* __restrict__ x,
    _Float16* __restrict__ W12, float* __restrict__ W34T,
    float* __restrict__ cvec, int* __restrict__ bucket_cnt,
    _Float16* __restrict__ xh, _Float16* __restrict__ Ah,
    _Float16* __restrict__ A3, _Float16* __restrict__ P)
{
  int m = blockIdx.x, tid = threadIdx.x;
  if (m >= 4) {
    int idx = (m - 4) * 256 + tid;              // 0..799999 exact
    const float4* p4 = (const float4*)(x + idx * 8);
    float4 a = p4[0], b = p4[1];
    half8 h;
    h[0] = (_Float16)a.x; h[1] = (_Float16)a.y; h[2] = (_Float16)a.z; h[3] = (_Float16)a.w;
    h[4] = (_Float16)b.x; h[5] = (_Float16)b.y; h[6] = (_Float16)b.z; h[7] = (_Float16)b.w;
    *(half8*)(xh + idx * 8) = h;
    return;
  }
  if (m < 2) {
    const float* Wr = m ? W2r : W1r;
    const float* Wo = m ? W2o : W1o;
    _Float16* dst = W12 + m * 8192;
    for (int idx = tid; idx < 8192; idx += 256) {
      int n = idx >> 7, k = idx & 127;
      float v = (k < 64) ? Wr[k * 64 + n] : Wo[(k - 64) * 64 + n];
      dst[idx] = (_Float16)v;
    }
  } else if (m == 2) {
    // W34T[c*64+k] = sum_j W3[k][j] * Wlin[j][c]
    for (int idx = tid; idx < 640; idx += 256) {
      int c = idx >> 6, k = idx & 63;
      float s = 0.f;
      for (int j = 0; j < 64; ++j) s = fmaf(W3[k * 64 + j], Wlin[j * 10 + c], s);
      W34T[c * 64 + k] = s;
    }
    if (tid < 10) {
      float s = blin[tid];
      for (int j = 0; j < 64; ++j) s = fmaf(b3[j], Wlin[j * 10 + tid], s);
      cvec[tid] = s;
    }
  } else {
    bucket_cnt[tid] = 0;
    if (tid < 64) {
      xh[NN * 64 + tid] = (_Float16)0.f;
      Ah[NN * 64 + tid] = (_Float16)0.f;
      A3[NN * 64 + tid] = (_Float16)0.f;
    }
    if (tid < 16) P[NN * 16 + tid] = (_Float16)0.f;
  }
}

// ---------------- fused layer: gather -> LDS -> K=128 MFMA -> relu(+scale) ----------------
template<bool SCALE_OUT>
__global__ __launch_bounds__(512) void k_layer(
    const _Float16* __restrict__ Ain, const int2* __restrict__ rp2,
    const int* __restrict__ csr, const _Float16* __restrict__ W12,
    const float* __restrict__ bias, const float* __restrict__ dinv,
    _Float16* __restrict__ Aout)
{
  __shared__ _Float16 sW[64 * 128];    // 16 KB [n][k] swizzled
  __shared__ _Float16 sA[128 * 128];   // 32 KB [node][k] swizzled

  const int tid = threadIdx.x;
  const int node0 = blockIdx.x * 128;
  const int l = tid & 63, w = tid >> 6;

  {
    const uint4* g4 = (const uint4*)W12;
#pragma unroll
    for (int i = 0; i < 2; ++i) {
      int c = tid + 512 * i;
      int n = c >> 4, kc = c & 15;
      *(uint4*)((char*)sW + n * 256 + ((kc * 16) ^ ((n & 7) << 4))) = g4[c];
    }
  }

  const int grp = l >> 3, c8 = l & 7;
#pragma unroll
  for (int r = 0; r < 2; ++r) {
    int nl = r * 64 + w * 8 + grp;
    int node = node0 + nl;
    float acc[8];
#pragma unroll
    for (int j = 0; j < 8; ++j) acc[j] = 0.f;
    half8 selfv = {};
    if (node < NN) {
      int2 se = rp2[node];
      for (int i = se.x; i < se.y; i += 8) {
        int4 sa = *(const int4*)(csr + i);
        int4 sb = *(const int4*)(csr + i + 4);
        half8 v0 = *(const half8*)(Ain + sa.x * 64 + c8 * 8);
        half8 v1 = *(const half8*)(Ain + sa.y * 64 + c8 * 8);
        half8 v2 = *(const half8*)(Ain + sa.z * 64 + c8 * 8);
        half8 v3 = *(const half8*)(Ain + sa.w * 64 + c8 * 8);
        half8 v4 = *(const half8*)(Ain + sb.x * 64 + c8 * 8);
        half8 v5 = *(const half8*)(Ain + sb.y * 64 + c8 * 8);
        half8 v6 = *(const half8*)(Ain + sb.z * 64 + c8 * 8);
        half8 v7 = *(const half8*)(Ain + sb.w * 64 + c8 * 8);
#pragma unroll
        for (int j = 0; j < 8; ++j)
          acc[j] += (((float)v0[j] + (float)v1[j]) + ((float)v2[j] + (float)v3[j]))
                  + (((float)v4[j] + (float)v5[j]) + ((float)v6[j] + (float)v7[j]));
      }
      selfv = *(const half8*)(Ain + node * 64 + c8 * 8);
    }
    half8 ha;
#pragma unroll
    for (int j = 0; j < 8; ++j) ha[j] = (_Float16)acc[j];
    char* rowp = (char*)sA + nl * 256;
    int swz = (nl & 7) << 4;
    *(half8*)(rowp + ((c8 * 16) ^ swz)) = ha;
    *(half8*)(rowp + ((128 + c8 * 16) ^ swz)) = selfv;
  }
  __syncthreads();

  const int lm = l & 15, lh = l >> 4;
  f32x4 acc[4];
#pragma unroll
  for (int nt = 0; nt < 4; ++nt) acc[nt] = (f32x4){0.f, 0.f, 0.f, 0.f};

  const int arow = w * 16 + lm;
  const int aswz = (arow & 7) << 4;
#pragma unroll
  for (int kb = 0; kb < 4; ++kb) {
    half8 af = *(half8*)((char*)sA + arow * 256 + ((kb * 64 + lh * 16) ^ aswz));
#pragma unroll
    for (int nt = 0; nt < 4; ++nt) {
      int n = nt * 16 + lm;
      half8 bf = *(half8*)((char*)sW + n * 256 + ((kb * 64 + lh * 16) ^ ((n & 7) << 4)));
      acc[nt] = __builtin_amdgcn_mfma_f32_16x16x32_f16(af, bf, acc[nt], 0, 0, 0);
    }
  }

#pragma unroll
  for (int nt = 0; nt < 4; ++nt) {
    int col = nt * 16 + lm;
    float bv = bias[col];
#pragma unroll
    for (int r2 = 0; r2 < 4; ++r2) {
      int row = node0 + w * 16 + lh * 4 + r2;
      if (row < NN) {
        float v = fmaxf(acc[nt][r2] + bv, 0.f);
        if (SCALE_OUT) v *= dinv[row];
        Aout[row * 64 + col] = (_Float16)v;
      }
    }
  }
}

// ---------------- P = A3 @ W34T  (f16 rows padded to 16) ----------------
// 32 nodes/block: 8-lane group per node; lane owns 8 k's; shfl-reduce; 2 lanes write.
__global__ __launch_bounds__(256) void k_pmat(const _Float16* __restrict__ A3,
    const float* __restrict__ W34T, _Float16* __restrict__ P)
{
  __shared__ float sWT[640];
  const int tid = threadIdx.x;
  for (int i = tid; i < 640; i += 256) sWT[i] = W34T[i];
  __syncthreads();

  const int g = tid >> 3, c8 = tid & 7;
  const int node = blockIdx.x * 32 + g;          // grid 3125 exact
  half8 v = *(const half8*)(A3 + node * 64 + c8 * 8);

  float p[10];
#pragma unroll
  for (int c = 0; c < 10; ++c) {
    const float* wb = sWT + c * 64 + c8 * 8;
    float s = 0.f;
#pragma unroll
    for (int j = 0; j < 8; ++j) s = fmaf((float)v[j], wb[j], s);
    p[c] = s;
  }
#pragma unroll
  for (int off = 1; off < 8; off <<= 1)
#pragma unroll
    for (int c = 0; c < 10; ++c) p[c] += __shfl_xor(p[c], off);

  if (c8 < 2) {
    half8 o = {};
#pragma unroll
    for (int j = 0; j < 8; ++j) {
      int c = c8 * 8 + j;
      if (c < 10) o[j] = (_Float16)p[c];
    }
    *(half8*)(P + node * 16 + c8 * 8) = o;
  }
}

// ---------------- head: gather P (32B rows), no shuffles ----------------
// out[n][c] = dinv[n] * (sum_{j in N(n)} P[j][c] + P[n][c]) + cvec[c]
__global__ __launch_bounds__(256) void k_head2(const int2* __restrict__ rp2,
    const int* __restrict__ csr, const _Float16* __restrict__ P,
    const float* __restrict__ dinv, const float* __restrict__ cvecg,
    float* __restrict__ out)
{
  __shared__ float sc[10];
  const int tid = threadIdx.x;
  if (tid < 10) sc[tid] = cvecg[tid];
  __syncthreads();

  const int node = blockIdx.x * 128 + (tid >> 1);
  const int half = tid & 1;
  if (node >= NN) return;
  int2 se = rp2[node];

  float acc[8];
#pragma unroll
  for (int j = 0; j < 8; ++j) acc[j] = 0.f;

  for (int i = se.x; i < se.y; i += 8) {
    int4 sa = *(const int4*)(csr + i);
    int4 sb = *(const int4*)(csr + i + 4);
    half8 v0 = *(const half8*)(P + sa.x * 16 + half * 8);
    half8 v1 = *(const half8*)(P + sa.y * 16 + half * 8);
    half8 v2 = *(const half8*)(P + sa.z * 16 + half * 8);
    half8 v3 = *(const half8*)(P + sa.w * 16 + half * 8);
    half8 v4 = *(const half8*)(P + sb.x * 16 + half * 8);
    half8 v5 = *(const half8*)(P + sb.y * 16 + half * 8);
    half8 v6 = *(const half8*)(P + sb.z * 16 + half * 8);
    half8 v7 = *(const half8*)(P + sb.w * 16 + half * 8);
#pragma unroll
    for (int j = 0; j < 8; ++j)
      acc[j] += (((float)v0[j] + (float)v1[j]) + ((float)v2[j] + (float)v3[j]))
              + (((float)v4[j] + (float)v5[j]) + ((float)v6[j] + (float)v7[j]));
  }
  half8 selfv = *(const half8*)(P + node * 16 + half * 8);
#pragma unroll
  for (int j = 0; j < 8; ++j) acc[j] += (float)selfv[j];

  float dv = dinv[node];
  if (half == 0) {
#pragma unroll
    for (int j = 0; j < 4; ++j) {
      float2 o;
      o.x = fmaf(dv, acc[2 * j], sc[2 * j]);
      o.y = fmaf(dv, acc[2 * j + 1], sc[2 * j + 1]);
      *(float2*)(out + node * 10 + 2 * j) = o;
    }
  } else {
    float2 o;
    o.x = fmaf(dv, acc[0], sc[8]);
    o.y = fmaf(dv, acc[1], sc[9]);
    *(float2*)(out + node * 10 + 8) = o;
  }
}

extern "C" void kernel_launch(void* const* d_in, const int* in_sizes, int n_in,
                              void* d_out, int out_size, void* d_ws, size_t ws_size,
                              hipStream_t stream) {
  const float* x       = (const float*)d_in[0];
  const int*   ei      = (const int*)d_in[1];
  const float* W1_rel  = (const float*)d_in[2];
  const float* b1      = (const float*)d_in[3];
  const float* W1_root = (const float*)d_in[4];
  const float* W2_rel  = (const float*)d_in[5];
  const float* b2      = (const float*)d_in[6];
  const float* W2_root = (const float*)d_in[7];
  const float* W3      = (const float*)d_in[8];
  const float* b3      = (const float*)d_in[9];
  const float* Wlin    = (const float*)d_in[10];
  const float* blin    = (const float*)d_in[11];
  float* out = (float*)d_out;

  char* ws = (char*)d_ws;
  _Float16* xh   = (_Float16*)(ws);               // (NN+1)*64 f16 = 12,800,128 B
  _Float16* Ah   = (_Float16*)(ws + 12800128);    // 12,800,128 B
  _Float16* A3   = (_Float16*)(ws + 25600256);    // 12,800,128 B
  float*    dinv = (float*)(ws + 38400384);       //    400,000 B
  int2*     rp2  = (int2*) (ws + 38800384);       //    800,000 B
  int*      csr  = (int*)  (ws + 39600384);       //  5,619,712 B
  _Float16* W12  = (_Float16*)(ws + 45220096);    //     32,768 B
  float*    W34T = (float*)(ws + 45252864);       //      2,560 B
  float*    cvec = (float*)(ws + 45255424);       //         64 B
  int* bucket_cnt= (int*)  (ws + 45255488);       //      1,024 B
  _Float16* P    = (_Float16*)(ws + 45256512);    //  3,200,032 B ((NN+1)*16 f16)
  // ebuf overlays A3 (dead until k_layer<true> writes it, after csr_build):
  int* ebuf      = (int*)  (ws + 25600256);       //  4,014,080 B

  dim3 b256(256), b512(512);

  k_prep<<<3129, b256, 0, stream>>>(W1_rel, W1_root, W2_rel, W2_root, W3, b3, Wlin,
                                    blin, x, W12, W34T, cvec, bucket_cnt, xh, Ah, A3, P);
  k_bucket<<<GRID_C, b256, 0, stream>>>(ei, bucket_cnt, ebuf);
  k_csr_build<<<NBUK, b256, 0, stream>>>(bucket_cnt, ebuf, rp2, csr, dinv);

  const int gl = (NN + 127) / 128;   // 782

  // layer 1: Ah = relu(concat(agg(xh), xh) @ [W1rel;W1root] + b1)
  k_layer<false><<<gl, b512, 0, stream>>>(xh, rp2, csr, W12, b1, nullptr, Ah);
  // layer 2: A3 = dinv * relu(concat(agg(Ah), Ah) @ [W2rel;W2root] + b2)
  k_layer<true><<<gl, b512, 0, stream>>>(Ah, rp2, csr, W12 + 8192, b2, dinv, A3);
  // P = A3 @ (W3@Wlin), f16 rows padded to 16
  k_pmat<<<3125, b256, 0, stream>>>(A3, W34T, P);
  // head: out = dinv*(agg(P)+P) + cvec
  k_head2<<<gl, b256, 0, stream>>>(rp2, csr, P, dinv, cvec, out);
}

// Round 13
// 106.485 us; speedup vs baseline: 6.9632x; 1.1397x over previous
//
#include <hip/hip_runtime.h>

#define NN 100000
#define NE 800000
#define BSH 9                 // 512 nodes per bucket
#define BSZ (1 << BSH)
#define NBUK ((NN + BSZ - 1) / BSZ)    // 196
#define CAP_E 5120            // ebuf bucket capacity (real edges, mean 4096)
#define CAP_C 7168            // csr bucket capacity (x8-padded spans)
#define ECHUNK 4096
#define GRID_C ((NE + ECHUNK - 1) / ECHUNK)  // 196

typedef _Float16 half8 __attribute__((ext_vector_type(8)));
typedef float f32x4 __attribute__((ext_vector_type(4)));

// ---------------- bucketed CSR build ----------------
__global__ __launch_bounds__(256) void k_bucket(const int* __restrict__ ei,
    int* __restrict__ bucket_cnt, int* __restrict__ ebuf) {
  __shared__ int h[256];
  __shared__ int cur[256];
  const int tid = threadIdx.x;
  h[tid] = 0;
  __syncthreads();

  const int e0 = blockIdx.x * ECHUNK;
  int pk[16], bk[16];
#pragma unroll
  for (int i = 0; i < 16; ++i) {
    int e = e0 + i * 256 + tid;
    if (e < NE) {
      int src = ei[e];
      int dst = ei[NE + e];
      int b = dst >> BSH;
      pk[i] = src | ((dst & (BSZ - 1)) << 17);
      bk[i] = b;
      atomicAdd(&h[b], 1);
    } else bk[i] = -1;
  }
  __syncthreads();
  cur[tid] = (tid < NBUK && h[tid] > 0) ? atomicAdd(&bucket_cnt[tid], h[tid]) : 0;
  __syncthreads();
#pragma unroll
  for (int i = 0; i < 16; ++i) {
    if (bk[i] >= 0) {
      int slot = atomicAdd(&cur[bk[i]], 1);
      ebuf[bk[i] * CAP_E + slot] = pk[i];
    }
  }
}

__global__ __launch_bounds__(256) void k_csr_build(const int* __restrict__ bucket_cnt,
    const int* __restrict__ ebuf, int2* __restrict__ rp2, int* __restrict__ csr,
    float* __restrict__ dinv) {
  __shared__ int h[BSZ];
  __shared__ int loff[BSZ];
  __shared__ int cur[BSZ];
  __shared__ int sd[256];
  const int tid = threadIdx.x;
  const int b = blockIdx.x;
  h[tid] = 0; h[tid + 256] = 0;
  __syncthreads();

  const int n = bucket_cnt[b];
  const int ebase = b * CAP_E;
  for (int i = tid; i < n; i += 256)
    atomicAdd(&h[ebuf[ebase + i] >> 17], 1);
  __syncthreads();

  int r0 = h[2 * tid], r1 = h[2 * tid + 1];
  int p0 = (r0 + 7) & ~7, p1 = (r1 + 7) & ~7;
  int ps = p0 + p1;
  sd[tid] = ps;
  __syncthreads();
  int incl = ps;
  for (int o = 1; o < 256; o <<= 1) {
    int add = (tid >= o) ? sd[tid - o] : 0;
    __syncthreads();
    incl += add;
    sd[tid] = incl;
    __syncthreads();
  }
  int ex = incl - ps;
  loff[2 * tid] = ex;
  loff[2 * tid + 1] = ex + p0;
  cur[2 * tid] = ex;
  cur[2 * tid + 1] = ex + p0;
  __syncthreads();

  const int node0 = b * BSZ;
  const int cbase = b * CAP_C;
#pragma unroll
  for (int t = 0; t < 2; ++t) {
    int j = tid + t * 256;
    int node = node0 + j;
    if (node < NN) {
      int hr = h[j];
      int hp = (hr + 7) & ~7;
      int beg = cbase + loff[j];
      rp2[node] = make_int2(beg, beg + hp);
      dinv[node] = rsqrtf((float)hr + 1.0f);
      for (int p = hr; p < hp; ++p) csr[beg + p] = NN;  // pads -> zero row
    }
  }

  for (int i = tid; i < n; i += 256) {
    int v = ebuf[ebase + i];
    int dl = v >> 17;
    int slot = atomicAdd(&cur[dl], 1);
    csr[cbase + slot] = v & 0x1FFFF;
  }
}

// ---------------- prep (weights, cvec, zero rows, bucket_cnt) + x->f16 ----------------
__global__ __launch_bounds__(256) void k_prep(
    const float* __restrict__ W1r, const float* __restrict__ W1o,
    const float* __restrict__ W2r, const float* __restrict__ W2o,
    const float* __restrict__ W3, const float* __restrict__ b3,
    const float* __restrict__ Wlin, const float* __restrict__ blin,
    const float* __restrict__ x,
    _Float16* __restrict__ W12, _Float16* __restrict__ W34h,
    float* __restrict__ cvec, int* __restrict__ bucket_cnt,
    _Float16* __restrict__ xh, _Float16* __restrict__ Ah, _Float16* __restrict__ P)
{
  int m = blockIdx.x, tid = threadIdx.x;
  if (m >= 4) {
    int idx = (m - 4) * 256 + tid;              // 0..799999 exact
    const float4* p4 = (const float4*)(x + idx * 8);
    float4 a = p4[0], b = p4[1];
    half8 h;
    h[0] = (_Float16)a.x; h[1] = (_Float16)a.y; h[2] = (_Float16)a.z; h[3] = (_Float16)a.w;
    h[4] = (_Float16)b.x; h[5] = (_Float16)b.y; h[6] = (_Float16)b.z; h[7] = (_Float16)b.w;
    *(half8*)(xh + idx * 8) = h;
    return;
  }
  if (m < 2) {
    const float* Wr = m ? W2r : W1r;
    const float* Wo = m ? W2o : W1o;
    _Float16* dst = W12 + m * 8192;
    for (int idx = tid; idx < 8192; idx += 256) {
      int n = idx >> 7, k = idx & 127;
      float v = (k < 64) ? Wr[k * 64 + n] : Wo[(k - 64) * 64 + n];
      dst[idx] = (_Float16)v;
    }
  } else if (m == 2) {
    // W34h[c][k] = sum_j W3[k][j]*Wlin[j][c], c<10 (0 for c in 10..15); f16 [n=c][k]
    for (int idx = tid; idx < 1024; idx += 256) {
      int c = idx >> 6, k = idx & 63;
      float s = 0.f;
      if (c < 10)
        for (int j = 0; j < 64; ++j) s = fmaf(W3[k * 64 + j], Wlin[j * 10 + c], s);
      W34h[idx] = (_Float16)s;
    }
    if (tid < 10) {
      float s = blin[tid];
      for (int j = 0; j < 64; ++j) s = fmaf(b3[j], Wlin[j * 10 + tid], s);
      cvec[tid] = s;
    }
  } else {
    bucket_cnt[tid] = 0;
    if (tid < 64) {
      xh[NN * 64 + tid] = (_Float16)0.f;
      Ah[NN * 64 + tid] = (_Float16)0.f;
    }
    if (tid < 16) P[NN * 16 + tid] = (_Float16)0.f;
  }
}

// ---------------- fused layer: gather -> LDS -> K=128 MFMA -> relu(+scale) ----------------
// PSTAGE: write relu*dinv result back to sA (own band), mini-MFMA with W34h -> P.
// else  : write relu result to Aout (f16 global).
template<bool PSTAGE>
__global__ __launch_bounds__(512) void k_layer(
    const _Float16* __restrict__ Ain, const int2* __restrict__ rp2,
    const int* __restrict__ csr, const _Float16* __restrict__ W12,
    const float* __restrict__ bias, const float* __restrict__ dinv,
    _Float16* __restrict__ Aout, const _Float16* __restrict__ W34h,
    _Float16* __restrict__ P)
{
  __shared__ _Float16 sW[64 * 128];               // 16 KB [n][k] swizzled
  __shared__ _Float16 sA[128 * 128];              // 32 KB [node][k] swizzled
  __shared__ _Float16 sW34[PSTAGE ? 16 * 64 : 8]; // 2 KB

  const int tid = threadIdx.x;
  const int node0 = blockIdx.x * 128;
  const int l = tid & 63, w = tid >> 6;

  {
    const uint4* g4 = (const uint4*)W12;
#pragma unroll
    for (int i = 0; i < 2; ++i) {
      int c = tid + 512 * i;
      int n = c >> 4, kc = c & 15;
      *(uint4*)((char*)sW + n * 256 + ((kc * 16) ^ ((n & 7) << 4))) = g4[c];
    }
    if (PSTAGE && tid < 128) {
      // 16 rows x 8 chunks of 16B  (row = 64 f16 = 128 B)
      int n = tid >> 3, kc = tid & 7;
      uint4 v = ((const uint4*)W34h)[tid];
      *(uint4*)((char*)sW34 + n * 128 + ((kc * 16) ^ ((n & 7) << 4))) = v;
    }
  }

  const int grp = l >> 3, c8 = l & 7;
#pragma unroll
  for (int r = 0; r < 2; ++r) {
    int nl = r * 64 + w * 8 + grp;
    int node = node0 + nl;
    float acc[8];
#pragma unroll
    for (int j = 0; j < 8; ++j) acc[j] = 0.f;
    half8 selfv = {};
    if (node < NN) {
      int2 se = rp2[node];
      for (int i = se.x; i < se.y; i += 8) {
        int4 sa = *(const int4*)(csr + i);
        int4 sb = *(const int4*)(csr + i + 4);
        half8 v0 = *(const half8*)(Ain + sa.x * 64 + c8 * 8);
        half8 v1 = *(const half8*)(Ain + sa.y * 64 + c8 * 8);
        half8 v2 = *(const half8*)(Ain + sa.z * 64 + c8 * 8);
        half8 v3 = *(const half8*)(Ain + sa.w * 64 + c8 * 8);
        half8 v4 = *(const half8*)(Ain + sb.x * 64 + c8 * 8);
        half8 v5 = *(const half8*)(Ain + sb.y * 64 + c8 * 8);
        half8 v6 = *(const half8*)(Ain + sb.z * 64 + c8 * 8);
        half8 v7 = *(const half8*)(Ain + sb.w * 64 + c8 * 8);
#pragma unroll
        for (int j = 0; j < 8; ++j)
          acc[j] += (((float)v0[j] + (float)v1[j]) + ((float)v2[j] + (float)v3[j]))
                  + (((float)v4[j] + (float)v5[j]) + ((float)v6[j] + (float)v7[j]));
      }
      selfv = *(const half8*)(Ain + node * 64 + c8 * 8);
    }
    half8 ha;
#pragma unroll
    for (int j = 0; j < 8; ++j) ha[j] = (_Float16)acc[j];
    char* rowp = (char*)sA + nl * 256;
    int swz = (nl & 7) << 4;
    *(half8*)(rowp + ((c8 * 16) ^ swz)) = ha;
    *(half8*)(rowp + ((128 + c8 * 16) ^ swz)) = selfv;
  }
  __syncthreads();

  const int lm = l & 15, lh = l >> 4;
  f32x4 acc[4];
#pragma unroll
  for (int nt = 0; nt < 4; ++nt) acc[nt] = (f32x4){0.f, 0.f, 0.f, 0.f};

  const int arow = w * 16 + lm;
  const int aswz = (arow & 7) << 4;
#pragma unroll
  for (int kb = 0; kb < 4; ++kb) {
    half8 af = *(half8*)((char*)sA + arow * 256 + ((kb * 64 + lh * 16) ^ aswz));
#pragma unroll
    for (int nt = 0; nt < 4; ++nt) {
      int n = nt * 16 + lm;
      half8 bf = *(half8*)((char*)sW + n * 256 + ((kb * 64 + lh * 16) ^ ((n & 7) << 4)));
      acc[nt] = __builtin_amdgcn_mfma_f32_16x16x32_f16(af, bf, acc[nt], 0, 0, 0);
    }
  }

  if (!PSTAGE) {
    // epilogue: relu -> f16 global
#pragma unroll
    for (int nt = 0; nt < 4; ++nt) {
      int col = nt * 16 + lm;
      float bv = bias[col];
#pragma unroll
      for (int r2 = 0; r2 < 4; ++r2) {
        int row = node0 + w * 16 + lh * 4 + r2;
        if (row < NN)
          Aout[row * 64 + col] = (_Float16)fmaxf(acc[nt][r2] + bv, 0.f);
      }
    }
  } else {
    // epilogue: A3 = relu(acc+b)*dinv -> own sA band (no cross-wave hazard),
    // then mini-MFMA (K=64) with W34h -> P rows.
#pragma unroll
    for (int r2 = 0; r2 < 4; ++r2) {
      int lrow = w * 16 + lh * 4 + r2;
      int grow = node0 + lrow;
      float s = (grow < NN) ? dinv[grow] : 0.f;
      char* rowp = (char*)sA + lrow * 256;
      int swz = (lrow & 7) << 4;
#pragma unroll
      for (int nt = 0; nt < 4; ++nt) {
        int col = nt * 16 + lm;
        float v = fmaxf(acc[nt][r2] + bias[col], 0.f) * s;
        *(_Float16*)(rowp + ((col * 2) ^ swz)) = (_Float16)v;
      }
    }
    // same-wave ds_write -> ds_read ordering is handled by waitcnt
    f32x4 accP = (f32x4){0.f, 0.f, 0.f, 0.f};
#pragma unroll
    for (int kb = 0; kb < 2; ++kb) {
      half8 af = *(half8*)((char*)sA + arow * 256 + ((kb * 64 + lh * 16) ^ aswz));
      half8 bf = *(half8*)((char*)sW34 + lm * 128 + ((kb * 64 + lh * 16) ^ ((lm & 7) << 4)));
      accP = __builtin_amdgcn_mfma_f32_16x16x32_f16(af, bf, accP, 0, 0, 0);
    }
#pragma unroll
    for (int r2 = 0; r2 < 4; ++r2) {
      int row = node0 + w * 16 + lh * 4 + r2;
      if (row < NN) P[row * 16 + lm] = (_Float16)accP[r2];
    }
  }
}

// ---------------- head: gather P (32B rows) ----------------
// out[n][c] = dinv[n] * (sum_{j in N(n)} P[j][c] + P[n][c]) + cvec[c]
__global__ __launch_bounds__(256) void k_head2(const int2* __restrict__ rp2,
    const int* __restrict__ csr, const _Float16* __restrict__ P,
    const float* __restrict__ dinv, const float* __restrict__ cvecg,
    float* __restrict__ out)
{
  __shared__ float sc[10];
  const int tid = threadIdx.x;
  if (tid < 10) sc[tid] = cvecg[tid];
  __syncthreads();

  const int node = blockIdx.x * 128 + (tid >> 1);
  const int half = tid & 1;
  if (node >= NN) return;
  int2 se = rp2[node];

  float acc[8];
#pragma unroll
  for (int j = 0; j < 8; ++j) acc[j] = 0.f;

  for (int i = se.x; i < se.y; i += 8) {
    int4 sa = *(const int4*)(csr + i);
    int4 sb = *(const int4*)(csr + i + 4);
    half8 v0 = *(const half8*)(P + sa.x * 16 + half * 8);
    half8 v1 = *(const half8*)(P + sa.y * 16 + half * 8);
    half8 v2 = *(const half8*)(P + sa.z * 16 + half * 8);
    half8 v3 = *(const half8*)(P + sa.w * 16 + half * 8);
    half8 v4 = *(const half8*)(P + sb.x * 16 + half * 8);
    half8 v5 = *(const half8*)(P + sb.y * 16 + half * 8);
    half8 v6 = *(const half8*)(P + sb.z * 16 + half * 8);
    half8 v7 = *(const half8*)(P + sb.w * 16 + half * 8);
#pragma unroll
    for (int j = 0; j < 8; ++j)
      acc[j] += (((float)v0[j] + (float)v1[j]) + ((float)v2[j] + (float)v3[j]))
              + (((float)v4[j] + (float)v5[j]) + ((float)v6[j] + (float)v7[j]));
  }
  half8 selfv = *(const half8*)(P + node * 16 + half * 8);
#pragma unroll
  for (int j = 0; j < 8; ++j) acc[j] += (float)selfv[j];

  float dv = dinv[node];
  if (half == 0) {
#pragma unroll
    for (int j = 0; j < 4; ++j) {
      float2 o;
      o.x = fmaf(dv, acc[2 * j], sc[2 * j]);
      o.y = fmaf(dv, acc[2 * j + 1], sc[2 * j + 1]);
      *(float2*)(out + node * 10 + 2 * j) = o;
    }
  } else {
    float2 o;
    o.x = fmaf(dv, acc[0], sc[8]);
    o.y = fmaf(dv, acc[1], sc[9]);
    *(float2*)(out + node * 10 + 8) = o;
  }
}

extern "C" void kernel_launch(void* const* d_in, const int* in_sizes, int n_in,
                              void* d_out, int out_size, void* d_ws, size_t ws_size,
                              hipStream_t stream) {
  const float* x       = (const float*)d_in[0];
  const int*   ei      = (const int*)d_in[1];
  const float* W1_rel  = (const float*)d_in[2];
  const float* b1      = (const float*)d_in[3];
  const float* W1_root = (const float*)d_in[4];
  const float* W2_rel  = (const float*)d_in[5];
  const float* b2      = (const float*)d_in[6];
  const float* W2_root = (const float*)d_in[7];
  const float* W3      = (const float*)d_in[8];
  const float* b3      = (const float*)d_in[9];
  const float* Wlin    = (const float*)d_in[10];
  const float* blin    = (const float*)d_in[11];
  float* out = (float*)d_out;

  char* ws = (char*)d_ws;
  _Float16* xh   = (_Float16*)(ws);               // (NN+1)*64 f16 = 12,800,128 B
  _Float16* Ah   = (_Float16*)(ws + 12800128);    // 12,800,128 B
  float*    dinv = (float*)(ws + 25600256);       //    400,000 B
  int2*     rp2  = (int2*) (ws + 26000256);       //    800,000 B
  int*      csr  = (int*)  (ws + 26800256);       //  5,619,712 B
  _Float16* W12  = (_Float16*)(ws + 32419968);    //     32,768 B
  _Float16* W34h = (_Float16*)(ws + 32452736);    //      2,048 B
  float*    cvec = (float*)(ws + 32454784);       //         64 B
  int* bucket_cnt= (int*)  (ws + 32454848);       //      1,024 B
  _Float16* P    = (_Float16*)(ws + 32455872);    //  3,200,032 B ((NN+1)*16)
  int* ebuf      = (int*)  (ws + 35655904);       //  4,014,080 B

  dim3 b256(256), b512(512);

  k_prep<<<3129, b256, 0, stream>>>(W1_rel, W1_root, W2_rel, W2_root, W3, b3, Wlin,
                                    blin, x, W12, W34h, cvec, bucket_cnt, xh, Ah, P);
  k_bucket<<<GRID_C, b256, 0, stream>>>(ei, bucket_cnt, ebuf);
  k_csr_build<<<NBUK, b256, 0, stream>>>(bucket_cnt, ebuf, rp2, csr, dinv);

  const int gl = (NN + 127) / 128;   // 782

  // layer 1: Ah = relu(concat(agg(xh), xh) @ [W1rel;W1root] + b1)
  k_layer<false><<<gl, b512, 0, stream>>>(xh, rp2, csr, W12, b1, nullptr, Ah,
                                          nullptr, nullptr);
  // layer 2 + GCN-project: A3 = dinv*relu(concat(agg(Ah),Ah)@[W2rel;W2root]+b2)
  //                        P  = A3 @ (W3@Wlin)   (in-LDS, no A3 materialization)
  k_layer<true><<<gl, b512, 0, stream>>>(Ah, rp2, csr, W12 + 8192, b2, dinv, nullptr,
                                         W34h, P);
  // head: out = dinv*(agg(P)+P) + cvec
  k_head2<<<gl, b256, 0, stream>>>(rp2, csr, P, dinv, cvec, out);
}

// Round 14
// 96.650 us; speedup vs baseline: 7.6718x; 1.1018x over previous
//
#include <hip/hip_runtime.h>

#define NN 100000
#define NE 800000
#define BSH 9                 // 512 nodes per bucket
#define BSZ (1 << BSH)
#define NBUK ((NN + BSZ - 1) / BSZ)    // 196
#define NCHUNK 196            // edge chunks of 4096
#define CAPB 64               // per-(chunk,bucket) capacity (mean 21, 9 sigma)
#define CAP_C 7168            // csr bucket capacity (x8-padded spans)

typedef _Float16 half8 __attribute__((ext_vector_type(8)));
typedef float f32x4 __attribute__((ext_vector_type(4)));

// ---------------- setup: weights + cvec + dummy rows + x->f16 + edge binning ----------------
// blocks 0..3: weight prep; 4..3128: x->f16; 3129..3324: chunk binning (atomic-free global)
__global__ __launch_bounds__(256) void k_setup(
    const float* __restrict__ W1r, const float* __restrict__ W1o,
    const float* __restrict__ W2r, const float* __restrict__ W2o,
    const float* __restrict__ W3, const float* __restrict__ b3,
    const float* __restrict__ Wlin, const float* __restrict__ blin,
    const float* __restrict__ x, const int* __restrict__ ei,
    _Float16* __restrict__ W12, _Float16* __restrict__ W34h,
    float* __restrict__ cvec,
    _Float16* __restrict__ xh, _Float16* __restrict__ Ah, _Float16* __restrict__ P,
    int* __restrict__ cnt2, int* __restrict__ ebuf2)
{
  const int m = blockIdx.x, tid = threadIdx.x;

  if (m >= 3129) {
    // ---- chunk binning: block owns edges [c*4096, (c+1)*4096) ----
    __shared__ int curs[256];
    const int c = m - 3129;
    curs[tid] = 0;
    __syncthreads();
    const int e0 = c * 4096;
    int pk[16], bk[16];
#pragma unroll
    for (int i = 0; i < 16; ++i) {
      int e = e0 + i * 256 + tid;
      if (e < NE) {
        int src = ei[e];
        int dst = ei[NE + e];
        bk[i] = dst >> BSH;
        pk[i] = src | ((dst & (BSZ - 1)) << 17);
      } else bk[i] = -1;
    }
#pragma unroll
    for (int i = 0; i < 16; ++i) {
      if (bk[i] >= 0) {
        int slot = atomicAdd(&curs[bk[i]], 1);            // LDS atomic only
        ebuf2[(c * NBUK + bk[i]) * CAPB + slot] = pk[i];
      }
    }
    __syncthreads();
    if (tid < NBUK) cnt2[c * NBUK + tid] = curs[tid];
    return;
  }

  if (m >= 4) {
    // ---- x -> f16 ----
    int idx = (m - 4) * 256 + tid;              // 0..799999 exact
    const float4* p4 = (const float4*)(x + idx * 8);
    float4 a = p4[0], b = p4[1];
    half8 h;
    h[0] = (_Float16)a.x; h[1] = (_Float16)a.y; h[2] = (_Float16)a.z; h[3] = (_Float16)a.w;
    h[4] = (_Float16)b.x; h[5] = (_Float16)b.y; h[6] = (_Float16)b.z; h[7] = (_Float16)b.w;
    *(half8*)(xh + idx * 8) = h;
    return;
  }

  if (m < 2) {
    const float* Wr = m ? W2r : W1r;
    const float* Wo = m ? W2o : W1o;
    _Float16* dst = W12 + m * 8192;
    for (int idx = tid; idx < 8192; idx += 256) {
      int n = idx >> 7, k = idx & 127;
      float v = (k < 64) ? Wr[k * 64 + n] : Wo[(k - 64) * 64 + n];
      dst[idx] = (_Float16)v;
    }
  } else if (m == 2) {
    // W34h[c][k] = sum_j W3[k][j]*Wlin[j][c], c<10 (0 for c in 10..15)
    for (int idx = tid; idx < 1024; idx += 256) {
      int c = idx >> 6, k = idx & 63;
      float s = 0.f;
      if (c < 10)
        for (int j = 0; j < 64; ++j) s = fmaf(W3[k * 64 + j], Wlin[j * 10 + c], s);
      W34h[idx] = (_Float16)s;
    }
    if (tid < 10) {
      float s = blin[tid];
      for (int j = 0; j < 64; ++j) s = fmaf(b3[j], Wlin[j * 10 + tid], s);
      cvec[tid] = s;
    }
  } else {  // m == 3: dummy zero rows
    if (tid < 64) {
      xh[NN * 64 + tid] = (_Float16)0.f;
      Ah[NN * 64 + tid] = (_Float16)0.f;
    }
    if (tid < 16) P[NN * 16 + tid] = (_Float16)0.f;
  }
}

// ---------------- CSR build: one block per bucket, all state block-local ----------------
__global__ __launch_bounds__(256) void k_csr2(const int* __restrict__ cnt2,
    const int* __restrict__ ebuf2, int2* __restrict__ rp2, int* __restrict__ csr,
    float* __restrict__ dinv)
{
  __shared__ int stage[6144];     // bucket edges (mean 4081, +32 sigma)
  __shared__ int h[BSZ];
  __shared__ int loff[BSZ];
  __shared__ int cur[BSZ];
  __shared__ int sd[256];
  __shared__ int cbase[NCHUNK];
  __shared__ int ntot;
  const int tid = threadIdx.x;
  const int b = blockIdx.x;
  h[tid] = 0; h[tid + 256] = 0;

  // scan per-chunk counts for this bucket -> stage bases
  int v = (tid < NCHUNK) ? cnt2[tid * NBUK + b] : 0;
  sd[tid] = v;
  __syncthreads();
  int incl = v;
  for (int o = 1; o < 256; o <<= 1) {
    int add = (tid >= o) ? sd[tid - o] : 0;
    __syncthreads();
    incl += add;
    sd[tid] = incl;
    __syncthreads();
  }
  if (tid < NCHUNK) cbase[tid] = incl - v;
  if (tid == 255) ntot = incl;
  __syncthreads();

  // copy chunk segments into stage
  if (tid < NCHUNK) {
    const int* src = ebuf2 + (tid * NBUK + b) * CAPB;
    int base = cbase[tid];
    for (int i = 0; i < v; ++i) stage[base + i] = src[i];
  }
  __syncthreads();
  const int n = ntot;

  // histogram over 512 local nodes
  for (int i = tid; i < n; i += 256)
    atomicAdd(&h[stage[i] >> 17], 1);
  __syncthreads();

  // scan padded counts hp = (h+7)&~7 (thread owns 2t, 2t+1)
  int r0 = h[2 * tid], r1 = h[2 * tid + 1];
  int p0 = (r0 + 7) & ~7, p1 = (r1 + 7) & ~7;
  int ps = p0 + p1;
  sd[tid] = ps;
  __syncthreads();
  int incl2 = ps;
  for (int o = 1; o < 256; o <<= 1) {
    int add = (tid >= o) ? sd[tid - o] : 0;
    __syncthreads();
    incl2 += add;
    sd[tid] = incl2;
    __syncthreads();
  }
  int ex = incl2 - ps;
  loff[2 * tid] = ex;
  loff[2 * tid + 1] = ex + p0;
  cur[2 * tid] = ex;
  cur[2 * tid + 1] = ex + p0;
  __syncthreads();

  const int node0 = b * BSZ;
  const int cbase2 = b * CAP_C;
#pragma unroll
  for (int t = 0; t < 2; ++t) {
    int j = tid + t * 256;
    int node = node0 + j;
    if (node < NN) {
      int hr = h[j];
      int hp = (hr + 7) & ~7;
      int beg = cbase2 + loff[j];
      rp2[node] = make_int2(beg, beg + hp);
      dinv[node] = rsqrtf((float)hr + 1.0f);
      for (int p = hr; p < hp; ++p) csr[beg + p] = NN;  // pads -> zero row
    }
  }

  for (int i = tid; i < n; i += 256) {
    int w = stage[i];
    int dl = w >> 17;
    int slot = atomicAdd(&cur[dl], 1);
    csr[cbase2 + slot] = w & 0x1FFFF;
  }
}

// ---------------- fused layer: gather -> LDS -> K=128 MFMA -> relu(+scale) ----------------
// PSTAGE: write relu*dinv result back to sA (own band), mini-MFMA with W34h -> P.
// else  : write relu result to Aout (f16 global).
template<bool PSTAGE>
__global__ __launch_bounds__(512) void k_layer(
    const _Float16* __restrict__ Ain, const int2* __restrict__ rp2,
    const int* __restrict__ csr, const _Float16* __restrict__ W12,
    const float* __restrict__ bias, const float* __restrict__ dinv,
    _Float16* __restrict__ Aout, const _Float16* __restrict__ W34h,
    _Float16* __restrict__ P)
{
  __shared__ _Float16 sW[64 * 128];               // 16 KB [n][k] swizzled
  __shared__ _Float16 sA[128 * 128];              // 32 KB [node][k] swizzled
  __shared__ _Float16 sW34[PSTAGE ? 16 * 64 : 8]; // 2 KB

  const int tid = threadIdx.x;
  const int node0 = blockIdx.x * 128;
  const int l = tid & 63, w = tid >> 6;

  {
    const uint4* g4 = (const uint4*)W12;
#pragma unroll
    for (int i = 0; i < 2; ++i) {
      int c = tid + 512 * i;
      int n = c >> 4, kc = c & 15;
      *(uint4*)((char*)sW + n * 256 + ((kc * 16) ^ ((n & 7) << 4))) = g4[c];
    }
    if (PSTAGE && tid < 128) {
      int n = tid >> 3, kc = tid & 7;             // 16 rows x 8 chunks of 16B
      uint4 v = ((const uint4*)W34h)[tid];
      *(uint4*)((char*)sW34 + n * 128 + ((kc * 16) ^ ((n & 7) << 4))) = v;
    }
  }

  const int grp = l >> 3, c8 = l & 7;
#pragma unroll
  for (int r = 0; r < 2; ++r) {
    int nl = r * 64 + w * 8 + grp;
    int node = node0 + nl;
    float acc[8];
#pragma unroll
    for (int j = 0; j < 8; ++j) acc[j] = 0.f;
    half8 selfv = {};
    if (node < NN) {
      int2 se = rp2[node];
      for (int i = se.x; i < se.y; i += 8) {
        int4 sa = *(const int4*)(csr + i);
        int4 sb = *(const int4*)(csr + i + 4);
        half8 v0 = *(const half8*)(Ain + sa.x * 64 + c8 * 8);
        half8 v1 = *(const half8*)(Ain + sa.y * 64 + c8 * 8);
        half8 v2 = *(const half8*)(Ain + sa.z * 64 + c8 * 8);
        half8 v3 = *(const half8*)(Ain + sa.w * 64 + c8 * 8);
        half8 v4 = *(const half8*)(Ain + sb.x * 64 + c8 * 8);
        half8 v5 = *(const half8*)(Ain + sb.y * 64 + c8 * 8);
        half8 v6 = *(const half8*)(Ain + sb.z * 64 + c8 * 8);
        half8 v7 = *(const half8*)(Ain + sb.w * 64 + c8 * 8);
#pragma unroll
        for (int j = 0; j < 8; ++j)
          acc[j] += (((float)v0[j] + (float)v1[j]) + ((float)v2[j] + (float)v3[j]))
                  + (((float)v4[j] + (float)v5[j]) + ((float)v6[j] + (float)v7[j]));
      }
      selfv = *(const half8*)(Ain + node * 64 + c8 * 8);
    }
    half8 ha;
#pragma unroll
    for (int j = 0; j < 8; ++j) ha[j] = (_Float16)acc[j];
    char* rowp = (char*)sA + nl * 256;
    int swz = (nl & 7) << 4;
    *(half8*)(rowp + ((c8 * 16) ^ swz)) = ha;
    *(half8*)(rowp + ((128 + c8 * 16) ^ swz)) = selfv;
  }
  __syncthreads();

  const int lm = l & 15, lh = l >> 4;
  f32x4 acc[4];
#pragma unroll
  for (int nt = 0; nt < 4; ++nt) acc[nt] = (f32x4){0.f, 0.f, 0.f, 0.f};

  const int arow = w * 16 + lm;
  const int aswz = (arow & 7) << 4;
#pragma unroll
  for (int kb = 0; kb < 4; ++kb) {
    half8 af = *(half8*)((char*)sA + arow * 256 + ((kb * 64 + lh * 16) ^ aswz));
#pragma unroll
    for (int nt = 0; nt < 4; ++nt) {
      int n = nt * 16 + lm;
      half8 bf = *(half8*)((char*)sW + n * 256 + ((kb * 64 + lh * 16) ^ ((n & 7) << 4)));
      acc[nt] = __builtin_amdgcn_mfma_f32_16x16x32_f16(af, bf, acc[nt], 0, 0, 0);
    }
  }

  if (!PSTAGE) {
#pragma unroll
    for (int nt = 0; nt < 4; ++nt) {
      int col = nt * 16 + lm;
      float bv = bias[col];
#pragma unroll
      for (int r2 = 0; r2 < 4; ++r2) {
        int row = node0 + w * 16 + lh * 4 + r2;
        if (row < NN)
          Aout[row * 64 + col] = (_Float16)fmaxf(acc[nt][r2] + bv, 0.f);
      }
    }
  } else {
    // A3 = relu(acc+b)*dinv -> own sA band, then mini-MFMA (K=64) -> P.
#pragma unroll
    for (int r2 = 0; r2 < 4; ++r2) {
      int lrow = w * 16 + lh * 4 + r2;
      int grow = node0 + lrow;
      float s = (grow < NN) ? dinv[grow] : 0.f;
      char* rowp = (char*)sA + lrow * 256;
      int swz = (lrow & 7) << 4;
#pragma unroll
      for (int nt = 0; nt < 4; ++nt) {
        int col = nt * 16 + lm;
        float v = fmaxf(acc[nt][r2] + bias[col], 0.f) * s;
        *(_Float16*)(rowp + ((col * 2) ^ swz)) = (_Float16)v;
      }
    }
    f32x4 accP = (f32x4){0.f, 0.f, 0.f, 0.f};
#pragma unroll
    for (int kb = 0; kb < 2; ++kb) {
      half8 af = *(half8*)((char*)sA + arow * 256 + ((kb * 64 + lh * 16) ^ aswz));
      half8 bf = *(half8*)((char*)sW34 + lm * 128 + ((kb * 64 + lh * 16) ^ ((lm & 7) << 4)));
      accP = __builtin_amdgcn_mfma_f32_16x16x32_f16(af, bf, accP, 0, 0, 0);
    }
#pragma unroll
    for (int r2 = 0; r2 < 4; ++r2) {
      int row = node0 + w * 16 + lh * 4 + r2;
      if (row < NN) P[row * 16 + lm] = (_Float16)accP[r2];
    }
  }
}

// ---------------- head: gather P (32B rows) ----------------
__global__ __launch_bounds__(256) void k_head2(const int2* __restrict__ rp2,
    const int* __restrict__ csr, const _Float16* __restrict__ P,
    const float* __restrict__ dinv, const float* __restrict__ cvecg,
    float* __restrict__ out)
{
  __shared__ float sc[10];
  const int tid = threadIdx.x;
  if (tid < 10) sc[tid] = cvecg[tid];
  __syncthreads();

  const int node = blockIdx.x * 128 + (tid >> 1);
  const int half = tid & 1;
  if (node >= NN) return;
  int2 se = rp2[node];

  float acc[8];
#pragma unroll
  for (int j = 0; j < 8; ++j) acc[j] = 0.f;

  for (int i = se.x; i < se.y; i += 8) {
    int4 sa = *(const int4*)(csr + i);
    int4 sb = *(const int4*)(csr + i + 4);
    half8 v0 = *(const half8*)(P + sa.x * 16 + half * 8);
    half8 v1 = *(const half8*)(P + sa.y * 16 + half * 8);
    half8 v2 = *(const half8*)(P + sa.z * 16 + half * 8);
    half8 v3 = *(const half8*)(P + sa.w * 16 + half * 8);
    half8 v4 = *(const half8*)(P + sb.x * 16 + half * 8);
    half8 v5 = *(const half8*)(P + sb.y * 16 + half * 8);
    half8 v6 = *(const half8*)(P + sb.z * 16 + half * 8);
    half8 v7 = *(const half8*)(P + sb.w * 16 + half * 8);
#pragma unroll
    for (int j = 0; j < 8; ++j)
      acc[j] += (((float)v0[j] + (float)v1[j]) + ((float)v2[j] + (float)v3[j]))
              + (((float)v4[j] + (float)v5[j]) + ((float)v6[j] + (float)v7[j]));
  }
  half8 selfv = *(const half8*)(P + node * 16 + half * 8);
#pragma unroll
  for (int j = 0; j < 8; ++j) acc[j] += (float)selfv[j];

  float dv = dinv[node];
  if (half == 0) {
#pragma unroll
    for (int j = 0; j < 4; ++j) {
      float2 o;
      o.x = fmaf(dv, acc[2 * j], sc[2 * j]);
      o.y = fmaf(dv, acc[2 * j + 1], sc[2 * j + 1]);
      *(float2*)(out + node * 10 + 2 * j) = o;
    }
  } else {
    float2 o;
    o.x = fmaf(dv, acc[0], sc[8]);
    o.y = fmaf(dv, acc[1], sc[9]);
    *(float2*)(out + node * 10 + 8) = o;
  }
}

extern "C" void kernel_launch(void* const* d_in, const int* in_sizes, int n_in,
                              void* d_out, int out_size, void* d_ws, size_t ws_size,
                              hipStream_t stream) {
  const float* x       = (const float*)d_in[0];
  const int*   ei      = (const int*)d_in[1];
  const float* W1_rel  = (const float*)d_in[2];
  const float* b1      = (const float*)d_in[3];
  const float* W1_root = (const float*)d_in[4];
  const float* W2_rel  = (const float*)d_in[5];
  const float* b2      = (const float*)d_in[6];
  const float* W2_root = (const float*)d_in[7];
  const float* W3      = (const float*)d_in[8];
  const float* b3      = (const float*)d_in[9];
  const float* Wlin    = (const float*)d_in[10];
  const float* blin    = (const float*)d_in[11];
  float* out = (float*)d_out;

  char* ws = (char*)d_ws;
  _Float16* xh   = (_Float16*)(ws);               // (NN+1)*64 f16 = 12,800,128 B
  _Float16* Ah   = (_Float16*)(ws + 12800128);    // 12,800,128 B
  float*    dinv = (float*)(ws + 25600256);       //    400,000 B
  int2*     rp2  = (int2*) (ws + 26000256);       //    800,000 B
  int*      csr  = (int*)  (ws + 26800256);       //  5,619,712 B (196*7168*4)
  _Float16* W12  = (_Float16*)(ws + 32419968);    //     32,768 B
  _Float16* W34h = (_Float16*)(ws + 32452736);    //      2,048 B
  float*    cvec = (float*)(ws + 32454784);       //         64 B
  _Float16* P    = (_Float16*)(ws + 32454848);    //  3,200,032 B ((NN+1)*16)
  int*      cnt2 = (int*)  (ws + 35654880);       //    153,664 B (196*196)
  int*      ebuf2= (int*)  (ws + 35808544);       //  9,834,496 B (196*196*64*4)

  dim3 b256(256), b512(512);

  // kernel 1: weights + cvec + dummy rows + x->f16 + atomic-free edge binning
  k_setup<<<3325, b256, 0, stream>>>(W1_rel, W1_root, W2_rel, W2_root, W3, b3, Wlin,
                                     blin, x, ei, W12, W34h, cvec, xh, Ah, P,
                                     cnt2, ebuf2);
  // kernel 2: per-bucket CSR (spans x8-padded, pads -> zero row NN)
  k_csr2<<<NBUK, b256, 0, stream>>>(cnt2, ebuf2, rp2, csr, dinv);

  const int gl = (NN + 127) / 128;   // 782

  // kernel 3: Ah = relu(concat(agg(xh), xh) @ [W1rel;W1root] + b1)
  k_layer<false><<<gl, b512, 0, stream>>>(xh, rp2, csr, W12, b1, nullptr, Ah,
                                          nullptr, nullptr);
  // kernel 4: A3 = dinv*relu(concat(agg(Ah),Ah)@[W2rel;W2root]+b2); P = A3@(W3@Wlin)
  k_layer<true><<<gl, b512, 0, stream>>>(Ah, rp2, csr, W12 + 8192, b2, dinv, nullptr,
                                         W34h, P);
  // kernel 5: out = dinv*(agg(P)+P) + cvec
  k_head2<<<gl, b256, 0, stream>>>(rp2, csr, P, dinv, cvec, out);
}